// Round 3
// baseline (3661.580 us; speedup 1.0000x reference)
//
#include <hip/hip_runtime.h>
#include <hip/hip_bf16.h>
#include <math.h>

#define DIM    256
#define KCB    4096
#define NROWS  32768
#define DECAYF 0.99f
#define MARGIN 0.03f

// ---- d_out offsets (in floats) ----
#define OUT_ZQ   0
#define OUT_IDX  8388608
#define OUT_LOSS 8421376
#define OUT_PPL  8421377
#define OUT_CB   8421378
#define OUT_CS   9469954
#define OUT_ES   9474050

// ---- d_ws offsets (bytes) ----
#define WS_A2      0u            // [32768][512] bf16 (hi|lo)  32 MB
#define WS_EH      33554432u     // [4096][256] bf16            2 MB
#define WS_ZSQ     35651584u     // N f32
#define WS_ESQ     35782656u     // K f32
#define WS_P1      35799040u     // [32][32768] f32 partial min1
#define WS_PI      39993344u     // [32][32768] i32 partial idx1
#define WS_P2      44187648u     // [32][32768] f32 partial min2
#define WS_IDX     48381952u     // N i32 final idx
#define WS_FLIST   48513024u     // N i32 flagged rows
#define WS_LIST2   48644096u     // N i32 inverted index
#define WS_BASE    48775168u     // K i32
#define WS_ZERO    48791552u     // zeroed region start
#define WS_COUNTS  48791552u     // K i32
#define WS_CURSOR  48807936u     // K i32
#define WS_FLCNT   48824320u
#define WS_LOSS    48824324u
#define WS_ENT     48824328u
#define WS_ZEROLEN 32800u

typedef __attribute__((ext_vector_type(8))) short short8;
typedef __attribute__((ext_vector_type(4))) float f32x4;

#define GLOAD(g, l) __builtin_amdgcn_global_load_lds( \
    (const __attribute__((address_space(1))) unsigned int*)(g), \
    (__attribute__((address_space(3))) unsigned int*)(l), 16, 0, 0)

__device__ __forceinline__ unsigned short f2bf(float x) {
  __hip_bfloat16 h = __float2bfloat16(x);
  return *reinterpret_cast<unsigned short*>(&h);
}
__device__ __forceinline__ float bf2f(unsigned short u) {
  unsigned int v = ((unsigned int)u) << 16;
  return *reinterpret_cast<float*>(&v);
}

// z -> A2 = [z_hi | z_lo] bf16, plus z_sq.  One wave per row.
__global__ __launch_bounds__(256) void prep_z(
    const float* __restrict__ z, unsigned short* __restrict__ A2,
    float* __restrict__ z_sq) {
  int gw = (blockIdx.x * 256 + threadIdx.x) >> 6;
  int lane = threadIdx.x & 63;
  float4 v = *(const float4*)(z + (size_t)gw * DIM + lane * 4);
  float x[4] = {v.x, v.y, v.z, v.w};
  unsigned short h[4], l[4];
  float ss = 0.f;
#pragma unroll
  for (int i = 0; i < 4; ++i) {
    ss += x[i] * x[i];
    h[i] = f2bf(x[i]);
    l[i] = f2bf(x[i] - bf2f(h[i]));
  }
  size_t o = (size_t)gw * 512 + lane * 4;
  *(ushort4*)(A2 + o) = make_ushort4(h[0], h[1], h[2], h[3]);
  *(ushort4*)(A2 + o + 256) = make_ushort4(l[0], l[1], l[2], l[3]);
#pragma unroll
  for (int off = 32; off > 0; off >>= 1) ss += __shfl_down(ss, off);
  if (lane == 0) z_sq[gw] = ss;
}

// codebook -> EH bf16 + e_sq (from fp32).  One wave per code.
__global__ __launch_bounds__(256) void prep_e(
    const float* __restrict__ cb, unsigned short* __restrict__ EH,
    float* __restrict__ e_sq) {
  int gw = (blockIdx.x * 256 + threadIdx.x) >> 6;
  int lane = threadIdx.x & 63;
  float4 v = *(const float4*)(cb + (size_t)gw * DIM + lane * 4);
  float x[4] = {v.x, v.y, v.z, v.w};
  unsigned short h[4];
  float ss = 0.f;
#pragma unroll
  for (int i = 0; i < 4; ++i) { ss += x[i] * x[i]; h[i] = f2bf(x[i]); }
  *(ushort4*)(EH + (size_t)gw * 256 + lane * 4) =
      make_ushort4(h[0], h[1], h[2], h[3]);
#pragma unroll
  for (int off = 32; off > 0; off >>= 1) ss += __shfl_down(ss, off);
  if (lane == 0) e_sq[gw] = ss;
}

// 128x128 tile bf16 MFMA "GEMM" over K=512 (hi|lo), fused per-row min1/min2.
// The two column-waves (wc=0/1) each cover 64 codes; their per-row results
// are merged through LDS with wc=0 as the single global writer (race fix).
__global__ __launch_bounds__(256) void dist_mfma(
    const unsigned short* __restrict__ A2, const unsigned short* __restrict__ EH,
    const float* __restrict__ e_sq,
    float* __restrict__ p1, int* __restrict__ pi, float* __restrict__ p2) {
  __shared__ __align__(16) unsigned short sA[128 * 32];
  __shared__ __align__(16) unsigned short sB[128 * 32];
  __shared__ float sm1[128];
  __shared__ int   smi[128];
  __shared__ float sm2[128];

  int wgid = blockIdx.x;
  int swz = (wgid & 7) * 1024 + (wgid >> 3);   // XCD-contiguous, bijective
  int rowp = swz >> 5, colp = swz & 31;
  int brow = rowp * 128, bcol = colp * 128;
  int tid = threadIdx.x;
  int lane = tid & 63, w = tid >> 6;
  int wr = w >> 1, wc = w & 1;
  int rl = lane & 15, k8 = lane >> 4;

  f32x4 acc[4][4] = {};

  const char* gA = (const char*)A2;
  const char* gB = (const char*)EH;
  int r0 = tid >> 2, seg = tid & 3;

  for (int ks = 0; ks < 16; ++ks) {
    __syncthreads();
    const char* ga0 = gA + (size_t)(brow + r0) * 1024 + ks * 64 + seg * 16;
    GLOAD(ga0, &sA[tid * 8]);
    GLOAD(ga0 + 64 * 1024, &sA[2048 + tid * 8]);
    const char* gb0 = gB + (size_t)(bcol + r0) * 512 + (ks & 7) * 64 + seg * 16;
    GLOAD(gb0, &sB[tid * 8]);
    GLOAD(gb0 + 64 * 512, &sB[2048 + tid * 8]);
    __syncthreads();

    short8 af[4], bfr[4];
#pragma unroll
    for (int mi = 0; mi < 4; ++mi)
      af[mi] = *(const short8*)&sA[(wr * 64 + mi * 16 + rl) * 32 + k8 * 8];
#pragma unroll
    for (int ni = 0; ni < 4; ++ni)
      bfr[ni] = *(const short8*)&sB[(wc * 64 + ni * 16 + rl) * 32 + k8 * 8];
#pragma unroll
    for (int mi = 0; mi < 4; ++mi)
#pragma unroll
      for (int ni = 0; ni < 4; ++ni)
        acc[mi][ni] = __builtin_amdgcn_mfma_f32_16x16x32_bf16(
            af[mi], bfr[ni], acc[mi][ni], 0, 0, 0);
  }

  // epilogue: q = e_sq - 2*dot ; per-row min1/min2 across this 128-code panel
  float e2[4];
#pragma unroll
  for (int ni = 0; ni < 4; ++ni) e2[ni] = e_sq[bcol + wc * 64 + ni * 16 + rl];

  for (int mi = 0; mi < 4; ++mi) {
    for (int j = 0; j < 4; ++j) {
      float m1 = 1e30f, m2 = 1e30f; int i1 = 0;
#pragma unroll
      for (int ni = 0; ni < 4; ++ni) {
        float q = e2[ni] - 2.0f * acc[mi][ni][j];
        if (q < m1) { m2 = m1; m1 = q; i1 = bcol + wc * 64 + ni * 16 + rl; }
        else if (q < m2) m2 = q;
      }
#pragma unroll
      for (int mk = 8; mk >= 1; mk >>= 1) {
        float v1 = __shfl_xor(m1, mk);
        int   vi = __shfl_xor(i1, mk);
        float v2 = __shfl_xor(m2, mk);
        float hi = fmaxf(m1, v1), lo2 = fminf(m2, v2);
        if (v1 < m1) { m1 = v1; i1 = vi; }
        else if (v1 == m1 && vi < i1) i1 = vi;
        m2 = fminf(hi, lo2);
      }
      int rowl = wr * 64 + mi * 16 + k8 * 4 + j;
      __syncthreads();
      if (wc == 1 && rl == 0) { sm1[rowl] = m1; smi[rowl] = i1; sm2[rowl] = m2; }
      __syncthreads();
      if (wc == 0 && rl == 0) {
        float v1 = sm1[rowl]; int vi = smi[rowl]; float v2 = sm2[rowl];
        float hi = fmaxf(m1, v1), lo2 = fminf(m2, v2);
        if (v1 < m1) { m1 = v1; i1 = vi; }   // wc=1 indices are larger; ties keep i1
        m2 = fminf(hi, lo2);
        size_t o = (size_t)colp * NROWS + (brow + rowl);
        p1[o] = m1; pi[o] = i1; p2[o] = m2;
      }
    }
  }
}

// merge 32 panel partials per row; flag near-ties for exact rescore
__global__ __launch_bounds__(256) void merge_kernel(
    const float* __restrict__ p1, const int* __restrict__ pi,
    const float* __restrict__ p2, int* __restrict__ idx,
    float* __restrict__ out_idxf, int* __restrict__ flist,
    int* __restrict__ flcnt) {
  int r = blockIdx.x * 256 + threadIdx.x;
  float m1 = 1e30f, m2 = 1e30f; int i1 = 0;
  for (int cb = 0; cb < 32; ++cb) {
    size_t o = (size_t)cb * NROWS + r;
    float v1 = p1[o]; int vi = pi[o]; float v2 = p2[o];
    float hi = fmaxf(m1, v1), lo2 = fminf(m2, v2);
    if (v1 < m1) { m1 = v1; i1 = vi; }
    else if (v1 == m1 && vi < i1) i1 = vi;
    m2 = fminf(hi, lo2);
  }
  idx[r] = i1;
  out_idxf[r] = (float)i1;
  if (m2 - m1 < MARGIN) { int p = atomicAdd(flcnt, 1); flist[p] = r; }
}

// exact fp32 rescore of flagged rows over all 4096 codes (8 rows per grab)
__global__ __launch_bounds__(256) void rescore_kernel(
    const float* __restrict__ z, const float* __restrict__ cb,
    const float* __restrict__ z_sq, const float* __restrict__ e_sq,
    const int* __restrict__ flist, const int* __restrict__ flcnt,
    int* __restrict__ idx, float* __restrict__ out_idxf) {
  __shared__ float zs[8][256];
  __shared__ float zq8[8];
  __shared__ int   rid[8];
  __shared__ float rmin[8][256];
  __shared__ int   rix[8][256];
  int t = threadIdx.x;
  int cnt = *flcnt;
  for (int base = blockIdx.x * 8; base < cnt; base += gridDim.x * 8) {
    int nr = min(8, cnt - base);
    __syncthreads();
    if (t < 8) {
      int rr = flist[base + ((t < nr) ? t : 0)];
      rid[t] = rr; zq8[t] = z_sq[rr];
    }
    __syncthreads();
    {
      int r8 = t >> 5, d0 = (t & 31) * 8;
      int row = rid[r8];
      float4 a = *(const float4*)(z + (size_t)row * DIM + d0);
      float4 b = *(const float4*)(z + (size_t)row * DIM + d0 + 4);
      *(float4*)&zs[r8][d0] = a;
      *(float4*)&zs[r8][d0 + 4] = b;
    }
    __syncthreads();
    float m1[8]; int i1[8];
#pragma unroll
    for (int r = 0; r < 8; ++r) { m1[r] = 1e30f; i1[r] = 0; }
    for (int cc = 0; cc < 16; ++cc) {
      int c = t * 16 + cc;
      float a0[8];
#pragma unroll
      for (int r = 0; r < 8; ++r) a0[r] = 0.f;
      for (int d = 0; d < DIM; d += 4) {
        float4 e = *(const float4*)(cb + (size_t)c * DIM + d);
#pragma unroll
        for (int r = 0; r < 8; ++r) {
          a0[r] = fmaf(zs[r][d], e.x, a0[r]);
          a0[r] = fmaf(zs[r][d + 1], e.y, a0[r]);
          a0[r] = fmaf(zs[r][d + 2], e.z, a0[r]);
          a0[r] = fmaf(zs[r][d + 3], e.w, a0[r]);
        }
      }
      float e2v = e_sq[c];
#pragma unroll
      for (int r = 0; r < 8; ++r) {
        float dv = (zq8[r] + e2v) - 2.0f * a0[r];
        if (dv < m1[r]) { m1[r] = dv; i1[r] = c; }
      }
    }
#pragma unroll
    for (int r = 0; r < 8; ++r) { rmin[r][t] = m1[r]; rix[r][t] = i1[r]; }
    __syncthreads();
    for (int s2 = 128; s2 >= 1; s2 >>= 1) {
      if (t < s2) {
#pragma unroll
        for (int r = 0; r < 8; ++r) {
          float a = rmin[r][t], b = rmin[r][t + s2];
          int ai = rix[r][t], bi = rix[r][t + s2];
          if (b < a || (b == a && bi < ai)) { rmin[r][t] = b; rix[r][t] = bi; }
        }
      }
      __syncthreads();
    }
    if (t < nr) {
      int rr = rid[t];
      idx[rr] = rix[t][0];
      out_idxf[rr] = (float)rix[t][0];
    }
  }
}

// z_q + straight-through + loss partial + counts.  One wave per row.
__global__ __launch_bounds__(256) void gather_kernel(
    const float* __restrict__ z, const float* __restrict__ cb,
    const int* __restrict__ idx, float* __restrict__ out_zq,
    int* __restrict__ counts, float* __restrict__ loss_acc) {
  int gw = (blockIdx.x * 256 + threadIdx.x) >> 6;
  int lane = threadIdx.x & 63;
  int k = idx[gw];
  float4 zq = *(const float4*)(cb + (size_t)k * DIM + lane * 4);
  float4 zv = *(const float4*)(z + (size_t)gw * DIM + lane * 4);
  float4 o;
  o.x = zv.x + (zq.x - zv.x);
  o.y = zv.y + (zq.y - zv.y);
  o.z = zv.z + (zq.z - zv.z);
  o.w = zv.w + (zq.w - zv.w);
  *(float4*)(out_zq + (size_t)gw * DIM + lane * 4) = o;
  float dx = zv.x - zq.x, dy = zv.y - zq.y, dz = zv.z - zq.z, dw = zv.w - zq.w;
  float s = dx * dx + dy * dy + dz * dz + dw * dw;
#pragma unroll
  for (int off = 32; off > 0; off >>= 1) s += __shfl_down(s, off);
  if (lane == 0) {
    atomicAdd(loss_acc, s);
    atomicAdd(&counts[k], 1);
  }
}

__global__ void prefix_kernel(const int* __restrict__ counts,
                              int* __restrict__ base, int* __restrict__ cursor) {
  __shared__ int part[256];
  __shared__ int pre[256];
  int t = threadIdx.x;
  int loc[16]; int s = 0;
#pragma unroll
  for (int i = 0; i < 16; ++i) { loc[i] = counts[t * 16 + i]; s += loc[i]; }
  part[t] = s;
  __syncthreads();
  if (t == 0) { int a = 0; for (int i = 0; i < 256; ++i) { pre[i] = a; a += part[i]; } }
  __syncthreads();
  int a = pre[t];
#pragma unroll
  for (int i = 0; i < 16; ++i) { base[t * 16 + i] = a; cursor[t * 16 + i] = a; a += loc[i]; }
}

__global__ void scatter_kernel(const int* __restrict__ idx,
                               int* __restrict__ cursor, int* __restrict__ list2) {
  int n = blockIdx.x * 256 + threadIdx.x;
  int k = idx[n];
  int p = atomicAdd(&cursor[k], 1);
  list2[p] = n;
}

// per-code: sum assigned z rows (inverted index), EMA update, outputs, entropy
__global__ __launch_bounds__(256) void finalize_codes(
    const float* __restrict__ ema_cs, const float* __restrict__ ema_es,
    const int* __restrict__ counts, const int* __restrict__ base,
    const int* __restrict__ list2, const float* __restrict__ z,
    float* __restrict__ out_cb, float* __restrict__ out_cs,
    float* __restrict__ out_es, float* __restrict__ ent_acc) {
  int gw = (blockIdx.x * 256 + threadIdx.x) >> 6;
  int lane = threadIdx.x & 63;
  int cnt = counts[gw], b0 = base[gw];
  float sx = 0.f, sy = 0.f, sz = 0.f, sw = 0.f;
  for (int i = 0; i < cnt; ++i) {
    int n = list2[b0 + i];
    float4 v = *(const float4*)(z + (size_t)n * DIM + lane * 4);
    sx += v.x; sy += v.y; sz += v.z; sw += v.w;
  }
  const float omd = 1.0f - DECAYF;
  float cntf = (float)cnt;
  float ncs = ema_cs[gw] * DECAYF + omd * cntf;
  float nden = ncs + 0.04096f;
  if (lane == 0) {
    out_cs[gw] = ncs;
    float p = cntf * (1.0f / (float)NROWS);
    atomicAdd(ent_acc, -p * logf(p + 1e-12f));
  }
  size_t o = (size_t)gw * DIM + lane * 4;
  float4 em = *(const float4*)(ema_es + o);
  float nex = em.x * DECAYF + omd * sx;
  float ney = em.y * DECAYF + omd * sy;
  float nez = em.z * DECAYF + omd * sz;
  float new_ = em.w * DECAYF + omd * sw;
  *(float2*)(out_es + o) = make_float2(nex, ney);
  *(float2*)(out_es + o + 2) = make_float2(nez, new_);
  *(float2*)(out_cb + o) = make_float2(nex / nden, ney / nden);
  *(float2*)(out_cb + o + 2) = make_float2(nez / nden, new_ / nden);
}

__global__ void finalize_scalars(const float* __restrict__ loss_acc,
                                 const float* __restrict__ ent_acc,
                                 float* __restrict__ out_loss,
                                 float* __restrict__ out_ppl) {
  if (threadIdx.x == 0 && blockIdx.x == 0) {
    out_loss[0] = 0.25f * (loss_acc[0] / 8388608.0f);
    out_ppl[0] = expf(ent_acc[0]);
  }
}

extern "C" void kernel_launch(void* const* d_in, const int* in_sizes, int n_in,
                              void* d_out, int out_size, void* d_ws, size_t ws_size,
                              hipStream_t stream) {
  (void)in_sizes; (void)n_in; (void)out_size; (void)ws_size;
  const float* z      = (const float*)d_in[0];
  const float* cb     = (const float*)d_in[1];
  const float* ema_cs = (const float*)d_in[2];
  const float* ema_es = (const float*)d_in[3];
  float* out = (float*)d_out;
  char*  ws  = (char*)d_ws;

  unsigned short* A2 = (unsigned short*)(ws + WS_A2);
  unsigned short* EH = (unsigned short*)(ws + WS_EH);
  float* z_sq  = (float*)(ws + WS_ZSQ);
  float* e_sq  = (float*)(ws + WS_ESQ);
  float* p1    = (float*)(ws + WS_P1);
  int*   pi    = (int*)(ws + WS_PI);
  float* p2    = (float*)(ws + WS_P2);
  int*   idx   = (int*)(ws + WS_IDX);
  int*   flist = (int*)(ws + WS_FLIST);
  int*   list2 = (int*)(ws + WS_LIST2);
  int*   base  = (int*)(ws + WS_BASE);
  int*   counts = (int*)(ws + WS_COUNTS);
  int*   cursor = (int*)(ws + WS_CURSOR);
  int*   flcnt  = (int*)(ws + WS_FLCNT);
  float* loss_p = (float*)(ws + WS_LOSS);
  float* ent_p  = (float*)(ws + WS_ENT);

  hipMemsetAsync(ws + WS_ZERO, 0, WS_ZEROLEN, stream);

  prep_z<<<NROWS / 4, 256, 0, stream>>>(z, A2, z_sq);
  prep_e<<<KCB / 4, 256, 0, stream>>>(cb, EH, e_sq);
  dist_mfma<<<(NROWS / 128) * (KCB / 128), 256, 0, stream>>>(A2, EH, e_sq,
                                                             p1, pi, p2);
  merge_kernel<<<NROWS / 256, 256, 0, stream>>>(p1, pi, p2, idx,
                                                out + OUT_IDX, flist, flcnt);
  rescore_kernel<<<512, 256, 0, stream>>>(z, cb, z_sq, e_sq, flist, flcnt,
                                          idx, out + OUT_IDX);
  gather_kernel<<<NROWS / 4, 256, 0, stream>>>(z, cb, idx, out + OUT_ZQ,
                                               counts, loss_p);
  prefix_kernel<<<1, 256, 0, stream>>>(counts, base, cursor);
  scatter_kernel<<<NROWS / 256, 256, 0, stream>>>(idx, cursor, list2);
  finalize_codes<<<KCB / 4, 256, 0, stream>>>(ema_cs, ema_es, counts, base,
                                              list2, z, out + OUT_CB,
                                              out + OUT_CS, out + OUT_ES, ent_p);
  finalize_scalars<<<1, 64, 0, stream>>>(loss_p, ent_p, out + OUT_LOSS,
                                         out + OUT_PPL);
}

// Round 4
// 1026.182 us; speedup vs baseline: 3.5682x; 3.5682x over previous
//
#include <hip/hip_runtime.h>
#include <hip/hip_bf16.h>
#include <math.h>

#define DIM    256
#define KCB    4096
#define NROWS  32768
#define DECAYF 0.99f
#define MARGIN 0.03f

// ---- d_out offsets (in floats) ----
#define OUT_ZQ   0
#define OUT_IDX  8388608
#define OUT_LOSS 8421376
#define OUT_PPL  8421377
#define OUT_CB   8421378
#define OUT_CS   9469954
#define OUT_ES   9474050

// ---- d_ws offsets (bytes) ----
#define WS_A2      0u            // [32768][512] bf16 (hi|lo)  32 MB
#define WS_EH      33554432u     // [4096][256] bf16            2 MB
#define WS_ZSQ     35651584u     // N f32
#define WS_ESQ     35782656u     // K f32
#define WS_P1      35799040u     // [32][32768] f32 partial min1
#define WS_PI      39993344u     // [32][32768] i32 partial idx1
#define WS_P2      44187648u     // [32][32768] f32 partial min2
#define WS_IDX     48381952u     // N i32 final idx
#define WS_FLIST   48513024u     // N i32 flagged rows
#define WS_LIST2   48644096u     // N i32 inverted index
#define WS_BASE    48775168u     // K i32
#define WS_ZERO    48791552u     // zeroed region start
#define WS_COUNTS  48791552u     // K i32
#define WS_CURSOR  48807936u     // K i32
#define WS_FLCNT   48824320u
#define WS_LOSS    48824324u
#define WS_ENT     48824328u
#define WS_ZEROLEN 32800u

typedef __attribute__((ext_vector_type(8))) short short8;
typedef __attribute__((ext_vector_type(4))) float f32x4;

#define GLOAD(g, l) __builtin_amdgcn_global_load_lds( \
    (const __attribute__((address_space(1))) unsigned int*)(g), \
    (__attribute__((address_space(3))) unsigned int*)(l), 16, 0, 0)

__device__ __forceinline__ unsigned short f2bf(float x) {
  __hip_bfloat16 h = __float2bfloat16(x);
  return *reinterpret_cast<unsigned short*>(&h);
}
__device__ __forceinline__ float bf2f(unsigned short u) {
  unsigned int v = ((unsigned int)u) << 16;
  return *reinterpret_cast<float*>(&v);
}

// z -> A2 = [z_hi | z_lo] bf16, plus z_sq.  One wave per row.
__global__ __launch_bounds__(256) void prep_z(
    const float* __restrict__ z, unsigned short* __restrict__ A2,
    float* __restrict__ z_sq) {
  int gw = (blockIdx.x * 256 + threadIdx.x) >> 6;
  int lane = threadIdx.x & 63;
  float4 v = *(const float4*)(z + (size_t)gw * DIM + lane * 4);
  float x[4] = {v.x, v.y, v.z, v.w};
  unsigned short h[4], l[4];
  float ss = 0.f;
#pragma unroll
  for (int i = 0; i < 4; ++i) {
    ss += x[i] * x[i];
    h[i] = f2bf(x[i]);
    l[i] = f2bf(x[i] - bf2f(h[i]));
  }
  size_t o = (size_t)gw * 512 + lane * 4;
  *(ushort4*)(A2 + o) = make_ushort4(h[0], h[1], h[2], h[3]);
  *(ushort4*)(A2 + o + 256) = make_ushort4(l[0], l[1], l[2], l[3]);
#pragma unroll
  for (int off = 32; off > 0; off >>= 1) ss += __shfl_down(ss, off);
  if (lane == 0) z_sq[gw] = ss;
}

// codebook -> EH bf16 + e_sq (from fp32).  One wave per code.
__global__ __launch_bounds__(256) void prep_e(
    const float* __restrict__ cb, unsigned short* __restrict__ EH,
    float* __restrict__ e_sq) {
  int gw = (blockIdx.x * 256 + threadIdx.x) >> 6;
  int lane = threadIdx.x & 63;
  float4 v = *(const float4*)(cb + (size_t)gw * DIM + lane * 4);
  float x[4] = {v.x, v.y, v.z, v.w};
  unsigned short h[4];
  float ss = 0.f;
#pragma unroll
  for (int i = 0; i < 4; ++i) { ss += x[i] * x[i]; h[i] = f2bf(x[i]); }
  *(ushort4*)(EH + (size_t)gw * 256 + lane * 4) =
      make_ushort4(h[0], h[1], h[2], h[3]);
#pragma unroll
  for (int off = 32; off > 0; off >>= 1) ss += __shfl_down(ss, off);
  if (lane == 0) e_sq[gw] = ss;
}

// 128x128 tile bf16 MFMA "GEMM" over K=512 (hi|lo), fused per-row min1/min2.
// Epilogue: fully unrolled (acc must stay in registers — runtime indexing
// spills the whole accumulator to scratch, rule #20), single barrier, LDS
// merge of the two column-wave halves, tid<128 does the global write.
__global__ __launch_bounds__(256) void dist_mfma(
    const unsigned short* __restrict__ A2, const unsigned short* __restrict__ EH,
    const float* __restrict__ e_sq,
    float* __restrict__ p1, int* __restrict__ pi, float* __restrict__ p2) {
  __shared__ __align__(16) unsigned short sA[128 * 32];
  __shared__ __align__(16) unsigned short sB[128 * 32];
  __shared__ float sm1[2][128];
  __shared__ int   smi[2][128];
  __shared__ float sm2[2][128];

  int wgid = blockIdx.x;
  int swz = (wgid & 7) * 1024 + (wgid >> 3);   // XCD-contiguous, bijective
  int rowp = swz >> 5, colp = swz & 31;
  int brow = rowp * 128, bcol = colp * 128;
  int tid = threadIdx.x;
  int lane = tid & 63, w = tid >> 6;
  int wr = w >> 1, wc = w & 1;
  int rl = lane & 15, k8 = lane >> 4;

  f32x4 acc[4][4] = {};

  const char* gA = (const char*)A2;
  const char* gB = (const char*)EH;
  int r0 = tid >> 2, seg = tid & 3;

  for (int ks = 0; ks < 16; ++ks) {
    __syncthreads();
    const char* ga0 = gA + (size_t)(brow + r0) * 1024 + ks * 64 + seg * 16;
    GLOAD(ga0, &sA[tid * 8]);
    GLOAD(ga0 + 64 * 1024, &sA[2048 + tid * 8]);
    const char* gb0 = gB + (size_t)(bcol + r0) * 512 + (ks & 7) * 64 + seg * 16;
    GLOAD(gb0, &sB[tid * 8]);
    GLOAD(gb0 + 64 * 512, &sB[2048 + tid * 8]);
    __syncthreads();

    short8 af[4], bfr[4];
#pragma unroll
    for (int mi = 0; mi < 4; ++mi)
      af[mi] = *(const short8*)&sA[(wr * 64 + mi * 16 + rl) * 32 + k8 * 8];
#pragma unroll
    for (int ni = 0; ni < 4; ++ni)
      bfr[ni] = *(const short8*)&sB[(wc * 64 + ni * 16 + rl) * 32 + k8 * 8];
#pragma unroll
    for (int mi = 0; mi < 4; ++mi)
#pragma unroll
      for (int ni = 0; ni < 4; ++ni)
        acc[mi][ni] = __builtin_amdgcn_mfma_f32_16x16x32_bf16(
            af[mi], bfr[ni], acc[mi][ni], 0, 0, 0);
  }

  // per-row min1/min2 across this wave's 64-code half (all indices static)
  float e2[4];
#pragma unroll
  for (int ni = 0; ni < 4; ++ni) e2[ni] = e_sq[bcol + wc * 64 + ni * 16 + rl];

#pragma unroll
  for (int mi = 0; mi < 4; ++mi) {
#pragma unroll
    for (int j = 0; j < 4; ++j) {
      float m1 = 1e30f, m2 = 1e30f; int i1 = 0;
#pragma unroll
      for (int ni = 0; ni < 4; ++ni) {
        float q = e2[ni] - 2.0f * acc[mi][ni][j];
        if (q < m1) { m2 = m1; m1 = q; i1 = bcol + wc * 64 + ni * 16 + rl; }
        else if (q < m2) m2 = q;
      }
#pragma unroll
      for (int mk = 8; mk >= 1; mk >>= 1) {
        float v1 = __shfl_xor(m1, mk);
        int   vi = __shfl_xor(i1, mk);
        float v2 = __shfl_xor(m2, mk);
        float hi = fmaxf(m1, v1), lo2 = fminf(m2, v2);
        if (v1 < m1) { m1 = v1; i1 = vi; }
        else if (v1 == m1 && vi < i1) i1 = vi;
        m2 = fminf(hi, lo2);
      }
      if (rl == 0) {
        int rowl = wr * 64 + mi * 16 + k8 * 4 + j;
        sm1[wc][rowl] = m1; smi[wc][rowl] = i1; sm2[wc][rowl] = m2;
      }
    }
  }
  __syncthreads();
  if (tid < 128) {
    float a1 = sm1[0][tid]; int ai = smi[0][tid]; float a2 = sm2[0][tid];
    float b1 = sm1[1][tid]; int bi = smi[1][tid]; float b2 = sm2[1][tid];
    float m1, m2; int i1;
    if (b1 < a1) { m1 = b1; i1 = bi; m2 = fminf(a1, b2); }
    else         { m1 = a1; i1 = ai; m2 = fminf(b1, a2); }  // ties keep smaller idx
    size_t o = (size_t)colp * NROWS + (brow + tid);
    p1[o] = m1; pi[o] = i1; p2[o] = m2;
  }
}

// merge 32 panel partials per row; flag near-ties for exact rescore
__global__ __launch_bounds__(256) void merge_kernel(
    const float* __restrict__ p1, const int* __restrict__ pi,
    const float* __restrict__ p2, int* __restrict__ idx,
    float* __restrict__ out_idxf, int* __restrict__ flist,
    int* __restrict__ flcnt) {
  int r = blockIdx.x * 256 + threadIdx.x;
  float m1 = 1e30f, m2 = 1e30f; int i1 = 0;
  for (int cb = 0; cb < 32; ++cb) {
    size_t o = (size_t)cb * NROWS + r;
    float v1 = p1[o]; int vi = pi[o]; float v2 = p2[o];
    float hi = fmaxf(m1, v1), lo2 = fminf(m2, v2);
    if (v1 < m1) { m1 = v1; i1 = vi; }
    else if (v1 == m1 && vi < i1) i1 = vi;
    m2 = fminf(hi, lo2);
  }
  idx[r] = i1;
  out_idxf[r] = (float)i1;
  if (m2 - m1 < MARGIN) { int p = atomicAdd(flcnt, 1); flist[p] = r; }
}

// exact fp32 rescore of flagged rows over all 4096 codes (8 rows per grab)
__global__ __launch_bounds__(256) void rescore_kernel(
    const float* __restrict__ z, const float* __restrict__ cb,
    const float* __restrict__ z_sq, const float* __restrict__ e_sq,
    const int* __restrict__ flist, const int* __restrict__ flcnt,
    int* __restrict__ idx, float* __restrict__ out_idxf) {
  __shared__ float zs[8][256];
  __shared__ float zq8[8];
  __shared__ int   rid[8];
  __shared__ float rmin[8][256];
  __shared__ int   rix[8][256];
  int t = threadIdx.x;
  int cnt = *flcnt;
  for (int base = blockIdx.x * 8; base < cnt; base += gridDim.x * 8) {
    int nr = min(8, cnt - base);
    __syncthreads();
    if (t < 8) {
      int rr = flist[base + ((t < nr) ? t : 0)];
      rid[t] = rr; zq8[t] = z_sq[rr];
    }
    __syncthreads();
    {
      int r8 = t >> 5, d0 = (t & 31) * 8;
      int row = rid[r8];
      float4 a = *(const float4*)(z + (size_t)row * DIM + d0);
      float4 b = *(const float4*)(z + (size_t)row * DIM + d0 + 4);
      *(float4*)&zs[r8][d0] = a;
      *(float4*)&zs[r8][d0 + 4] = b;
    }
    __syncthreads();
    float m1[8]; int i1[8];
#pragma unroll
    for (int r = 0; r < 8; ++r) { m1[r] = 1e30f; i1[r] = 0; }
    for (int cc = 0; cc < 16; ++cc) {
      int c = t * 16 + cc;
      float a0[8];
#pragma unroll
      for (int r = 0; r < 8; ++r) a0[r] = 0.f;
      for (int d = 0; d < DIM; d += 4) {
        float4 e = *(const float4*)(cb + (size_t)c * DIM + d);
#pragma unroll
        for (int r = 0; r < 8; ++r) {
          a0[r] = fmaf(zs[r][d], e.x, a0[r]);
          a0[r] = fmaf(zs[r][d + 1], e.y, a0[r]);
          a0[r] = fmaf(zs[r][d + 2], e.z, a0[r]);
          a0[r] = fmaf(zs[r][d + 3], e.w, a0[r]);
        }
      }
      float e2v = e_sq[c];
#pragma unroll
      for (int r = 0; r < 8; ++r) {
        float dv = (zq8[r] + e2v) - 2.0f * a0[r];
        if (dv < m1[r]) { m1[r] = dv; i1[r] = c; }
      }
    }
#pragma unroll
    for (int r = 0; r < 8; ++r) { rmin[r][t] = m1[r]; rix[r][t] = i1[r]; }
    __syncthreads();
    for (int s2 = 128; s2 >= 1; s2 >>= 1) {
      if (t < s2) {
#pragma unroll
        for (int r = 0; r < 8; ++r) {
          float a = rmin[r][t], b = rmin[r][t + s2];
          int ai = rix[r][t], bi = rix[r][t + s2];
          if (b < a || (b == a && bi < ai)) { rmin[r][t] = b; rix[r][t] = bi; }
        }
      }
      __syncthreads();
    }
    if (t < nr) {
      int rr = rid[t];
      idx[rr] = rix[t][0];
      out_idxf[rr] = (float)rix[t][0];
    }
  }
}

// z_q + straight-through + loss partial + counts.  One wave per row.
__global__ __launch_bounds__(256) void gather_kernel(
    const float* __restrict__ z, const float* __restrict__ cb,
    const int* __restrict__ idx, float* __restrict__ out_zq,
    int* __restrict__ counts, float* __restrict__ loss_acc) {
  int gw = (blockIdx.x * 256 + threadIdx.x) >> 6;
  int lane = threadIdx.x & 63;
  int k = idx[gw];
  float4 zq = *(const float4*)(cb + (size_t)k * DIM + lane * 4);
  float4 zv = *(const float4*)(z + (size_t)gw * DIM + lane * 4);
  float4 o;
  o.x = zv.x + (zq.x - zv.x);
  o.y = zv.y + (zq.y - zv.y);
  o.z = zv.z + (zq.z - zv.z);
  o.w = zv.w + (zq.w - zv.w);
  *(float4*)(out_zq + (size_t)gw * DIM + lane * 4) = o;
  float dx = zv.x - zq.x, dy = zv.y - zq.y, dz = zv.z - zq.z, dw = zv.w - zq.w;
  float s = dx * dx + dy * dy + dz * dz + dw * dw;
#pragma unroll
  for (int off = 32; off > 0; off >>= 1) s += __shfl_down(s, off);
  if (lane == 0) {
    atomicAdd(loss_acc, s);
    atomicAdd(&counts[k], 1);
  }
}

__global__ void prefix_kernel(const int* __restrict__ counts,
                              int* __restrict__ base, int* __restrict__ cursor) {
  __shared__ int part[256];
  __shared__ int pre[256];
  int t = threadIdx.x;
  int loc[16]; int s = 0;
#pragma unroll
  for (int i = 0; i < 16; ++i) { loc[i] = counts[t * 16 + i]; s += loc[i]; }
  part[t] = s;
  __syncthreads();
  if (t == 0) { int a = 0; for (int i = 0; i < 256; ++i) { pre[i] = a; a += part[i]; } }
  __syncthreads();
  int a = pre[t];
#pragma unroll
  for (int i = 0; i < 16; ++i) { base[t * 16 + i] = a; cursor[t * 16 + i] = a; a += loc[i]; }
}

__global__ void scatter_kernel(const int* __restrict__ idx,
                               int* __restrict__ cursor, int* __restrict__ list2) {
  int n = blockIdx.x * 256 + threadIdx.x;
  int k = idx[n];
  int p = atomicAdd(&cursor[k], 1);
  list2[p] = n;
}

// per-code: sum assigned z rows (inverted index), EMA update, outputs, entropy
__global__ __launch_bounds__(256) void finalize_codes(
    const float* __restrict__ ema_cs, const float* __restrict__ ema_es,
    const int* __restrict__ counts, const int* __restrict__ base,
    const int* __restrict__ list2, const float* __restrict__ z,
    float* __restrict__ out_cb, float* __restrict__ out_cs,
    float* __restrict__ out_es, float* __restrict__ ent_acc) {
  int gw = (blockIdx.x * 256 + threadIdx.x) >> 6;
  int lane = threadIdx.x & 63;
  int cnt = counts[gw], b0 = base[gw];
  float sx = 0.f, sy = 0.f, sz = 0.f, sw = 0.f;
  for (int i = 0; i < cnt; ++i) {
    int n = list2[b0 + i];
    float4 v = *(const float4*)(z + (size_t)n * DIM + lane * 4);
    sx += v.x; sy += v.y; sz += v.z; sw += v.w;
  }
  const float omd = 1.0f - DECAYF;
  float cntf = (float)cnt;
  float ncs = ema_cs[gw] * DECAYF + omd * cntf;
  float nden = ncs + 0.04096f;
  if (lane == 0) {
    out_cs[gw] = ncs;
    float p = cntf * (1.0f / (float)NROWS);
    atomicAdd(ent_acc, -p * logf(p + 1e-12f));
  }
  size_t o = (size_t)gw * DIM + lane * 4;
  float4 em = *(const float4*)(ema_es + o);
  float nex = em.x * DECAYF + omd * sx;
  float ney = em.y * DECAYF + omd * sy;
  float nez = em.z * DECAYF + omd * sz;
  float new_ = em.w * DECAYF + omd * sw;
  *(float2*)(out_es + o) = make_float2(nex, ney);
  *(float2*)(out_es + o + 2) = make_float2(nez, new_);
  *(float2*)(out_cb + o) = make_float2(nex / nden, ney / nden);
  *(float2*)(out_cb + o + 2) = make_float2(nez / nden, new_ / nden);
}

__global__ void finalize_scalars(const float* __restrict__ loss_acc,
                                 const float* __restrict__ ent_acc,
                                 float* __restrict__ out_loss,
                                 float* __restrict__ out_ppl) {
  if (threadIdx.x == 0 && blockIdx.x == 0) {
    out_loss[0] = 0.25f * (loss_acc[0] / 8388608.0f);
    out_ppl[0] = expf(ent_acc[0]);
  }
}

extern "C" void kernel_launch(void* const* d_in, const int* in_sizes, int n_in,
                              void* d_out, int out_size, void* d_ws, size_t ws_size,
                              hipStream_t stream) {
  (void)in_sizes; (void)n_in; (void)out_size; (void)ws_size;
  const float* z      = (const float*)d_in[0];
  const float* cb     = (const float*)d_in[1];
  const float* ema_cs = (const float*)d_in[2];
  const float* ema_es = (const float*)d_in[3];
  float* out = (float*)d_out;
  char*  ws  = (char*)d_ws;

  unsigned short* A2 = (unsigned short*)(ws + WS_A2);
  unsigned short* EH = (unsigned short*)(ws + WS_EH);
  float* z_sq  = (float*)(ws + WS_ZSQ);
  float* e_sq  = (float*)(ws + WS_ESQ);
  float* p1    = (float*)(ws + WS_P1);
  int*   pi    = (int*)(ws + WS_PI);
  float* p2    = (float*)(ws + WS_P2);
  int*   idx   = (int*)(ws + WS_IDX);
  int*   flist = (int*)(ws + WS_FLIST);
  int*   list2 = (int*)(ws + WS_LIST2);
  int*   base  = (int*)(ws + WS_BASE);
  int*   counts = (int*)(ws + WS_COUNTS);
  int*   cursor = (int*)(ws + WS_CURSOR);
  int*   flcnt  = (int*)(ws + WS_FLCNT);
  float* loss_p = (float*)(ws + WS_LOSS);
  float* ent_p  = (float*)(ws + WS_ENT);

  hipMemsetAsync(ws + WS_ZERO, 0, WS_ZEROLEN, stream);

  prep_z<<<NROWS / 4, 256, 0, stream>>>(z, A2, z_sq);
  prep_e<<<KCB / 4, 256, 0, stream>>>(cb, EH, e_sq);
  dist_mfma<<<(NROWS / 128) * (KCB / 128), 256, 0, stream>>>(A2, EH, e_sq,
                                                             p1, pi, p2);
  merge_kernel<<<NROWS / 256, 256, 0, stream>>>(p1, pi, p2, idx,
                                                out + OUT_IDX, flist, flcnt);
  rescore_kernel<<<512, 256, 0, stream>>>(z, cb, z_sq, e_sq, flist, flcnt,
                                          idx, out + OUT_IDX);
  gather_kernel<<<NROWS / 4, 256, 0, stream>>>(z, cb, idx, out + OUT_ZQ,
                                               counts, loss_p);
  prefix_kernel<<<1, 256, 0, stream>>>(counts, base, cursor);
  scatter_kernel<<<NROWS / 256, 256, 0, stream>>>(idx, cursor, list2);
  finalize_codes<<<KCB / 4, 256, 0, stream>>>(ema_cs, ema_es, counts, base,
                                              list2, z, out + OUT_CB,
                                              out + OUT_CS, out + OUT_ES, ent_p);
  finalize_scalars<<<1, 64, 0, stream>>>(loss_p, ent_p, out + OUT_LOSS,
                                         out + OUT_PPL);
}

// Round 5
// 589.198 us; speedup vs baseline: 6.2145x; 1.7417x over previous
//
#include <hip/hip_runtime.h>
#include <hip/hip_bf16.h>
#include <math.h>

#define DIM    256
#define KCB    4096
#define NROWS  32768
#define DECAYF 0.99f
#define MARGIN 0.03f

// ---- d_out offsets (in floats) ----
#define OUT_ZQ   0
#define OUT_IDX  8388608
#define OUT_LOSS 8421376
#define OUT_PPL  8421377
#define OUT_CB   8421378
#define OUT_CS   9469954
#define OUT_ES   9474050

// ---- d_ws offsets (bytes) ----
#define WS_A2      0u            // [32768][512] bf16 (hi|lo)  32 MB
#define WS_EH      33554432u     // [4096][256] bf16            2 MB
#define WS_ZSQ     35651584u     // N f32
#define WS_ESQ     35782656u     // K f32
#define WS_P1      35799040u     // [32][32768] f32 partial min1
#define WS_PI      39993344u     // [32][32768] i32 partial idx1
#define WS_P2      44187648u     // [32][32768] f32 partial min2 (dead after
                                 // merge_kernel -> reused for loss partials)
#define WS_IDX     48381952u     // N i32 final idx
#define WS_FLIST   48513024u     // N i32 flagged rows
#define WS_LIST2   48644096u     // N i32 inverted index
#define WS_BASE    48775168u     // K i32
#define WS_ZERO    48791552u     // zeroed region start
#define WS_COUNTS  48791552u     // K i32
#define WS_CURSOR  48807936u     // K i32
#define WS_FLCNT   48824320u
#define WS_ZEROLEN 32772u

typedef __attribute__((ext_vector_type(8))) short short8;
typedef __attribute__((ext_vector_type(4))) float f32x4;

#define GLOAD(g, l) __builtin_amdgcn_global_load_lds( \
    (const __attribute__((address_space(1))) unsigned int*)(g), \
    (__attribute__((address_space(3))) unsigned int*)(l), 16, 0, 0)

__device__ __forceinline__ unsigned short f2bf(float x) {
  __hip_bfloat16 h = __float2bfloat16(x);
  return *reinterpret_cast<unsigned short*>(&h);
}
__device__ __forceinline__ float bf2f(unsigned short u) {
  unsigned int v = ((unsigned int)u) << 16;
  return *reinterpret_cast<float*>(&v);
}

// z -> A2 = [z_hi | z_lo] bf16, plus z_sq.  One wave per row.
__global__ __launch_bounds__(256) void prep_z(
    const float* __restrict__ z, unsigned short* __restrict__ A2,
    float* __restrict__ z_sq) {
  int gw = (blockIdx.x * 256 + threadIdx.x) >> 6;
  int lane = threadIdx.x & 63;
  float4 v = *(const float4*)(z + (size_t)gw * DIM + lane * 4);
  float x[4] = {v.x, v.y, v.z, v.w};
  unsigned short h[4], l[4];
  float ss = 0.f;
#pragma unroll
  for (int i = 0; i < 4; ++i) {
    ss += x[i] * x[i];
    h[i] = f2bf(x[i]);
    l[i] = f2bf(x[i] - bf2f(h[i]));
  }
  size_t o = (size_t)gw * 512 + lane * 4;
  *(ushort4*)(A2 + o) = make_ushort4(h[0], h[1], h[2], h[3]);
  *(ushort4*)(A2 + o + 256) = make_ushort4(l[0], l[1], l[2], l[3]);
#pragma unroll
  for (int off = 32; off > 0; off >>= 1) ss += __shfl_down(ss, off);
  if (lane == 0) z_sq[gw] = ss;
}

// codebook -> EH bf16 + e_sq (from fp32).  One wave per code.
__global__ __launch_bounds__(256) void prep_e(
    const float* __restrict__ cb, unsigned short* __restrict__ EH,
    float* __restrict__ e_sq) {
  int gw = (blockIdx.x * 256 + threadIdx.x) >> 6;
  int lane = threadIdx.x & 63;
  float4 v = *(const float4*)(cb + (size_t)gw * DIM + lane * 4);
  float x[4] = {v.x, v.y, v.z, v.w};
  unsigned short h[4];
  float ss = 0.f;
#pragma unroll
  for (int i = 0; i < 4; ++i) { ss += x[i] * x[i]; h[i] = f2bf(x[i]); }
  *(ushort4*)(EH + (size_t)gw * 256 + lane * 4) =
      make_ushort4(h[0], h[1], h[2], h[3]);
#pragma unroll
  for (int off = 32; off > 0; off >>= 1) ss += __shfl_down(ss, off);
  if (lane == 0) e_sq[gw] = ss;
}

// 128x128 tile bf16 MFMA "GEMM" over K=512 (hi|lo), fused per-row min1/min2.
// Epilogue: fully unrolled (acc must stay in registers — runtime indexing
// spills the whole accumulator to scratch, rule #20), single barrier, LDS
// merge of the two column-wave halves, tid<128 does the global write.
__global__ __launch_bounds__(256) void dist_mfma(
    const unsigned short* __restrict__ A2, const unsigned short* __restrict__ EH,
    const float* __restrict__ e_sq,
    float* __restrict__ p1, int* __restrict__ pi, float* __restrict__ p2) {
  __shared__ __align__(16) unsigned short sA[128 * 32];
  __shared__ __align__(16) unsigned short sB[128 * 32];
  __shared__ float sm1[2][128];
  __shared__ int   smi[2][128];
  __shared__ float sm2[2][128];

  int wgid = blockIdx.x;
  int swz = (wgid & 7) * 1024 + (wgid >> 3);   // XCD-contiguous, bijective
  int rowp = swz >> 5, colp = swz & 31;
  int brow = rowp * 128, bcol = colp * 128;
  int tid = threadIdx.x;
  int lane = tid & 63, w = tid >> 6;
  int wr = w >> 1, wc = w & 1;
  int rl = lane & 15, k8 = lane >> 4;

  f32x4 acc[4][4] = {};

  const char* gA = (const char*)A2;
  const char* gB = (const char*)EH;
  int r0 = tid >> 2, seg = tid & 3;

  for (int ks = 0; ks < 16; ++ks) {
    __syncthreads();
    const char* ga0 = gA + (size_t)(brow + r0) * 1024 + ks * 64 + seg * 16;
    GLOAD(ga0, &sA[tid * 8]);
    GLOAD(ga0 + 64 * 1024, &sA[2048 + tid * 8]);
    const char* gb0 = gB + (size_t)(bcol + r0) * 512 + (ks & 7) * 64 + seg * 16;
    GLOAD(gb0, &sB[tid * 8]);
    GLOAD(gb0 + 64 * 512, &sB[2048 + tid * 8]);
    __syncthreads();

    short8 af[4], bfr[4];
#pragma unroll
    for (int mi = 0; mi < 4; ++mi)
      af[mi] = *(const short8*)&sA[(wr * 64 + mi * 16 + rl) * 32 + k8 * 8];
#pragma unroll
    for (int ni = 0; ni < 4; ++ni)
      bfr[ni] = *(const short8*)&sB[(wc * 64 + ni * 16 + rl) * 32 + k8 * 8];
#pragma unroll
    for (int mi = 0; mi < 4; ++mi)
#pragma unroll
      for (int ni = 0; ni < 4; ++ni)
        acc[mi][ni] = __builtin_amdgcn_mfma_f32_16x16x32_bf16(
            af[mi], bfr[ni], acc[mi][ni], 0, 0, 0);
  }

  // per-row min1/min2 across this wave's 64-code half (all indices static)
  float e2[4];
#pragma unroll
  for (int ni = 0; ni < 4; ++ni) e2[ni] = e_sq[bcol + wc * 64 + ni * 16 + rl];

#pragma unroll
  for (int mi = 0; mi < 4; ++mi) {
#pragma unroll
    for (int j = 0; j < 4; ++j) {
      float m1 = 1e30f, m2 = 1e30f; int i1 = 0;
#pragma unroll
      for (int ni = 0; ni < 4; ++ni) {
        float q = e2[ni] - 2.0f * acc[mi][ni][j];
        if (q < m1) { m2 = m1; m1 = q; i1 = bcol + wc * 64 + ni * 16 + rl; }
        else if (q < m2) m2 = q;
      }
#pragma unroll
      for (int mk = 8; mk >= 1; mk >>= 1) {
        float v1 = __shfl_xor(m1, mk);
        int   vi = __shfl_xor(i1, mk);
        float v2 = __shfl_xor(m2, mk);
        float hi = fmaxf(m1, v1), lo2 = fminf(m2, v2);
        if (v1 < m1) { m1 = v1; i1 = vi; }
        else if (v1 == m1 && vi < i1) i1 = vi;
        m2 = fminf(hi, lo2);
      }
      if (rl == 0) {
        int rowl = wr * 64 + mi * 16 + k8 * 4 + j;
        sm1[wc][rowl] = m1; smi[wc][rowl] = i1; sm2[wc][rowl] = m2;
      }
    }
  }
  __syncthreads();
  if (tid < 128) {
    float a1 = sm1[0][tid]; int ai = smi[0][tid]; float a2 = sm2[0][tid];
    float b1 = sm1[1][tid]; int bi = smi[1][tid]; float b2 = sm2[1][tid];
    float m1, m2; int i1;
    if (b1 < a1) { m1 = b1; i1 = bi; m2 = fminf(a1, b2); }
    else         { m1 = a1; i1 = ai; m2 = fminf(b1, a2); }  // ties keep smaller idx
    size_t o = (size_t)colp * NROWS + (brow + tid);
    p1[o] = m1; pi[o] = i1; p2[o] = m2;
  }
}

// merge 32 panel partials per row; flag near-ties for exact rescore
__global__ __launch_bounds__(256) void merge_kernel(
    const float* __restrict__ p1, const int* __restrict__ pi,
    const float* __restrict__ p2, int* __restrict__ idx,
    float* __restrict__ out_idxf, int* __restrict__ flist,
    int* __restrict__ flcnt) {
  int r = blockIdx.x * 256 + threadIdx.x;
  float m1 = 1e30f, m2 = 1e30f; int i1 = 0;
  for (int cb = 0; cb < 32; ++cb) {
    size_t o = (size_t)cb * NROWS + r;
    float v1 = p1[o]; int vi = pi[o]; float v2 = p2[o];
    float hi = fmaxf(m1, v1), lo2 = fminf(m2, v2);
    if (v1 < m1) { m1 = v1; i1 = vi; }
    else if (v1 == m1 && vi < i1) i1 = vi;
    m2 = fminf(hi, lo2);
  }
  idx[r] = i1;
  out_idxf[r] = (float)i1;
  if (m2 - m1 < MARGIN) { int p = atomicAdd(flcnt, 1); flist[p] = r; }
}

// exact fp32 rescore of flagged rows over all 4096 codes (8 rows per grab)
__global__ __launch_bounds__(256) void rescore_kernel(
    const float* __restrict__ z, const float* __restrict__ cb,
    const float* __restrict__ z_sq, const float* __restrict__ e_sq,
    const int* __restrict__ flist, const int* __restrict__ flcnt,
    int* __restrict__ idx, float* __restrict__ out_idxf) {
  __shared__ float zs[8][256];
  __shared__ float zq8[8];
  __shared__ int   rid[8];
  __shared__ float rmin[8][256];
  __shared__ int   rix[8][256];
  int t = threadIdx.x;
  int cnt = *flcnt;
  for (int base = blockIdx.x * 8; base < cnt; base += gridDim.x * 8) {
    int nr = min(8, cnt - base);
    __syncthreads();
    if (t < 8) {
      int rr = flist[base + ((t < nr) ? t : 0)];
      rid[t] = rr; zq8[t] = z_sq[rr];
    }
    __syncthreads();
    {
      int r8 = t >> 5, d0 = (t & 31) * 8;
      int row = rid[r8];
      float4 a = *(const float4*)(z + (size_t)row * DIM + d0);
      float4 b = *(const float4*)(z + (size_t)row * DIM + d0 + 4);
      *(float4*)&zs[r8][d0] = a;
      *(float4*)&zs[r8][d0 + 4] = b;
    }
    __syncthreads();
    float m1[8]; int i1[8];
#pragma unroll
    for (int r = 0; r < 8; ++r) { m1[r] = 1e30f; i1[r] = 0; }
    for (int cc = 0; cc < 16; ++cc) {
      int c = t * 16 + cc;
      float a0[8];
#pragma unroll
      for (int r = 0; r < 8; ++r) a0[r] = 0.f;
      for (int d = 0; d < DIM; d += 4) {
        float4 e = *(const float4*)(cb + (size_t)c * DIM + d);
#pragma unroll
        for (int r = 0; r < 8; ++r) {
          a0[r] = fmaf(zs[r][d], e.x, a0[r]);
          a0[r] = fmaf(zs[r][d + 1], e.y, a0[r]);
          a0[r] = fmaf(zs[r][d + 2], e.z, a0[r]);
          a0[r] = fmaf(zs[r][d + 3], e.w, a0[r]);
        }
      }
      float e2v = e_sq[c];
#pragma unroll
      for (int r = 0; r < 8; ++r) {
        float dv = (zq8[r] + e2v) - 2.0f * a0[r];
        if (dv < m1[r]) { m1[r] = dv; i1[r] = c; }
      }
    }
#pragma unroll
    for (int r = 0; r < 8; ++r) { rmin[r][t] = m1[r]; rix[r][t] = i1[r]; }
    __syncthreads();
    for (int s2 = 128; s2 >= 1; s2 >>= 1) {
      if (t < s2) {
#pragma unroll
        for (int r = 0; r < 8; ++r) {
          float a = rmin[r][t], b = rmin[r][t + s2];
          int ai = rix[r][t], bi = rix[r][t + s2];
          if (b < a || (b == a && bi < ai)) { rmin[r][t] = b; rix[r][t] = bi; }
        }
      }
      __syncthreads();
    }
    if (t < nr) {
      int rr = rid[t];
      idx[rr] = rix[t][0];
      out_idxf[rr] = (float)rix[t][0];
    }
  }
}

// z_q + straight-through + loss partial (per-block, no global atomic) + counts.
__global__ __launch_bounds__(256) void gather_kernel(
    const float* __restrict__ z, const float* __restrict__ cb,
    const int* __restrict__ idx, float* __restrict__ out_zq,
    int* __restrict__ counts, float* __restrict__ lossp) {
  __shared__ float ls[4];
  int gw = (blockIdx.x * 256 + threadIdx.x) >> 6;
  int lane = threadIdx.x & 63;
  int w = threadIdx.x >> 6;
  int k = idx[gw];
  float4 zq = *(const float4*)(cb + (size_t)k * DIM + lane * 4);
  float4 zv = *(const float4*)(z + (size_t)gw * DIM + lane * 4);
  float4 o;
  o.x = zv.x + (zq.x - zv.x);
  o.y = zv.y + (zq.y - zv.y);
  o.z = zv.z + (zq.z - zv.z);
  o.w = zv.w + (zq.w - zv.w);
  *(float4*)(out_zq + (size_t)gw * DIM + lane * 4) = o;
  float dx = zv.x - zq.x, dy = zv.y - zq.y, dz = zv.z - zq.z, dw = zv.w - zq.w;
  float s = dx * dx + dy * dy + dz * dz + dw * dw;
#pragma unroll
  for (int off = 32; off > 0; off >>= 1) s += __shfl_down(s, off);
  if (lane == 0) {
    ls[w] = s;
    atomicAdd(&counts[k], 1);
  }
  __syncthreads();
  if (threadIdx.x == 0)
    lossp[blockIdx.x] = ls[0] + ls[1] + ls[2] + ls[3];
}

__global__ void prefix_kernel(const int* __restrict__ counts,
                              int* __restrict__ base, int* __restrict__ cursor) {
  __shared__ int part[256];
  __shared__ int pre[256];
  int t = threadIdx.x;
  int loc[16]; int s = 0;
#pragma unroll
  for (int i = 0; i < 16; ++i) { loc[i] = counts[t * 16 + i]; s += loc[i]; }
  part[t] = s;
  __syncthreads();
  if (t == 0) { int a = 0; for (int i = 0; i < 256; ++i) { pre[i] = a; a += part[i]; } }
  __syncthreads();
  int a = pre[t];
#pragma unroll
  for (int i = 0; i < 16; ++i) { base[t * 16 + i] = a; cursor[t * 16 + i] = a; a += loc[i]; }
}

__global__ void scatter_kernel(const int* __restrict__ idx,
                               int* __restrict__ cursor, int* __restrict__ list2) {
  int n = blockIdx.x * 256 + threadIdx.x;
  int k = idx[n];
  int p = atomicAdd(&cursor[k], 1);
  list2[p] = n;
}

// per-code: sum assigned z rows (inverted index), EMA update, outputs
__global__ __launch_bounds__(256) void finalize_codes(
    const float* __restrict__ ema_cs, const float* __restrict__ ema_es,
    const int* __restrict__ counts, const int* __restrict__ base,
    const int* __restrict__ list2, const float* __restrict__ z,
    float* __restrict__ out_cb, float* __restrict__ out_cs,
    float* __restrict__ out_es) {
  int gw = (blockIdx.x * 256 + threadIdx.x) >> 6;
  int lane = threadIdx.x & 63;
  int cnt = counts[gw], b0 = base[gw];
  float sx = 0.f, sy = 0.f, sz = 0.f, sw = 0.f;
  for (int i = 0; i < cnt; ++i) {
    int n = list2[b0 + i];
    float4 v = *(const float4*)(z + (size_t)n * DIM + lane * 4);
    sx += v.x; sy += v.y; sz += v.z; sw += v.w;
  }
  const float omd = 1.0f - DECAYF;
  float cntf = (float)cnt;
  float ncs = ema_cs[gw] * DECAYF + omd * cntf;
  float nden = ncs + 0.04096f;
  if (lane == 0) out_cs[gw] = ncs;
  size_t o = (size_t)gw * DIM + lane * 4;
  float4 em = *(const float4*)(ema_es + o);
  float nex = em.x * DECAYF + omd * sx;
  float ney = em.y * DECAYF + omd * sy;
  float nez = em.z * DECAYF + omd * sz;
  float new_ = em.w * DECAYF + omd * sw;
  *(float2*)(out_es + o) = make_float2(nex, ney);
  *(float2*)(out_es + o + 2) = make_float2(nez, new_);
  *(float2*)(out_cb + o) = make_float2(nex / nden, ney / nden);
  *(float2*)(out_cb + o + 2) = make_float2(nez / nden, new_ / nden);
}

// one block: reduce 8192 loss partials + entropy from counts
__global__ __launch_bounds__(256) void finalize_scalars(
    const float* __restrict__ lossp, const int* __restrict__ counts,
    float* __restrict__ out_loss, float* __restrict__ out_ppl) {
  __shared__ float red[256];
  int t = threadIdx.x;
  float s = 0.f;
  for (int i = t; i < 8192; i += 256) s += lossp[i];
  float e = 0.f;
  for (int i = t; i < 4096; i += 256) {
    float p = (float)counts[i] * (1.0f / (float)NROWS);
    e -= p * logf(p + 1e-12f);
  }
  red[t] = s;
  __syncthreads();
  for (int st = 128; st > 0; st >>= 1) {
    if (t < st) red[t] += red[t + st];
    __syncthreads();
  }
  float loss_tot = red[0];
  __syncthreads();
  red[t] = e;
  __syncthreads();
  for (int st = 128; st > 0; st >>= 1) {
    if (t < st) red[t] += red[t + st];
    __syncthreads();
  }
  if (t == 0) {
    out_loss[0] = 0.25f * (loss_tot / 8388608.0f);
    out_ppl[0] = expf(red[0]);
  }
}

extern "C" void kernel_launch(void* const* d_in, const int* in_sizes, int n_in,
                              void* d_out, int out_size, void* d_ws, size_t ws_size,
                              hipStream_t stream) {
  (void)in_sizes; (void)n_in; (void)out_size; (void)ws_size;
  const float* z      = (const float*)d_in[0];
  const float* cb     = (const float*)d_in[1];
  const float* ema_cs = (const float*)d_in[2];
  const float* ema_es = (const float*)d_in[3];
  float* out = (float*)d_out;
  char*  ws  = (char*)d_ws;

  unsigned short* A2 = (unsigned short*)(ws + WS_A2);
  unsigned short* EH = (unsigned short*)(ws + WS_EH);
  float* z_sq  = (float*)(ws + WS_ZSQ);
  float* e_sq  = (float*)(ws + WS_ESQ);
  float* p1    = (float*)(ws + WS_P1);
  int*   pi    = (int*)(ws + WS_PI);
  float* p2    = (float*)(ws + WS_P2);
  float* lossp = (float*)(ws + WS_P2);   // reuse: dead after merge_kernel
  int*   idx   = (int*)(ws + WS_IDX);
  int*   flist = (int*)(ws + WS_FLIST);
  int*   list2 = (int*)(ws + WS_LIST2);
  int*   base  = (int*)(ws + WS_BASE);
  int*   counts = (int*)(ws + WS_COUNTS);
  int*   cursor = (int*)(ws + WS_CURSOR);
  int*   flcnt  = (int*)(ws + WS_FLCNT);

  hipMemsetAsync(ws + WS_ZERO, 0, WS_ZEROLEN, stream);

  prep_z<<<NROWS / 4, 256, 0, stream>>>(z, A2, z_sq);
  prep_e<<<KCB / 4, 256, 0, stream>>>(cb, EH, e_sq);
  dist_mfma<<<(NROWS / 128) * (KCB / 128), 256, 0, stream>>>(A2, EH, e_sq,
                                                             p1, pi, p2);
  merge_kernel<<<NROWS / 256, 256, 0, stream>>>(p1, pi, p2, idx,
                                                out + OUT_IDX, flist, flcnt);
  rescore_kernel<<<512, 256, 0, stream>>>(z, cb, z_sq, e_sq, flist, flcnt,
                                          idx, out + OUT_IDX);
  gather_kernel<<<NROWS / 4, 256, 0, stream>>>(z, cb, idx, out + OUT_ZQ,
                                               counts, lossp);
  prefix_kernel<<<1, 256, 0, stream>>>(counts, base, cursor);
  scatter_kernel<<<NROWS / 256, 256, 0, stream>>>(idx, cursor, list2);
  finalize_codes<<<KCB / 4, 256, 0, stream>>>(ema_cs, ema_es, counts, base,
                                              list2, z, out + OUT_CB,
                                              out + OUT_CS, out + OUT_ES);
  finalize_scalars<<<1, 256, 0, stream>>>(lossp, counts, out + OUT_LOSS,
                                          out + OUT_PPL);
}

// Round 6
// 400.070 us; speedup vs baseline: 9.1523x; 1.4727x over previous
//
#include <hip/hip_runtime.h>
#include <hip/hip_bf16.h>
#include <math.h>

#define DIM    256
#define KCB    4096
#define NROWS  32768
#define DECAYF 0.99f
#define MARGIN 0.03f

// ---- d_out offsets (in floats) ----
#define OUT_ZQ   0
#define OUT_IDX  8388608
#define OUT_LOSS 8421376
#define OUT_PPL  8421377
#define OUT_CB   8421378
#define OUT_CS   9469954
#define OUT_ES   9474050

// ---- d_ws offsets (bytes) ----
#define WS_A2      0u            // [32768][512] bf16 (hi|lo)  32 MB; dead after
                                 // dist_mfma -> reused: slot[] (+0), cbT (+1MB)
#define WS_EH      33554432u     // [4096][256] bf16            2 MB
#define WS_ZSQ     35651584u     // N f32
#define WS_ESQ     35782656u     // K f32
#define WS_P1      35799040u     // [32][32768] f32 partial min1
#define WS_PI      39993344u     // [32][32768] i32 partial idx1
#define WS_P2      44187648u     // [32][32768] f32 partial min2 (dead after
                                 // merge_kernel -> reused for loss partials)
#define WS_IDX     48381952u     // N i32 final idx
#define WS_FLIST   48513024u     // N i32 flagged rows
#define WS_LIST2   48644096u     // N i32 inverted index
#define WS_BASE    48775168u     // K i32
#define WS_ZERO    48791552u     // zeroed region start
#define WS_COUNTS  48791552u     // K i32
#define WS_CURSOR  48807936u     // K i32
#define WS_FLCNT   48824320u
#define WS_ZEROLEN 32772u

#define WS_SLOT    WS_A2                 // N u64 packed (distbits<<32)|idx
#define WS_CBT     (WS_A2 + 1048576u)    // [256][4096] f32 transposed codebook

typedef __attribute__((ext_vector_type(8))) short short8;
typedef __attribute__((ext_vector_type(4))) float f32x4;

#define GLOAD(g, l) __builtin_amdgcn_global_load_lds( \
    (const __attribute__((address_space(1))) unsigned int*)(g), \
    (__attribute__((address_space(3))) unsigned int*)(l), 16, 0, 0)

__device__ __forceinline__ unsigned short f2bf(float x) {
  __hip_bfloat16 h = __float2bfloat16(x);
  return *reinterpret_cast<unsigned short*>(&h);
}
__device__ __forceinline__ float bf2f(unsigned short u) {
  unsigned int v = ((unsigned int)u) << 16;
  return *reinterpret_cast<float*>(&v);
}

// z -> A2 = [z_hi | z_lo] bf16, plus z_sq.  One wave per row.
__global__ __launch_bounds__(256) void prep_z(
    const float* __restrict__ z, unsigned short* __restrict__ A2,
    float* __restrict__ z_sq) {
  int gw = (blockIdx.x * 256 + threadIdx.x) >> 6;
  int lane = threadIdx.x & 63;
  float4 v = *(const float4*)(z + (size_t)gw * DIM + lane * 4);
  float x[4] = {v.x, v.y, v.z, v.w};
  unsigned short h[4], l[4];
  float ss = 0.f;
#pragma unroll
  for (int i = 0; i < 4; ++i) {
    ss += x[i] * x[i];
    h[i] = f2bf(x[i]);
    l[i] = f2bf(x[i] - bf2f(h[i]));
  }
  size_t o = (size_t)gw * 512 + lane * 4;
  *(ushort4*)(A2 + o) = make_ushort4(h[0], h[1], h[2], h[3]);
  *(ushort4*)(A2 + o + 256) = make_ushort4(l[0], l[1], l[2], l[3]);
#pragma unroll
  for (int off = 32; off > 0; off >>= 1) ss += __shfl_down(ss, off);
  if (lane == 0) z_sq[gw] = ss;
}

// codebook -> EH bf16 + e_sq (from fp32).  One wave per code.
__global__ __launch_bounds__(256) void prep_e(
    const float* __restrict__ cb, unsigned short* __restrict__ EH,
    float* __restrict__ e_sq) {
  int gw = (blockIdx.x * 256 + threadIdx.x) >> 6;
  int lane = threadIdx.x & 63;
  float4 v = *(const float4*)(cb + (size_t)gw * DIM + lane * 4);
  float x[4] = {v.x, v.y, v.z, v.w};
  unsigned short h[4];
  float ss = 0.f;
#pragma unroll
  for (int i = 0; i < 4; ++i) { ss += x[i] * x[i]; h[i] = f2bf(x[i]); }
  *(ushort4*)(EH + (size_t)gw * 256 + lane * 4) =
      make_ushort4(h[0], h[1], h[2], h[3]);
#pragma unroll
  for (int off = 32; off > 0; off >>= 1) ss += __shfl_down(ss, off);
  if (lane == 0) e_sq[gw] = ss;
}

// cb[4096][256] -> cbT[256][4096], 32-code LDS tiles (pad 257 kills conflicts)
__global__ __launch_bounds__(256) void tp_cb(
    const float* __restrict__ cb, float* __restrict__ cbT) {
  __shared__ float tile[32][257];
  int c0 = blockIdx.x * 32;
  int t = threadIdx.x;
  int r = t >> 6, c4 = (t & 63) * 4;
#pragma unroll
  for (int i = 0; i < 8; ++i) {
    float4 v = *(const float4*)(cb + (size_t)(c0 + r + i * 4) * DIM + c4);
    tile[r + i * 4][c4 + 0] = v.x;
    tile[r + i * 4][c4 + 1] = v.y;
    tile[r + i * 4][c4 + 2] = v.z;
    tile[r + i * 4][c4 + 3] = v.w;
  }
  __syncthreads();
  int cs = (t & 7) * 4;
#pragma unroll
  for (int j = 0; j < 8; ++j) {
    int d = (t >> 3) + j * 32;
    float4 w = make_float4(tile[cs][d], tile[cs + 1][d],
                           tile[cs + 2][d], tile[cs + 3][d]);
    *(float4*)(cbT + (size_t)d * KCB + c0 + cs) = w;
  }
}

// 128x128 tile bf16 MFMA "GEMM" over K=512 (hi|lo), fused per-row min1/min2.
__global__ __launch_bounds__(256) void dist_mfma(
    const unsigned short* __restrict__ A2, const unsigned short* __restrict__ EH,
    const float* __restrict__ e_sq,
    float* __restrict__ p1, int* __restrict__ pi, float* __restrict__ p2) {
  __shared__ __align__(16) unsigned short sA[128 * 32];
  __shared__ __align__(16) unsigned short sB[128 * 32];
  __shared__ float sm1[2][128];
  __shared__ int   smi[2][128];
  __shared__ float sm2[2][128];

  int wgid = blockIdx.x;
  int swz = (wgid & 7) * 1024 + (wgid >> 3);   // XCD-contiguous, bijective
  int rowp = swz >> 5, colp = swz & 31;
  int brow = rowp * 128, bcol = colp * 128;
  int tid = threadIdx.x;
  int lane = tid & 63, w = tid >> 6;
  int wr = w >> 1, wc = w & 1;
  int rl = lane & 15, k8 = lane >> 4;

  f32x4 acc[4][4] = {};

  const char* gA = (const char*)A2;
  const char* gB = (const char*)EH;
  int r0 = tid >> 2, seg = tid & 3;

  for (int ks = 0; ks < 16; ++ks) {
    __syncthreads();
    const char* ga0 = gA + (size_t)(brow + r0) * 1024 + ks * 64 + seg * 16;
    GLOAD(ga0, &sA[tid * 8]);
    GLOAD(ga0 + 64 * 1024, &sA[2048 + tid * 8]);
    const char* gb0 = gB + (size_t)(bcol + r0) * 512 + (ks & 7) * 64 + seg * 16;
    GLOAD(gb0, &sB[tid * 8]);
    GLOAD(gb0 + 64 * 512, &sB[2048 + tid * 8]);
    __syncthreads();

    short8 af[4], bfr[4];
#pragma unroll
    for (int mi = 0; mi < 4; ++mi)
      af[mi] = *(const short8*)&sA[(wr * 64 + mi * 16 + rl) * 32 + k8 * 8];
#pragma unroll
    for (int ni = 0; ni < 4; ++ni)
      bfr[ni] = *(const short8*)&sB[(wc * 64 + ni * 16 + rl) * 32 + k8 * 8];
#pragma unroll
    for (int mi = 0; mi < 4; ++mi)
#pragma unroll
      for (int ni = 0; ni < 4; ++ni)
        acc[mi][ni] = __builtin_amdgcn_mfma_f32_16x16x32_bf16(
            af[mi], bfr[ni], acc[mi][ni], 0, 0, 0);
  }

  float e2[4];
#pragma unroll
  for (int ni = 0; ni < 4; ++ni) e2[ni] = e_sq[bcol + wc * 64 + ni * 16 + rl];

#pragma unroll
  for (int mi = 0; mi < 4; ++mi) {
#pragma unroll
    for (int j = 0; j < 4; ++j) {
      float m1 = 1e30f, m2 = 1e30f; int i1 = 0;
#pragma unroll
      for (int ni = 0; ni < 4; ++ni) {
        float q = e2[ni] - 2.0f * acc[mi][ni][j];
        if (q < m1) { m2 = m1; m1 = q; i1 = bcol + wc * 64 + ni * 16 + rl; }
        else if (q < m2) m2 = q;
      }
#pragma unroll
      for (int mk = 8; mk >= 1; mk >>= 1) {
        float v1 = __shfl_xor(m1, mk);
        int   vi = __shfl_xor(i1, mk);
        float v2 = __shfl_xor(m2, mk);
        float hi = fmaxf(m1, v1), lo2 = fminf(m2, v2);
        if (v1 < m1) { m1 = v1; i1 = vi; }
        else if (v1 == m1 && vi < i1) i1 = vi;
        m2 = fminf(hi, lo2);
      }
      if (rl == 0) {
        int rowl = wr * 64 + mi * 16 + k8 * 4 + j;
        sm1[wc][rowl] = m1; smi[wc][rowl] = i1; sm2[wc][rowl] = m2;
      }
    }
  }
  __syncthreads();
  if (tid < 128) {
    float a1 = sm1[0][tid]; int ai = smi[0][tid]; float a2 = sm2[0][tid];
    float b1 = sm1[1][tid]; int bi = smi[1][tid]; float b2 = sm2[1][tid];
    float m1, m2; int i1;
    if (b1 < a1) { m1 = b1; i1 = bi; m2 = fminf(a1, b2); }
    else         { m1 = a1; i1 = ai; m2 = fminf(b1, a2); }  // ties keep smaller idx
    size_t o = (size_t)colp * NROWS + (brow + tid);
    p1[o] = m1; pi[o] = i1; p2[o] = m2;
  }
}

// merge 32 panel partials per row; flag near-ties (init their rescore slot)
__global__ __launch_bounds__(256) void merge_kernel(
    const float* __restrict__ p1, const int* __restrict__ pi,
    const float* __restrict__ p2, int* __restrict__ idx,
    float* __restrict__ out_idxf, int* __restrict__ flist,
    int* __restrict__ flcnt, unsigned long long* __restrict__ slot) {
  int r = blockIdx.x * 256 + threadIdx.x;
  float m1 = 1e30f, m2 = 1e30f; int i1 = 0;
  for (int cb = 0; cb < 32; ++cb) {
    size_t o = (size_t)cb * NROWS + r;
    float v1 = p1[o]; int vi = pi[o]; float v2 = p2[o];
    float hi = fmaxf(m1, v1), lo2 = fminf(m2, v2);
    if (v1 < m1) { m1 = v1; i1 = vi; }
    else if (v1 == m1 && vi < i1) i1 = vi;
    m2 = fminf(hi, lo2);
  }
  idx[r] = i1;
  out_idxf[r] = (float)i1;
  if (m2 - m1 < MARGIN) {
    slot[r] = ~0ULL;
    int p = atomicAdd(flcnt, 1);
    flist[p] = r;
  }
}

// exact fp32 rescore: item = (16-row batch, 1024-code quarter).
// 4 codes x 16 rows register tile; cbT gives coalesced code loads; result
// merged across quarters via packed u64 atomicMin (lexicographic (dist,idx)).
__global__ __launch_bounds__(256) void rescore_partial(
    const float* __restrict__ z, const float* __restrict__ cbT,
    const float* __restrict__ z_sq, const float* __restrict__ e_sq,
    const int* __restrict__ flist, const int* __restrict__ flcnt,
    unsigned long long* __restrict__ slot) {
  __shared__ float zs[16][256];
  __shared__ int   rid[16];
  __shared__ float zq[16];
  __shared__ unsigned long long wred[4][16];
  int t = threadIdx.x;
  int lane = t & 63, w = t >> 6;
  int cnt = *flcnt;
  int nitems = ((cnt + 15) >> 4) << 2;
  for (int it = blockIdx.x; it < nitems; it += gridDim.x) {
    int batch = it >> 2, quarter = it & 3;
    __syncthreads();
    if (t < 16) {
      int fi = batch * 16 + t;
      int rr = flist[fi < cnt ? fi : (cnt - 1)];
      rid[t] = rr; zq[t] = z_sq[rr];
    }
    __syncthreads();
    {
      int r8 = t >> 4, c0 = (t & 15) * 16;
      const float* zp = z + (size_t)rid[r8] * DIM + c0;
#pragma unroll
      for (int i = 0; i < 4; ++i)
        *(float4*)&zs[r8][c0 + i * 4] = *(const float4*)(zp + i * 4);
    }
    __syncthreads();
    int cbase = quarter * 1024 + t * 4;
    float4 es4 = *(const float4*)(e_sq + cbase);
    float a0[16], a1[16], a2[16], a3[16];
#pragma unroll
    for (int r = 0; r < 16; ++r) { a0[r] = 0.f; a1[r] = 0.f; a2[r] = 0.f; a3[r] = 0.f; }
    for (int d = 0; d < DIM; ++d) {
      float4 e = *(const float4*)(cbT + (size_t)d * KCB + cbase);
#pragma unroll
      for (int r = 0; r < 16; ++r) {
        float zv = zs[r][d];
        a0[r] = fmaf(zv, e.x, a0[r]);
        a1[r] = fmaf(zv, e.y, a1[r]);
        a2[r] = fmaf(zv, e.z, a2[r]);
        a3[r] = fmaf(zv, e.w, a3[r]);
      }
    }
#pragma unroll
    for (int r = 0; r < 16; ++r) {
      float d0 = (zq[r] + es4.x) - 2.0f * a0[r];
      float d1 = (zq[r] + es4.y) - 2.0f * a1[r];
      float d2 = (zq[r] + es4.z) - 2.0f * a2[r];
      float d3 = (zq[r] + es4.w) - 2.0f * a3[r];
      float m = d0; int ci = cbase;
      if (d1 < m) { m = d1; ci = cbase + 1; }
      if (d2 < m) { m = d2; ci = cbase + 2; }
      if (d3 < m) { m = d3; ci = cbase + 3; }
      unsigned long long p =
          ((unsigned long long)__float_as_uint(m) << 32) | (unsigned)ci;
#pragma unroll
      for (int mk = 32; mk >= 1; mk >>= 1) {
        unsigned long long q = __shfl_xor(p, mk);
        if (q < p) p = q;
      }
      if (lane == 0) wred[w][r] = p;
    }
    __syncthreads();
    if (t < 16) {
      unsigned long long m = wred[0][t];
      if (wred[1][t] < m) m = wred[1][t];
      if (wred[2][t] < m) m = wred[2][t];
      if (wred[3][t] < m) m = wred[3][t];
      atomicMin(&slot[rid[t]], m);
    }
  }
}

__global__ __launch_bounds__(256) void rescore_final(
    const int* __restrict__ flist, const int* __restrict__ flcnt,
    const unsigned long long* __restrict__ slot,
    int* __restrict__ idx, float* __restrict__ out_idxf) {
  int i = blockIdx.x * 256 + threadIdx.x;
  if (i >= *flcnt) return;
  int r = flist[i];
  int ci = (int)(unsigned)(slot[r] & 0xFFFFFFFFu);
  idx[r] = ci;
  out_idxf[r] = (float)ci;
}

// z_q + straight-through + loss partial (per-block, no global atomic) + counts.
__global__ __launch_bounds__(256) void gather_kernel(
    const float* __restrict__ z, const float* __restrict__ cb,
    const int* __restrict__ idx, float* __restrict__ out_zq,
    int* __restrict__ counts, float* __restrict__ lossp) {
  __shared__ float ls[4];
  int gw = (blockIdx.x * 256 + threadIdx.x) >> 6;
  int lane = threadIdx.x & 63;
  int w = threadIdx.x >> 6;
  int k = idx[gw];
  float4 zq = *(const float4*)(cb + (size_t)k * DIM + lane * 4);
  float4 zv = *(const float4*)(z + (size_t)gw * DIM + lane * 4);
  float4 o;
  o.x = zv.x + (zq.x - zv.x);
  o.y = zv.y + (zq.y - zv.y);
  o.z = zv.z + (zq.z - zv.z);
  o.w = zv.w + (zq.w - zv.w);
  *(float4*)(out_zq + (size_t)gw * DIM + lane * 4) = o;
  float dx = zv.x - zq.x, dy = zv.y - zq.y, dz = zv.z - zq.z, dw = zv.w - zq.w;
  float s = dx * dx + dy * dy + dz * dz + dw * dw;
#pragma unroll
  for (int off = 32; off > 0; off >>= 1) s += __shfl_down(s, off);
  if (lane == 0) {
    ls[w] = s;
    atomicAdd(&counts[k], 1);
  }
  __syncthreads();
  if (threadIdx.x == 0)
    lossp[blockIdx.x] = ls[0] + ls[1] + ls[2] + ls[3];
}

__global__ void prefix_kernel(const int* __restrict__ counts,
                              int* __restrict__ base, int* __restrict__ cursor) {
  __shared__ int part[256];
  __shared__ int pre[256];
  int t = threadIdx.x;
  int loc[16]; int s = 0;
#pragma unroll
  for (int i = 0; i < 16; ++i) { loc[i] = counts[t * 16 + i]; s += loc[i]; }
  part[t] = s;
  __syncthreads();
  if (t == 0) { int a = 0; for (int i = 0; i < 256; ++i) { pre[i] = a; a += part[i]; } }
  __syncthreads();
  int a = pre[t];
#pragma unroll
  for (int i = 0; i < 16; ++i) { base[t * 16 + i] = a; cursor[t * 16 + i] = a; a += loc[i]; }
}

__global__ void scatter_kernel(const int* __restrict__ idx,
                               int* __restrict__ cursor, int* __restrict__ list2) {
  int n = blockIdx.x * 256 + threadIdx.x;
  int k = idx[n];
  int p = atomicAdd(&cursor[k], 1);
  list2[p] = n;
}

// per-code: sum assigned z rows (inverted index), EMA update, outputs
__global__ __launch_bounds__(256) void finalize_codes(
    const float* __restrict__ ema_cs, const float* __restrict__ ema_es,
    const int* __restrict__ counts, const int* __restrict__ base,
    const int* __restrict__ list2, const float* __restrict__ z,
    float* __restrict__ out_cb, float* __restrict__ out_cs,
    float* __restrict__ out_es) {
  int gw = (blockIdx.x * 256 + threadIdx.x) >> 6;
  int lane = threadIdx.x & 63;
  int cnt = counts[gw], b0 = base[gw];
  float sx = 0.f, sy = 0.f, sz = 0.f, sw = 0.f;
  for (int i = 0; i < cnt; ++i) {
    int n = list2[b0 + i];
    float4 v = *(const float4*)(z + (size_t)n * DIM + lane * 4);
    sx += v.x; sy += v.y; sz += v.z; sw += v.w;
  }
  const float omd = 1.0f - DECAYF;
  float cntf = (float)cnt;
  float ncs = ema_cs[gw] * DECAYF + omd * cntf;
  float nden = ncs + 0.04096f;
  if (lane == 0) out_cs[gw] = ncs;
  size_t o = (size_t)gw * DIM + lane * 4;
  float4 em = *(const float4*)(ema_es + o);
  float nex = em.x * DECAYF + omd * sx;
  float ney = em.y * DECAYF + omd * sy;
  float nez = em.z * DECAYF + omd * sz;
  float new_ = em.w * DECAYF + omd * sw;
  *(float2*)(out_es + o) = make_float2(nex, ney);
  *(float2*)(out_es + o + 2) = make_float2(nez, new_);
  *(float2*)(out_cb + o) = make_float2(nex / nden, ney / nden);
  *(float2*)(out_cb + o + 2) = make_float2(nez / nden, new_ / nden);
}

// one block: reduce 8192 loss partials + entropy from counts
__global__ __launch_bounds__(256) void finalize_scalars(
    const float* __restrict__ lossp, const int* __restrict__ counts,
    float* __restrict__ out_loss, float* __restrict__ out_ppl) {
  __shared__ float red[256];
  int t = threadIdx.x;
  float s = 0.f;
  for (int i = t; i < 8192; i += 256) s += lossp[i];
  float e = 0.f;
  for (int i = t; i < 4096; i += 256) {
    float p = (float)counts[i] * (1.0f / (float)NROWS);
    e -= p * logf(p + 1e-12f);
  }
  red[t] = s;
  __syncthreads();
  for (int st = 128; st > 0; st >>= 1) {
    if (t < st) red[t] += red[t + st];
    __syncthreads();
  }
  float loss_tot = red[0];
  __syncthreads();
  red[t] = e;
  __syncthreads();
  for (int st = 128; st > 0; st >>= 1) {
    if (t < st) red[t] += red[t + st];
    __syncthreads();
  }
  if (t == 0) {
    out_loss[0] = 0.25f * (loss_tot / 8388608.0f);
    out_ppl[0] = expf(red[0]);
  }
}

extern "C" void kernel_launch(void* const* d_in, const int* in_sizes, int n_in,
                              void* d_out, int out_size, void* d_ws, size_t ws_size,
                              hipStream_t stream) {
  (void)in_sizes; (void)n_in; (void)out_size; (void)ws_size;
  const float* z      = (const float*)d_in[0];
  const float* cb     = (const float*)d_in[1];
  const float* ema_cs = (const float*)d_in[2];
  const float* ema_es = (const float*)d_in[3];
  float* out = (float*)d_out;
  char*  ws  = (char*)d_ws;

  unsigned short* A2 = (unsigned short*)(ws + WS_A2);
  unsigned short* EH = (unsigned short*)(ws + WS_EH);
  float* z_sq  = (float*)(ws + WS_ZSQ);
  float* e_sq  = (float*)(ws + WS_ESQ);
  float* p1    = (float*)(ws + WS_P1);
  int*   pi    = (int*)(ws + WS_PI);
  float* p2    = (float*)(ws + WS_P2);
  float* lossp = (float*)(ws + WS_P2);   // reuse: dead after merge_kernel
  unsigned long long* slot = (unsigned long long*)(ws + WS_SLOT);  // A2 reuse
  float* cbT   = (float*)(ws + WS_CBT);                            // A2 reuse
  int*   idx   = (int*)(ws + WS_IDX);
  int*   flist = (int*)(ws + WS_FLIST);
  int*   list2 = (int*)(ws + WS_LIST2);
  int*   base  = (int*)(ws + WS_BASE);
  int*   counts = (int*)(ws + WS_COUNTS);
  int*   cursor = (int*)(ws + WS_CURSOR);
  int*   flcnt  = (int*)(ws + WS_FLCNT);

  hipMemsetAsync(ws + WS_ZERO, 0, WS_ZEROLEN, stream);

  prep_z<<<NROWS / 4, 256, 0, stream>>>(z, A2, z_sq);
  prep_e<<<KCB / 4, 256, 0, stream>>>(cb, EH, e_sq);
  dist_mfma<<<(NROWS / 128) * (KCB / 128), 256, 0, stream>>>(A2, EH, e_sq,
                                                             p1, pi, p2);
  tp_cb<<<KCB / 32, 256, 0, stream>>>(cb, cbT);            // A2 dead from here
  merge_kernel<<<NROWS / 256, 256, 0, stream>>>(p1, pi, p2, idx,
                                                out + OUT_IDX, flist, flcnt,
                                                slot);
  rescore_partial<<<2048, 256, 0, stream>>>(z, cbT, z_sq, e_sq, flist, flcnt,
                                            slot);
  rescore_final<<<NROWS / 256, 256, 0, stream>>>(flist, flcnt, slot, idx,
                                                 out + OUT_IDX);
  gather_kernel<<<NROWS / 4, 256, 0, stream>>>(z, cb, idx, out + OUT_ZQ,
                                               counts, lossp);
  prefix_kernel<<<1, 256, 0, stream>>>(counts, base, cursor);
  scatter_kernel<<<NROWS / 256, 256, 0, stream>>>(idx, cursor, list2);
  finalize_codes<<<KCB / 4, 256, 0, stream>>>(ema_cs, ema_es, counts, base,
                                              list2, z, out + OUT_CB,
                                              out + OUT_CS, out + OUT_ES);
  finalize_scalars<<<1, 256, 0, stream>>>(lossp, counts, out + OUT_LOSS,
                                          out + OUT_PPL);
}

// Round 7
// 348.239 us; speedup vs baseline: 10.5146x; 1.1488x over previous
//
#include <hip/hip_runtime.h>
#include <hip/hip_bf16.h>
#include <math.h>

#define DIM    256
#define KCB    4096
#define NROWS  32768
#define DECAYF 0.99f
#define MARGIN 0.03f

// ---- d_out offsets (in floats) ----
#define OUT_ZQ   0
#define OUT_IDX  8388608
#define OUT_LOSS 8421376
#define OUT_PPL  8421377
#define OUT_CB   8421378
#define OUT_CS   9469954
#define OUT_ES   9474050

// ---- d_ws offsets (bytes) ----
#define WS_A2      0u            // [32768][256] bf16 (hi only) 16 MB; dead after
                                 // dist_mfma -> reused: slot[] (+0), cbT (+1MB)
#define WS_EH      33554432u     // [4096][256] bf16            2 MB
#define WS_ZSQ     35651584u     // N f32
#define WS_ESQ     35782656u     // K f32
#define WS_P1      35799040u     // [32][32768] f32 partial min1
#define WS_PI      39993344u     // [32][32768] i32 partial idx1
#define WS_P2      44187648u     // [32][32768] f32 partial min2 (dead after
                                 // merge_kernel -> reused for loss partials)
#define WS_IDX     48381952u     // N i32 final idx
#define WS_FLIST   48513024u     // N i32 flagged rows
#define WS_LIST2   48644096u     // N i32 inverted index
#define WS_BASE    48775168u     // K i32
#define WS_ZERO    48791552u     // zeroed region start
#define WS_COUNTS  48791552u     // K i32
#define WS_CURSOR  48807936u     // K i32
#define WS_FLCNT   48824320u
#define WS_ZEROLEN 32772u

#define WS_SLOT    WS_A2                 // N u64 packed (distbits<<32)|idx
#define WS_CBT     (WS_A2 + 1048576u)    // [256][4096] f32 transposed codebook

typedef __attribute__((ext_vector_type(8))) short short8;
typedef __attribute__((ext_vector_type(4))) float f32x4;

#define GLOAD(g, l) __builtin_amdgcn_global_load_lds( \
    (const __attribute__((address_space(1))) unsigned int*)(g), \
    (__attribute__((address_space(3))) unsigned int*)(l), 16, 0, 0)

__device__ __forceinline__ unsigned short f2bf(float x) {
  __hip_bfloat16 h = __float2bfloat16(x);
  return *reinterpret_cast<unsigned short*>(&h);
}

// z -> A2 = z_hi bf16, plus z_sq.  One wave per row.
__global__ __launch_bounds__(256) void prep_z(
    const float* __restrict__ z, unsigned short* __restrict__ A2,
    float* __restrict__ z_sq) {
  int gw = (blockIdx.x * 256 + threadIdx.x) >> 6;
  int lane = threadIdx.x & 63;
  float4 v = *(const float4*)(z + (size_t)gw * DIM + lane * 4);
  float x[4] = {v.x, v.y, v.z, v.w};
  unsigned short h[4];
  float ss = 0.f;
#pragma unroll
  for (int i = 0; i < 4; ++i) { ss += x[i] * x[i]; h[i] = f2bf(x[i]); }
  *(ushort4*)(A2 + (size_t)gw * 256 + lane * 4) =
      make_ushort4(h[0], h[1], h[2], h[3]);
#pragma unroll
  for (int off = 32; off > 0; off >>= 1) ss += __shfl_down(ss, off);
  if (lane == 0) z_sq[gw] = ss;
}

// codebook -> EH bf16 + e_sq (from fp32).  One wave per code.
__global__ __launch_bounds__(256) void prep_e(
    const float* __restrict__ cb, unsigned short* __restrict__ EH,
    float* __restrict__ e_sq) {
  int gw = (blockIdx.x * 256 + threadIdx.x) >> 6;
  int lane = threadIdx.x & 63;
  float4 v = *(const float4*)(cb + (size_t)gw * DIM + lane * 4);
  float x[4] = {v.x, v.y, v.z, v.w};
  unsigned short h[4];
  float ss = 0.f;
#pragma unroll
  for (int i = 0; i < 4; ++i) { ss += x[i] * x[i]; h[i] = f2bf(x[i]); }
  *(ushort4*)(EH + (size_t)gw * 256 + lane * 4) =
      make_ushort4(h[0], h[1], h[2], h[3]);
#pragma unroll
  for (int off = 32; off > 0; off >>= 1) ss += __shfl_down(ss, off);
  if (lane == 0) e_sq[gw] = ss;
}

// cb[4096][256] -> cbT[256][4096], 32-code LDS tiles (pad 257 kills conflicts)
__global__ __launch_bounds__(256) void tp_cb(
    const float* __restrict__ cb, float* __restrict__ cbT) {
  __shared__ float tile[32][257];
  int c0 = blockIdx.x * 32;
  int t = threadIdx.x;
  int r = t >> 6, c4 = (t & 63) * 4;
#pragma unroll
  for (int i = 0; i < 8; ++i) {
    float4 v = *(const float4*)(cb + (size_t)(c0 + r + i * 4) * DIM + c4);
    tile[r + i * 4][c4 + 0] = v.x;
    tile[r + i * 4][c4 + 1] = v.y;
    tile[r + i * 4][c4 + 2] = v.z;
    tile[r + i * 4][c4 + 3] = v.w;
  }
  __syncthreads();
  int cs = (t & 7) * 4;
#pragma unroll
  for (int j = 0; j < 8; ++j) {
    int d = (t >> 3) + j * 32;
    float4 w = make_float4(tile[cs][d], tile[cs + 1][d],
                           tile[cs + 2][d], tile[cs + 3][d]);
    *(float4*)(cbT + (size_t)d * KCB + c0 + cs) = w;
  }
}

// 128x128 tile bf16 MFMA "GEMM" over K=256 (hi only), BK=64, XOR-swizzled LDS
// (linear gload_lds dest + pre-swizzled global source + swizzled ds_read:
// 16B-seg s' = s ^ (row&7) -> conflict-free b128 reads).  Fused min1/min2.
__global__ __launch_bounds__(256) void dist_mfma(
    const unsigned short* __restrict__ A2, const unsigned short* __restrict__ EH,
    const float* __restrict__ e_sq,
    float* __restrict__ p1, int* __restrict__ pi, float* __restrict__ p2) {
  __shared__ __align__(16) unsigned short sA[128 * 64];
  __shared__ __align__(16) unsigned short sB[128 * 64];
  __shared__ float sm1[2][128];
  __shared__ int   smi[2][128];
  __shared__ float sm2[2][128];

  int wgid = blockIdx.x;
  int swz = (wgid & 7) * 1024 + (wgid >> 3);   // XCD-contiguous, bijective
  int rowp = swz >> 5, colp = swz & 31;
  int brow = rowp * 128, bcol = colp * 128;
  int tid = threadIdx.x;
  int lane = tid & 63, w = tid >> 6;
  int wr = w >> 1, wc = w & 1;
  int rl = lane & 15, k8 = lane >> 4;
  int rx = rl & 7;                 // read-side swizzle bits

  f32x4 acc[4][4] = {};

  const char* gA = (const char*)A2;
  const char* gB = (const char*)EH;
  int r0 = tid >> 3, s_slot = tid & 7;
  int s_src = s_slot ^ (r0 & 7);   // pre-swizzled global 16B-seg

  for (int ks = 0; ks < 4; ++ks) {
    __syncthreads();
#pragma unroll
    for (int c = 0; c < 4; ++c) {
      const char* ga = gA + (size_t)(brow + c * 32 + r0) * 512 + ks * 128 + s_src * 16;
      GLOAD(ga, &sA[c * 2048 + tid * 8]);
      const char* gb = gB + (size_t)(bcol + c * 32 + r0) * 512 + ks * 128 + s_src * 16;
      GLOAD(gb, &sB[c * 2048 + tid * 8]);
    }
    __syncthreads();

#pragma unroll
    for (int kb = 0; kb < 2; ++kb) {
      short8 af[4], bfr[4];
      int sseg = ((kb * 4 + k8) ^ rx) * 8;
#pragma unroll
      for (int mi = 0; mi < 4; ++mi)
        af[mi] = *(const short8*)&sA[(wr * 64 + mi * 16 + rl) * 64 + sseg];
#pragma unroll
      for (int ni = 0; ni < 4; ++ni)
        bfr[ni] = *(const short8*)&sB[(wc * 64 + ni * 16 + rl) * 64 + sseg];
#pragma unroll
      for (int mi = 0; mi < 4; ++mi)
#pragma unroll
        for (int ni = 0; ni < 4; ++ni)
          acc[mi][ni] = __builtin_amdgcn_mfma_f32_16x16x32_bf16(
              af[mi], bfr[ni], acc[mi][ni], 0, 0, 0);
    }
  }

  // per-row min1/min2 across this wave's 64-code half (all indices static)
  float e2[4];
#pragma unroll
  for (int ni = 0; ni < 4; ++ni) e2[ni] = e_sq[bcol + wc * 64 + ni * 16 + rl];

#pragma unroll
  for (int mi = 0; mi < 4; ++mi) {
#pragma unroll
    for (int j = 0; j < 4; ++j) {
      float m1 = 1e30f, m2 = 1e30f; int i1 = 0;
#pragma unroll
      for (int ni = 0; ni < 4; ++ni) {
        float q = e2[ni] - 2.0f * acc[mi][ni][j];
        if (q < m1) { m2 = m1; m1 = q; i1 = bcol + wc * 64 + ni * 16 + rl; }
        else if (q < m2) m2 = q;
      }
#pragma unroll
      for (int mk = 8; mk >= 1; mk >>= 1) {
        float v1 = __shfl_xor(m1, mk);
        int   vi = __shfl_xor(i1, mk);
        float v2 = __shfl_xor(m2, mk);
        float hi = fmaxf(m1, v1), lo2 = fminf(m2, v2);
        if (v1 < m1) { m1 = v1; i1 = vi; }
        else if (v1 == m1 && vi < i1) i1 = vi;
        m2 = fminf(hi, lo2);
      }
      if (rl == 0) {
        int rowl = wr * 64 + mi * 16 + k8 * 4 + j;
        sm1[wc][rowl] = m1; smi[wc][rowl] = i1; sm2[wc][rowl] = m2;
      }
    }
  }
  __syncthreads();
  if (tid < 128) {
    float a1 = sm1[0][tid]; int ai = smi[0][tid]; float a2 = sm2[0][tid];
    float b1 = sm1[1][tid]; int bi = smi[1][tid]; float b2 = sm2[1][tid];
    float m1, m2; int i1;
    if (b1 < a1) { m1 = b1; i1 = bi; m2 = fminf(a1, b2); }
    else         { m1 = a1; i1 = ai; m2 = fminf(b1, a2); }  // ties keep smaller idx
    size_t o = (size_t)colp * NROWS + (brow + tid);
    p1[o] = m1; pi[o] = i1; p2[o] = m2;
  }
}

// merge 32 panel partials per row; flag near-ties (init their rescore slot)
__global__ __launch_bounds__(256) void merge_kernel(
    const float* __restrict__ p1, const int* __restrict__ pi,
    const float* __restrict__ p2, int* __restrict__ idx,
    float* __restrict__ out_idxf, int* __restrict__ flist,
    int* __restrict__ flcnt, unsigned long long* __restrict__ slot) {
  int r = blockIdx.x * 256 + threadIdx.x;
  float m1 = 1e30f, m2 = 1e30f; int i1 = 0;
  for (int cb = 0; cb < 32; ++cb) {
    size_t o = (size_t)cb * NROWS + r;
    float v1 = p1[o]; int vi = pi[o]; float v2 = p2[o];
    float hi = fmaxf(m1, v1), lo2 = fminf(m2, v2);
    if (v1 < m1) { m1 = v1; i1 = vi; }
    else if (v1 == m1 && vi < i1) i1 = vi;
    m2 = fminf(hi, lo2);
  }
  idx[r] = i1;
  out_idxf[r] = (float)i1;
  if (m2 - m1 < MARGIN) {
    slot[r] = ~0ULL;
    int p = atomicAdd(flcnt, 1);
    flist[p] = r;
  }
}

// exact fp32 rescore: item = (16-row batch, 1024-code quarter).
// 4 codes x 16 rows register tile; cbT gives coalesced code loads; result
// merged across quarters via packed u64 atomicMin (lexicographic (dist,idx)).
__global__ __launch_bounds__(256) void rescore_partial(
    const float* __restrict__ z, const float* __restrict__ cbT,
    const float* __restrict__ z_sq, const float* __restrict__ e_sq,
    const int* __restrict__ flist, const int* __restrict__ flcnt,
    unsigned long long* __restrict__ slot) {
  __shared__ float zs[16][256];
  __shared__ int   rid[16];
  __shared__ float zq[16];
  __shared__ unsigned long long wred[4][16];
  int t = threadIdx.x;
  int lane = t & 63, w = t >> 6;
  int cnt = *flcnt;
  int nitems = ((cnt + 15) >> 4) << 2;
  for (int it = blockIdx.x; it < nitems; it += gridDim.x) {
    int batch = it >> 2, quarter = it & 3;
    __syncthreads();
    if (t < 16) {
      int fi = batch * 16 + t;
      int rr = flist[fi < cnt ? fi : (cnt - 1)];
      rid[t] = rr; zq[t] = z_sq[rr];
    }
    __syncthreads();
    {
      int r8 = t >> 4, c0 = (t & 15) * 16;
      const float* zp = z + (size_t)rid[r8] * DIM + c0;
#pragma unroll
      for (int i = 0; i < 4; ++i)
        *(float4*)&zs[r8][c0 + i * 4] = *(const float4*)(zp + i * 4);
    }
    __syncthreads();
    int cbase = quarter * 1024 + t * 4;
    float4 es4 = *(const float4*)(e_sq + cbase);
    float a0[16], a1[16], a2[16], a3[16];
#pragma unroll
    for (int r = 0; r < 16; ++r) { a0[r] = 0.f; a1[r] = 0.f; a2[r] = 0.f; a3[r] = 0.f; }
    for (int d = 0; d < DIM; ++d) {
      float4 e = *(const float4*)(cbT + (size_t)d * KCB + cbase);
#pragma unroll
      for (int r = 0; r < 16; ++r) {
        float zv = zs[r][d];
        a0[r] = fmaf(zv, e.x, a0[r]);
        a1[r] = fmaf(zv, e.y, a1[r]);
        a2[r] = fmaf(zv, e.z, a2[r]);
        a3[r] = fmaf(zv, e.w, a3[r]);
      }
    }
#pragma unroll
    for (int r = 0; r < 16; ++r) {
      float d0 = (zq[r] + es4.x) - 2.0f * a0[r];
      float d1 = (zq[r] + es4.y) - 2.0f * a1[r];
      float d2 = (zq[r] + es4.z) - 2.0f * a2[r];
      float d3 = (zq[r] + es4.w) - 2.0f * a3[r];
      float m = d0; int ci = cbase;
      if (d1 < m) { m = d1; ci = cbase + 1; }
      if (d2 < m) { m = d2; ci = cbase + 2; }
      if (d3 < m) { m = d3; ci = cbase + 3; }
      unsigned long long p =
          ((unsigned long long)__float_as_uint(m) << 32) | (unsigned)ci;
#pragma unroll
      for (int mk = 32; mk >= 1; mk >>= 1) {
        unsigned long long q = __shfl_xor(p, mk);
        if (q < p) p = q;
      }
      if (lane == 0) wred[w][r] = p;
    }
    __syncthreads();
    if (t < 16) {
      unsigned long long m = wred[0][t];
      if (wred[1][t] < m) m = wred[1][t];
      if (wred[2][t] < m) m = wred[2][t];
      if (wred[3][t] < m) m = wred[3][t];
      atomicMin(&slot[rid[t]], m);
    }
  }
}

__global__ __launch_bounds__(256) void rescore_final(
    const int* __restrict__ flist, const int* __restrict__ flcnt,
    const unsigned long long* __restrict__ slot,
    int* __restrict__ idx, float* __restrict__ out_idxf) {
  int i = blockIdx.x * 256 + threadIdx.x;
  if (i >= *flcnt) return;
  int r = flist[i];
  int ci = (int)(unsigned)(slot[r] & 0xFFFFFFFFu);
  idx[r] = ci;
  out_idxf[r] = (float)ci;
}

// z_q + straight-through + loss partial (per-block, no global atomic) + counts.
__global__ __launch_bounds__(256) void gather_kernel(
    const float* __restrict__ z, const float* __restrict__ cb,
    const int* __restrict__ idx, float* __restrict__ out_zq,
    int* __restrict__ counts, float* __restrict__ lossp) {
  __shared__ float ls[4];
  int gw = (blockIdx.x * 256 + threadIdx.x) >> 6;
  int lane = threadIdx.x & 63;
  int w = threadIdx.x >> 6;
  int k = idx[gw];
  float4 zq = *(const float4*)(cb + (size_t)k * DIM + lane * 4);
  float4 zv = *(const float4*)(z + (size_t)gw * DIM + lane * 4);
  float4 o;
  o.x = zv.x + (zq.x - zv.x);
  o.y = zv.y + (zq.y - zv.y);
  o.z = zv.z + (zq.z - zv.z);
  o.w = zv.w + (zq.w - zv.w);
  *(float4*)(out_zq + (size_t)gw * DIM + lane * 4) = o;
  float dx = zv.x - zq.x, dy = zv.y - zq.y, dz = zv.z - zq.z, dw = zv.w - zq.w;
  float s = dx * dx + dy * dy + dz * dz + dw * dw;
#pragma unroll
  for (int off = 32; off > 0; off >>= 1) s += __shfl_down(s, off);
  if (lane == 0) {
    ls[w] = s;
    atomicAdd(&counts[k], 1);
  }
  __syncthreads();
  if (threadIdx.x == 0)
    lossp[blockIdx.x] = ls[0] + ls[1] + ls[2] + ls[3];
}

__global__ void prefix_kernel(const int* __restrict__ counts,
                              int* __restrict__ base, int* __restrict__ cursor) {
  __shared__ int part[256];
  __shared__ int pre[256];
  int t = threadIdx.x;
  int loc[16]; int s = 0;
#pragma unroll
  for (int i = 0; i < 16; ++i) { loc[i] = counts[t * 16 + i]; s += loc[i]; }
  part[t] = s;
  __syncthreads();
  if (t == 0) { int a = 0; for (int i = 0; i < 256; ++i) { pre[i] = a; a += part[i]; } }
  __syncthreads();
  int a = pre[t];
#pragma unroll
  for (int i = 0; i < 16; ++i) { base[t * 16 + i] = a; cursor[t * 16 + i] = a; a += loc[i]; }
}

__global__ void scatter_kernel(const int* __restrict__ idx,
                               int* __restrict__ cursor, int* __restrict__ list2) {
  int n = blockIdx.x * 256 + threadIdx.x;
  int k = idx[n];
  int p = atomicAdd(&cursor[k], 1);
  list2[p] = n;
}

// per-code: sum assigned z rows (inverted index), EMA update, outputs
__global__ __launch_bounds__(256) void finalize_codes(
    const float* __restrict__ ema_cs, const float* __restrict__ ema_es,
    const int* __restrict__ counts, const int* __restrict__ base,
    const int* __restrict__ list2, const float* __restrict__ z,
    float* __restrict__ out_cb, float* __restrict__ out_cs,
    float* __restrict__ out_es) {
  int gw = (blockIdx.x * 256 + threadIdx.x) >> 6;
  int lane = threadIdx.x & 63;
  int cnt = counts[gw], b0 = base[gw];
  float sx = 0.f, sy = 0.f, sz = 0.f, sw = 0.f;
  for (int i = 0; i < cnt; ++i) {
    int n = list2[b0 + i];
    float4 v = *(const float4*)(z + (size_t)n * DIM + lane * 4);
    sx += v.x; sy += v.y; sz += v.z; sw += v.w;
  }
  const float omd = 1.0f - DECAYF;
  float cntf = (float)cnt;
  float ncs = ema_cs[gw] * DECAYF + omd * cntf;
  float nden = ncs + 0.04096f;
  if (lane == 0) out_cs[gw] = ncs;
  size_t o = (size_t)gw * DIM + lane * 4;
  float4 em = *(const float4*)(ema_es + o);
  float nex = em.x * DECAYF + omd * sx;
  float ney = em.y * DECAYF + omd * sy;
  float nez = em.z * DECAYF + omd * sz;
  float new_ = em.w * DECAYF + omd * sw;
  *(float2*)(out_es + o) = make_float2(nex, ney);
  *(float2*)(out_es + o + 2) = make_float2(nez, new_);
  *(float2*)(out_cb + o) = make_float2(nex / nden, ney / nden);
  *(float2*)(out_cb + o + 2) = make_float2(nez / nden, new_ / nden);
}

// one block: reduce 8192 loss partials + entropy from counts
__global__ __launch_bounds__(256) void finalize_scalars(
    const float* __restrict__ lossp, const int* __restrict__ counts,
    float* __restrict__ out_loss, float* __restrict__ out_ppl) {
  __shared__ float red[256];
  int t = threadIdx.x;
  float s = 0.f;
  for (int i = t; i < 8192; i += 256) s += lossp[i];
  float e = 0.f;
  for (int i = t; i < 4096; i += 256) {
    float p = (float)counts[i] * (1.0f / (float)NROWS);
    e -= p * logf(p + 1e-12f);
  }
  red[t] = s;
  __syncthreads();
  for (int st = 128; st > 0; st >>= 1) {
    if (t < st) red[t] += red[t + st];
    __syncthreads();
  }
  float loss_tot = red[0];
  __syncthreads();
  red[t] = e;
  __syncthreads();
  for (int st = 128; st > 0; st >>= 1) {
    if (t < st) red[t] += red[t + st];
    __syncthreads();
  }
  if (t == 0) {
    out_loss[0] = 0.25f * (loss_tot / 8388608.0f);
    out_ppl[0] = expf(red[0]);
  }
}

extern "C" void kernel_launch(void* const* d_in, const int* in_sizes, int n_in,
                              void* d_out, int out_size, void* d_ws, size_t ws_size,
                              hipStream_t stream) {
  (void)in_sizes; (void)n_in; (void)out_size; (void)ws_size;
  const float* z      = (const float*)d_in[0];
  const float* cb     = (const float*)d_in[1];
  const float* ema_cs = (const float*)d_in[2];
  const float* ema_es = (const float*)d_in[3];
  float* out = (float*)d_out;
  char*  ws  = (char*)d_ws;

  unsigned short* A2 = (unsigned short*)(ws + WS_A2);
  unsigned short* EH = (unsigned short*)(ws + WS_EH);
  float* z_sq  = (float*)(ws + WS_ZSQ);
  float* e_sq  = (float*)(ws + WS_ESQ);
  float* p1    = (float*)(ws + WS_P1);
  int*   pi    = (int*)(ws + WS_PI);
  float* p2    = (float*)(ws + WS_P2);
  float* lossp = (float*)(ws + WS_P2);   // reuse: dead after merge_kernel
  unsigned long long* slot = (unsigned long long*)(ws + WS_SLOT);  // A2 reuse
  float* cbT   = (float*)(ws + WS_CBT);                            // A2 reuse
  int*   idx   = (int*)(ws + WS_IDX);
  int*   flist = (int*)(ws + WS_FLIST);
  int*   list2 = (int*)(ws + WS_LIST2);
  int*   base  = (int*)(ws + WS_BASE);
  int*   counts = (int*)(ws + WS_COUNTS);
  int*   cursor = (int*)(ws + WS_CURSOR);
  int*   flcnt  = (int*)(ws + WS_FLCNT);

  hipMemsetAsync(ws + WS_ZERO, 0, WS_ZEROLEN, stream);

  prep_z<<<NROWS / 4, 256, 0, stream>>>(z, A2, z_sq);
  prep_e<<<KCB / 4, 256, 0, stream>>>(cb, EH, e_sq);
  dist_mfma<<<(NROWS / 128) * (KCB / 128), 256, 0, stream>>>(A2, EH, e_sq,
                                                             p1, pi, p2);
  tp_cb<<<KCB / 32, 256, 0, stream>>>(cb, cbT);            // A2 dead from here
  merge_kernel<<<NROWS / 256, 256, 0, stream>>>(p1, pi, p2, idx,
                                                out + OUT_IDX, flist, flcnt,
                                                slot);
  rescore_partial<<<2048, 256, 0, stream>>>(z, cbT, z_sq, e_sq, flist, flcnt,
                                            slot);
  rescore_final<<<NROWS / 256, 256, 0, stream>>>(flist, flcnt, slot, idx,
                                                 out + OUT_IDX);
  gather_kernel<<<NROWS / 4, 256, 0, stream>>>(z, cb, idx, out + OUT_ZQ,
                                               counts, lossp);
  prefix_kernel<<<1, 256, 0, stream>>>(counts, base, cursor);
  scatter_kernel<<<NROWS / 256, 256, 0, stream>>>(idx, cursor, list2);
  finalize_codes<<<KCB / 4, 256, 0, stream>>>(ema_cs, ema_es, counts, base,
                                              list2, z, out + OUT_CB,
                                              out + OUT_CS, out + OUT_ES);
  finalize_scalars<<<1, 256, 0, stream>>>(lossp, counts, out + OUT_LOSS,
                                          out + OUT_PPL);
}

// Round 8
// 306.252 us; speedup vs baseline: 11.9561x; 1.1371x over previous
//
#include <hip/hip_runtime.h>
#include <hip/hip_bf16.h>
#include <math.h>

#define DIM    256
#define KCB    4096
#define NROWS  32768
#define DECAYF 0.99f
#define MARGIN 0.03f

// ---- d_out offsets (in floats) ----
#define OUT_ZQ   0
#define OUT_IDX  8388608
#define OUT_LOSS 8421376
#define OUT_PPL  8421377
#define OUT_CB   8421378
#define OUT_CS   9469954
#define OUT_ES   9474050

// ---- d_ws offsets (bytes) ----
#define WS_A2      0u            // [32768][256] bf16 (hi only) 16 MB; dead after
                                 // dist_mfma -> reused: slot[] (+0), cbT (+1MB)
#define WS_EH      33554432u     // [4096][256] bf16            2 MB
#define WS_ZSQ     35651584u     // N f32
#define WS_ESQ     35782656u     // K f32
#define WS_P1      35799040u     // [32][32768] f32 partial min1
#define WS_PI      39993344u     // [32][32768] i32 partial idx1
#define WS_P2      44187648u     // [32][32768] f32 partial min2 (dead after
                                 // merge_kernel -> reused for loss partials)
#define WS_IDX     48381952u     // N i32 final idx
#define WS_FLIST   48513024u     // N i32 flagged rows
#define WS_LIST2   48644096u     // N i32 inverted index
#define WS_BASE    48775168u     // K i32
#define WS_ZERO    48791552u     // zeroed region start
#define WS_COUNTS  48791552u     // K i32
#define WS_CURSOR  48807936u     // K i32
#define WS_FLCNT   48824320u
#define WS_ZEROLEN 32772u

#define WS_SLOT    WS_A2                 // N u64 packed (distbits<<32)|idx
#define WS_CBT     (WS_A2 + 1048576u)    // [256][4096] f32 transposed codebook

typedef __attribute__((ext_vector_type(8))) short short8;
typedef __attribute__((ext_vector_type(4))) float f32x4;

#define GLOAD(g, l) __builtin_amdgcn_global_load_lds( \
    (const __attribute__((address_space(1))) unsigned int*)(g), \
    (__attribute__((address_space(3))) unsigned int*)(l), 16, 0, 0)

__device__ __forceinline__ unsigned short f2bf(float x) {
  __hip_bfloat16 h = __float2bfloat16(x);
  return *reinterpret_cast<unsigned short*>(&h);
}

// z -> A2 = z_hi bf16, plus z_sq.  One wave per row.
__global__ __launch_bounds__(256) void prep_z(
    const float* __restrict__ z, unsigned short* __restrict__ A2,
    float* __restrict__ z_sq) {
  int gw = (blockIdx.x * 256 + threadIdx.x) >> 6;
  int lane = threadIdx.x & 63;
  float4 v = *(const float4*)(z + (size_t)gw * DIM + lane * 4);
  float x[4] = {v.x, v.y, v.z, v.w};
  unsigned short h[4];
  float ss = 0.f;
#pragma unroll
  for (int i = 0; i < 4; ++i) { ss += x[i] * x[i]; h[i] = f2bf(x[i]); }
  *(ushort4*)(A2 + (size_t)gw * 256 + lane * 4) =
      make_ushort4(h[0], h[1], h[2], h[3]);
#pragma unroll
  for (int off = 32; off > 0; off >>= 1) ss += __shfl_down(ss, off);
  if (lane == 0) z_sq[gw] = ss;
}

// codebook -> EH bf16 + e_sq (from fp32).  One wave per code.
__global__ __launch_bounds__(256) void prep_e(
    const float* __restrict__ cb, unsigned short* __restrict__ EH,
    float* __restrict__ e_sq) {
  int gw = (blockIdx.x * 256 + threadIdx.x) >> 6;
  int lane = threadIdx.x & 63;
  float4 v = *(const float4*)(cb + (size_t)gw * DIM + lane * 4);
  float x[4] = {v.x, v.y, v.z, v.w};
  unsigned short h[4];
  float ss = 0.f;
#pragma unroll
  for (int i = 0; i < 4; ++i) { ss += x[i] * x[i]; h[i] = f2bf(x[i]); }
  *(ushort4*)(EH + (size_t)gw * 256 + lane * 4) =
      make_ushort4(h[0], h[1], h[2], h[3]);
#pragma unroll
  for (int off = 32; off > 0; off >>= 1) ss += __shfl_down(ss, off);
  if (lane == 0) e_sq[gw] = ss;
}

// cb[4096][256] -> cbT[256][4096], 32-code LDS tiles (pad 257 kills conflicts)
__global__ __launch_bounds__(256) void tp_cb(
    const float* __restrict__ cb, float* __restrict__ cbT) {
  __shared__ float tile[32][257];
  int c0 = blockIdx.x * 32;
  int t = threadIdx.x;
  int r = t >> 6, c4 = (t & 63) * 4;
#pragma unroll
  for (int i = 0; i < 8; ++i) {
    float4 v = *(const float4*)(cb + (size_t)(c0 + r + i * 4) * DIM + c4);
    tile[r + i * 4][c4 + 0] = v.x;
    tile[r + i * 4][c4 + 1] = v.y;
    tile[r + i * 4][c4 + 2] = v.z;
    tile[r + i * 4][c4 + 3] = v.w;
  }
  __syncthreads();
  int cs = (t & 7) * 4;
#pragma unroll
  for (int j = 0; j < 8; ++j) {
    int d = (t >> 3) + j * 32;
    float4 w = make_float4(tile[cs][d], tile[cs + 1][d],
                           tile[cs + 2][d], tile[cs + 3][d]);
    *(float4*)(cbT + (size_t)d * KCB + c0 + cs) = w;
  }
}

// 128x128 tile bf16 MFMA over K=256, 2-phase double-buffered staging
// (T3-minimum: STAGE(next) -> compute(cur) -> vmcnt(0) -> s_barrier), LDS
// XOR-swizzle (verified conflict-free).  SWAPPED operands: D row=code,
// col=z-row, so the per-row argmin axis is lane-local (16 codes in-register,
// only 2 shfl stages across the k8 group).
__global__ __launch_bounds__(256) void dist_mfma(
    const unsigned short* __restrict__ A2, const unsigned short* __restrict__ EH,
    const float* __restrict__ e_sq,
    float* __restrict__ p1, int* __restrict__ pi, float* __restrict__ p2) {
  __shared__ __align__(16) unsigned short sZ[2][128 * 64];
  __shared__ __align__(16) unsigned short sE[2][128 * 64];
  __shared__ float se[128];
  __shared__ float sm1[2][128];
  __shared__ int   smi[2][128];
  __shared__ float sm2[2][128];

  int wgid = blockIdx.x;
  int swz = (wgid & 7) * 1024 + (wgid >> 3);   // XCD-contiguous, bijective
  int rowp = swz >> 5, colp = swz & 31;
  int brow = rowp * 128, bcol = colp * 128;
  int tid = threadIdx.x;
  int lane = tid & 63, w = tid >> 6;
  int wr = w >> 1, wc = w & 1;
  int rl = lane & 15, k8 = lane >> 4;

  f32x4 acc[4][4] = {};

  const char* gA = (const char*)A2;
  const char* gB = (const char*)EH;
  int r0 = tid >> 3, s_slot = tid & 7;
  int s_src = s_slot ^ (r0 & 7);   // pre-swizzled global 16B-seg

#define STAGE(b, ks) do {                                                     \
    _Pragma("unroll")                                                         \
    for (int c = 0; c < 4; ++c) {                                             \
      GLOAD(gA + (size_t)(brow + c * 32 + r0) * 512 + (ks) * 128 + s_src * 16,\
            &sZ[b][c * 2048 + tid * 8]);                                      \
      GLOAD(gB + (size_t)(bcol + c * 32 + r0) * 512 + (ks) * 128 + s_src * 16,\
            &sE[b][c * 2048 + tid * 8]);                                      \
    }                                                                         \
  } while (0)

  if (tid < 128) se[tid] = e_sq[bcol + tid];
  STAGE(0, 0);
  asm volatile("s_waitcnt vmcnt(0) lgkmcnt(0)" ::: "memory");
  __builtin_amdgcn_s_barrier();

#pragma unroll
  for (int ks = 0; ks < 4; ++ks) {
    int cur = ks & 1;
    if (ks < 3) STAGE(cur ^ 1, ks + 1);
    const unsigned short* za = sZ[cur];
    const unsigned short* ea = sE[cur];
#pragma unroll
    for (int kb = 0; kb < 2; ++kb) {
      short8 ef[4], zf[4];
      int sseg = ((kb * 4 + k8) ^ (rl & 7)) * 8;
#pragma unroll
      for (int mi = 0; mi < 4; ++mi)
        ef[mi] = *(const short8*)&ea[(wr * 64 + mi * 16 + rl) * 64 + sseg];
#pragma unroll
      for (int ni = 0; ni < 4; ++ni)
        zf[ni] = *(const short8*)&za[(wc * 64 + ni * 16 + rl) * 64 + sseg];
#pragma unroll
      for (int mi = 0; mi < 4; ++mi)
#pragma unroll
        for (int ni = 0; ni < 4; ++ni)
          acc[mi][ni] = __builtin_amdgcn_mfma_f32_16x16x32_bf16(
              ef[mi], zf[ni], acc[mi][ni], 0, 0, 0);
    }
    asm volatile("s_waitcnt vmcnt(0)" ::: "memory");
    __builtin_amdgcn_s_barrier();
  }
#undef STAGE

  // e_sq for this lane's 16 in-register codes (code = cb0 + mi*16 + j)
  int cb0 = bcol + wr * 64 + k8 * 4;
  float e2l[4][4];
#pragma unroll
  for (int mi = 0; mi < 4; ++mi)
#pragma unroll
    for (int j = 0; j < 4; ++j)
      e2l[mi][j] = se[wr * 64 + mi * 16 + k8 * 4 + j];

  // per z-row (ni, rl): in-lane scan of 16 codes, then 2-stage k8 reduce
#pragma unroll
  for (int ni = 0; ni < 4; ++ni) {
    float m1 = 1e30f, m2 = 1e30f; int i1 = 0;
#pragma unroll
    for (int mi = 0; mi < 4; ++mi) {
#pragma unroll
      for (int j = 0; j < 4; ++j) {
        float q = e2l[mi][j] - 2.0f * acc[mi][ni][j];
        if (q < m1) { m2 = m1; m1 = q; i1 = cb0 + mi * 16 + j; }
        else if (q < m2) m2 = q;
      }
    }
#pragma unroll
    for (int mk = 16; mk <= 32; mk <<= 1) {
      float v1 = __shfl_xor(m1, mk);
      int   vi = __shfl_xor(i1, mk);
      float v2 = __shfl_xor(m2, mk);
      float hi = fmaxf(m1, v1), lo2 = fminf(m2, v2);
      if (v1 < m1) { m1 = v1; i1 = vi; }
      else if (v1 == m1 && vi < i1) i1 = vi;
      m2 = fminf(hi, lo2);
    }
    if (k8 == 0) {
      int rowl = wc * 64 + ni * 16 + rl;
      sm1[wr][rowl] = m1; smi[wr][rowl] = i1; sm2[wr][rowl] = m2;
    }
  }
  __syncthreads();
  if (tid < 128) {
    float a1 = sm1[0][tid]; int ai = smi[0][tid]; float a2 = sm2[0][tid];
    float b1 = sm1[1][tid]; int bi = smi[1][tid]; float b2 = sm2[1][tid];
    float m1, m2; int i1;
    if (b1 < a1) { m1 = b1; i1 = bi; m2 = fminf(a1, b2); }
    else         { m1 = a1; i1 = ai; m2 = fminf(b1, a2); }  // ties keep smaller idx
    size_t o = (size_t)colp * NROWS + (brow + tid);
    p1[o] = m1; pi[o] = i1; p2[o] = m2;
  }
}

// merge 32 panel partials per row; flag near-ties (init their rescore slot)
__global__ __launch_bounds__(256) void merge_kernel(
    const float* __restrict__ p1, const int* __restrict__ pi,
    const float* __restrict__ p2, int* __restrict__ idx,
    float* __restrict__ out_idxf, int* __restrict__ flist,
    int* __restrict__ flcnt, unsigned long long* __restrict__ slot) {
  int r = blockIdx.x * 256 + threadIdx.x;
  float m1 = 1e30f, m2 = 1e30f; int i1 = 0;
  for (int cb = 0; cb < 32; ++cb) {
    size_t o = (size_t)cb * NROWS + r;
    float v1 = p1[o]; int vi = pi[o]; float v2 = p2[o];
    float hi = fmaxf(m1, v1), lo2 = fminf(m2, v2);
    if (v1 < m1) { m1 = v1; i1 = vi; }
    else if (v1 == m1 && vi < i1) i1 = vi;
    m2 = fminf(hi, lo2);
  }
  idx[r] = i1;
  out_idxf[r] = (float)i1;
  if (m2 - m1 < MARGIN) {
    slot[r] = ~0ULL;
    int p = atomicAdd(flcnt, 1);
    flist[p] = r;
  }
}

// exact fp32 rescore: item = (16-row batch, 1024-code quarter).
__global__ __launch_bounds__(256) void rescore_partial(
    const float* __restrict__ z, const float* __restrict__ cbT,
    const float* __restrict__ z_sq, const float* __restrict__ e_sq,
    const int* __restrict__ flist, const int* __restrict__ flcnt,
    unsigned long long* __restrict__ slot) {
  __shared__ float zs[16][256];
  __shared__ int   rid[16];
  __shared__ float zq[16];
  __shared__ unsigned long long wred[4][16];
  int t = threadIdx.x;
  int lane = t & 63, w = t >> 6;
  int cnt = *flcnt;
  int nitems = ((cnt + 15) >> 4) << 2;
  for (int it = blockIdx.x; it < nitems; it += gridDim.x) {
    int batch = it >> 2, quarter = it & 3;
    __syncthreads();
    if (t < 16) {
      int fi = batch * 16 + t;
      int rr = flist[fi < cnt ? fi : (cnt - 1)];
      rid[t] = rr; zq[t] = z_sq[rr];
    }
    __syncthreads();
    {
      int r8 = t >> 4, c0 = (t & 15) * 16;
      const float* zp = z + (size_t)rid[r8] * DIM + c0;
#pragma unroll
      for (int i = 0; i < 4; ++i)
        *(float4*)&zs[r8][c0 + i * 4] = *(const float4*)(zp + i * 4);
    }
    __syncthreads();
    int cbase = quarter * 1024 + t * 4;
    float4 es4 = *(const float4*)(e_sq + cbase);
    float a0[16], a1[16], a2[16], a3[16];
#pragma unroll
    for (int r = 0; r < 16; ++r) { a0[r] = 0.f; a1[r] = 0.f; a2[r] = 0.f; a3[r] = 0.f; }
    for (int d = 0; d < DIM; ++d) {
      float4 e = *(const float4*)(cbT + (size_t)d * KCB + cbase);
#pragma unroll
      for (int r = 0; r < 16; ++r) {
        float zv = zs[r][d];
        a0[r] = fmaf(zv, e.x, a0[r]);
        a1[r] = fmaf(zv, e.y, a1[r]);
        a2[r] = fmaf(zv, e.z, a2[r]);
        a3[r] = fmaf(zv, e.w, a3[r]);
      }
    }
#pragma unroll
    for (int r = 0; r < 16; ++r) {
      float d0 = (zq[r] + es4.x) - 2.0f * a0[r];
      float d1 = (zq[r] + es4.y) - 2.0f * a1[r];
      float d2 = (zq[r] + es4.z) - 2.0f * a2[r];
      float d3 = (zq[r] + es4.w) - 2.0f * a3[r];
      float m = d0; int ci = cbase;
      if (d1 < m) { m = d1; ci = cbase + 1; }
      if (d2 < m) { m = d2; ci = cbase + 2; }
      if (d3 < m) { m = d3; ci = cbase + 3; }
      unsigned long long p =
          ((unsigned long long)__float_as_uint(m) << 32) | (unsigned)ci;
#pragma unroll
      for (int mk = 32; mk >= 1; mk >>= 1) {
        unsigned long long q = __shfl_xor(p, mk);
        if (q < p) p = q;
      }
      if (lane == 0) wred[w][r] = p;
    }
    __syncthreads();
    if (t < 16) {
      unsigned long long m = wred[0][t];
      if (wred[1][t] < m) m = wred[1][t];
      if (wred[2][t] < m) m = wred[2][t];
      if (wred[3][t] < m) m = wred[3][t];
      atomicMin(&slot[rid[t]], m);
    }
  }
}

__global__ __launch_bounds__(256) void rescore_final(
    const int* __restrict__ flist, const int* __restrict__ flcnt,
    const unsigned long long* __restrict__ slot,
    int* __restrict__ idx, float* __restrict__ out_idxf) {
  int i = blockIdx.x * 256 + threadIdx.x;
  if (i >= *flcnt) return;
  int r = flist[i];
  int ci = (int)(unsigned)(slot[r] & 0xFFFFFFFFu);
  idx[r] = ci;
  out_idxf[r] = (float)ci;
}

// z_q + straight-through + loss partial (per-block, no global atomic) + counts.
__global__ __launch_bounds__(256) void gather_kernel(
    const float* __restrict__ z, const float* __restrict__ cb,
    const int* __restrict__ idx, float* __restrict__ out_zq,
    int* __restrict__ counts, float* __restrict__ lossp) {
  __shared__ float ls[4];
  int gw = (blockIdx.x * 256 + threadIdx.x) >> 6;
  int lane = threadIdx.x & 63;
  int w = threadIdx.x >> 6;
  int k = idx[gw];
  float4 zq = *(const float4*)(cb + (size_t)k * DIM + lane * 4);
  float4 zv = *(const float4*)(z + (size_t)gw * DIM + lane * 4);
  float4 o;
  o.x = zv.x + (zq.x - zv.x);
  o.y = zv.y + (zq.y - zv.y);
  o.z = zv.z + (zq.z - zv.z);
  o.w = zv.w + (zq.w - zv.w);
  *(float4*)(out_zq + (size_t)gw * DIM + lane * 4) = o;
  float dx = zv.x - zq.x, dy = zv.y - zq.y, dz = zv.z - zq.z, dw = zv.w - zq.w;
  float s = dx * dx + dy * dy + dz * dz + dw * dw;
#pragma unroll
  for (int off = 32; off > 0; off >>= 1) s += __shfl_down(s, off);
  if (lane == 0) {
    ls[w] = s;
    atomicAdd(&counts[k], 1);
  }
  __syncthreads();
  if (threadIdx.x == 0)
    lossp[blockIdx.x] = ls[0] + ls[1] + ls[2] + ls[3];
}

__global__ void prefix_kernel(const int* __restrict__ counts,
                              int* __restrict__ base, int* __restrict__ cursor) {
  __shared__ int part[256];
  __shared__ int pre[256];
  int t = threadIdx.x;
  int loc[16]; int s = 0;
#pragma unroll
  for (int i = 0; i < 16; ++i) { loc[i] = counts[t * 16 + i]; s += loc[i]; }
  part[t] = s;
  __syncthreads();
  if (t == 0) { int a = 0; for (int i = 0; i < 256; ++i) { pre[i] = a; a += part[i]; } }
  __syncthreads();
  int a = pre[t];
#pragma unroll
  for (int i = 0; i < 16; ++i) { base[t * 16 + i] = a; cursor[t * 16 + i] = a; a += loc[i]; }
}

__global__ void scatter_kernel(const int* __restrict__ idx,
                               int* __restrict__ cursor, int* __restrict__ list2) {
  int n = blockIdx.x * 256 + threadIdx.x;
  int k = idx[n];
  int p = atomicAdd(&cursor[k], 1);
  list2[p] = n;
}

// per-code: sum assigned z rows (inverted index), EMA update, outputs
__global__ __launch_bounds__(256) void finalize_codes(
    const float* __restrict__ ema_cs, const float* __restrict__ ema_es,
    const int* __restrict__ counts, const int* __restrict__ base,
    const int* __restrict__ list2, const float* __restrict__ z,
    float* __restrict__ out_cb, float* __restrict__ out_cs,
    float* __restrict__ out_es) {
  int gw = (blockIdx.x * 256 + threadIdx.x) >> 6;
  int lane = threadIdx.x & 63;
  int cnt = counts[gw], b0 = base[gw];
  float sx = 0.f, sy = 0.f, sz = 0.f, sw = 0.f;
  for (int i = 0; i < cnt; ++i) {
    int n = list2[b0 + i];
    float4 v = *(const float4*)(z + (size_t)n * DIM + lane * 4);
    sx += v.x; sy += v.y; sz += v.z; sw += v.w;
  }
  const float omd = 1.0f - DECAYF;
  float cntf = (float)cnt;
  float ncs = ema_cs[gw] * DECAYF + omd * cntf;
  float nden = ncs + 0.04096f;
  if (lane == 0) out_cs[gw] = ncs;
  size_t o = (size_t)gw * DIM + lane * 4;
  float4 em = *(const float4*)(ema_es + o);
  float nex = em.x * DECAYF + omd * sx;
  float ney = em.y * DECAYF + omd * sy;
  float nez = em.z * DECAYF + omd * sz;
  float new_ = em.w * DECAYF + omd * sw;
  *(float2*)(out_es + o) = make_float2(nex, ney);
  *(float2*)(out_es + o + 2) = make_float2(nez, new_);
  *(float2*)(out_cb + o) = make_float2(nex / nden, ney / nden);
  *(float2*)(out_cb + o + 2) = make_float2(nez / nden, new_ / nden);
}

// one block: reduce 8192 loss partials + entropy from counts
__global__ __launch_bounds__(256) void finalize_scalars(
    const float* __restrict__ lossp, const int* __restrict__ counts,
    float* __restrict__ out_loss, float* __restrict__ out_ppl) {
  __shared__ float red[256];
  int t = threadIdx.x;
  float s = 0.f;
  for (int i = t; i < 8192; i += 256) s += lossp[i];
  float e = 0.f;
  for (int i = t; i < 4096; i += 256) {
    float p = (float)counts[i] * (1.0f / (float)NROWS);
    e -= p * logf(p + 1e-12f);
  }
  red[t] = s;
  __syncthreads();
  for (int st = 128; st > 0; st >>= 1) {
    if (t < st) red[t] += red[t + st];
    __syncthreads();
  }
  float loss_tot = red[0];
  __syncthreads();
  red[t] = e;
  __syncthreads();
  for (int st = 128; st > 0; st >>= 1) {
    if (t < st) red[t] += red[t + st];
    __syncthreads();
  }
  if (t == 0) {
    out_loss[0] = 0.25f * (loss_tot / 8388608.0f);
    out_ppl[0] = expf(red[0]);
  }
}

extern "C" void kernel_launch(void* const* d_in, const int* in_sizes, int n_in,
                              void* d_out, int out_size, void* d_ws, size_t ws_size,
                              hipStream_t stream) {
  (void)in_sizes; (void)n_in; (void)out_size; (void)ws_size;
  const float* z      = (const float*)d_in[0];
  const float* cb     = (const float*)d_in[1];
  const float* ema_cs = (const float*)d_in[2];
  const float* ema_es = (const float*)d_in[3];
  float* out = (float*)d_out;
  char*  ws  = (char*)d_ws;

  unsigned short* A2 = (unsigned short*)(ws + WS_A2);
  unsigned short* EH = (unsigned short*)(ws + WS_EH);
  float* z_sq  = (float*)(ws + WS_ZSQ);
  float* e_sq  = (float*)(ws + WS_ESQ);
  float* p1    = (float*)(ws + WS_P1);
  int*   pi    = (int*)(ws + WS_PI);
  float* p2    = (float*)(ws + WS_P2);
  float* lossp = (float*)(ws + WS_P2);   // reuse: dead after merge_kernel
  unsigned long long* slot = (unsigned long long*)(ws + WS_SLOT);  // A2 reuse
  float* cbT   = (float*)(ws + WS_CBT);                            // A2 reuse
  int*   idx   = (int*)(ws + WS_IDX);
  int*   flist = (int*)(ws + WS_FLIST);
  int*   list2 = (int*)(ws + WS_LIST2);
  int*   base  = (int*)(ws + WS_BASE);
  int*   counts = (int*)(ws + WS_COUNTS);
  int*   cursor = (int*)(ws + WS_CURSOR);
  int*   flcnt  = (int*)(ws + WS_FLCNT);

  hipMemsetAsync(ws + WS_ZERO, 0, WS_ZEROLEN, stream);

  prep_z<<<NROWS / 4, 256, 0, stream>>>(z, A2, z_sq);
  prep_e<<<KCB / 4, 256, 0, stream>>>(cb, EH, e_sq);
  dist_mfma<<<(NROWS / 128) * (KCB / 128), 256, 0, stream>>>(A2, EH, e_sq,
                                                             p1, pi, p2);
  tp_cb<<<KCB / 32, 256, 0, stream>>>(cb, cbT);            // A2 dead from here
  merge_kernel<<<NROWS / 256, 256, 0, stream>>>(p1, pi, p2, idx,
                                                out + OUT_IDX, flist, flcnt,
                                                slot);
  rescore_partial<<<2048, 256, 0, stream>>>(z, cbT, z_sq, e_sq, flist, flcnt,
                                            slot);
  rescore_final<<<NROWS / 256, 256, 0, stream>>>(flist, flcnt, slot, idx,
                                                 out + OUT_IDX);
  gather_kernel<<<NROWS / 4, 256, 0, stream>>>(z, cb, idx, out + OUT_ZQ,
                                               counts, lossp);
  prefix_kernel<<<1, 256, 0, stream>>>(counts, base, cursor);
  scatter_kernel<<<NROWS / 256, 256, 0, stream>>>(idx, cursor, list2);
  finalize_codes<<<KCB / 4, 256, 0, stream>>>(ema_cs, ema_es, counts, base,
                                              list2, z, out + OUT_CB,
                                              out + OUT_CS, out + OUT_ES);
  finalize_scalars<<<1, 256, 0, stream>>>(lossp, counts, out + OUT_LOSS,
                                          out + OUT_PPL);
}

// Round 10
// 286.575 us; speedup vs baseline: 12.7771x; 1.0687x over previous
//
#include <hip/hip_runtime.h>
#include <hip/hip_bf16.h>
#include <math.h>

#define DIM    256
#define KCB    4096
#define NROWS  32768
#define DECAYF 0.99f
#define MARGIN 0.03f

// ---- d_out offsets (in floats) ----
#define OUT_ZQ   0
#define OUT_IDX  8388608
#define OUT_LOSS 8421376
#define OUT_PPL  8421377
#define OUT_CB   8421378
#define OUT_CS   9469954
#define OUT_ES   9474050

// ---- d_ws offsets (bytes) ----
#define WS_A2      0u            // [32768][256] bf16 (hi only) 16 MB; dead after
                                 // dist_mfma -> reused: slot[] (+0), cbT (+1MB)
#define WS_EH      33554432u     // [4096][256] bf16            2 MB
#define WS_ZSQ     35651584u     // N f32
#define WS_ESQ     35782656u     // K f32
#define WS_P1      35799040u     // [32][32768] f32 partial min1
#define WS_PI      39993344u     // [32][32768] i32 partial idx1
#define WS_P2      44187648u     // [32][32768] f32 partial min2 (dead after
                                 // merge_kernel -> reused for loss partials)
#define WS_IDX     48381952u     // N i32 final idx
#define WS_FLIST   48513024u     // N i32 flagged rows
#define WS_LIST2   48644096u     // N i32 inverted index
#define WS_BASE    48775168u     // K i32
#define WS_ZERO    48791552u     // zeroed region start
#define WS_COUNTS  48791552u     // K i32
#define WS_CURSOR  48807936u     // K i32
#define WS_FLCNT   48824320u
#define WS_ZEROLEN 32772u

#define WS_SLOT    WS_A2                 // N u64 packed (distbits<<32)|idx
#define WS_CBT     (WS_A2 + 1048576u)    // [256][4096] f32 transposed codebook

typedef __attribute__((ext_vector_type(8))) short short8;
typedef __attribute__((ext_vector_type(4))) float f32x4;

#define GLOAD(g, l) __builtin_amdgcn_global_load_lds( \
    (const __attribute__((address_space(1))) unsigned int*)(g), \
    (__attribute__((address_space(3))) unsigned int*)(l), 16, 0, 0)

__device__ __forceinline__ unsigned short f2bf(float x) {
  __hip_bfloat16 h = __float2bfloat16(x);
  return *reinterpret_cast<unsigned short*>(&h);
}

// z -> A2 = z_hi bf16, plus z_sq.  One wave per row.
__global__ __launch_bounds__(256) void prep_z(
    const float* __restrict__ z, unsigned short* __restrict__ A2,
    float* __restrict__ z_sq) {
  int gw = (blockIdx.x * 256 + threadIdx.x) >> 6;
  int lane = threadIdx.x & 63;
  float4 v = *(const float4*)(z + (size_t)gw * DIM + lane * 4);
  float x[4] = {v.x, v.y, v.z, v.w};
  unsigned short h[4];
  float ss = 0.f;
#pragma unroll
  for (int i = 0; i < 4; ++i) { ss += x[i] * x[i]; h[i] = f2bf(x[i]); }
  *(ushort4*)(A2 + (size_t)gw * 256 + lane * 4) =
      make_ushort4(h[0], h[1], h[2], h[3]);
#pragma unroll
  for (int off = 32; off > 0; off >>= 1) ss += __shfl_down(ss, off);
  if (lane == 0) z_sq[gw] = ss;
}

// codebook -> EH bf16 + e_sq (from fp32).  One wave per code.
__global__ __launch_bounds__(256) void prep_e(
    const float* __restrict__ cb, unsigned short* __restrict__ EH,
    float* __restrict__ e_sq) {
  int gw = (blockIdx.x * 256 + threadIdx.x) >> 6;
  int lane = threadIdx.x & 63;
  float4 v = *(const float4*)(cb + (size_t)gw * DIM + lane * 4);
  float x[4] = {v.x, v.y, v.z, v.w};
  unsigned short h[4];
  float ss = 0.f;
#pragma unroll
  for (int i = 0; i < 4; ++i) { ss += x[i] * x[i]; h[i] = f2bf(x[i]); }
  *(ushort4*)(EH + (size_t)gw * 256 + lane * 4) =
      make_ushort4(h[0], h[1], h[2], h[3]);
#pragma unroll
  for (int off = 32; off > 0; off >>= 1) ss += __shfl_down(ss, off);
  if (lane == 0) e_sq[gw] = ss;
}

// cb[4096][256] -> cbT[256][4096], 32-code LDS tiles (pad 257 kills conflicts)
__global__ __launch_bounds__(256) void tp_cb(
    const float* __restrict__ cb, float* __restrict__ cbT) {
  __shared__ float tile[32][257];
  int c0 = blockIdx.x * 32;
  int t = threadIdx.x;
  int r = t >> 6, c4 = (t & 63) * 4;
#pragma unroll
  for (int i = 0; i < 8; ++i) {
    float4 v = *(const float4*)(cb + (size_t)(c0 + r + i * 4) * DIM + c4);
    tile[r + i * 4][c4 + 0] = v.x;
    tile[r + i * 4][c4 + 1] = v.y;
    tile[r + i * 4][c4 + 2] = v.z;
    tile[r + i * 4][c4 + 3] = v.w;
  }
  __syncthreads();
  int cs = (t & 7) * 4;
#pragma unroll
  for (int j = 0; j < 8; ++j) {
    int d = (t >> 3) + j * 32;
    float4 w = make_float4(tile[cs][d], tile[cs + 1][d],
                           tile[cs + 2][d], tile[cs + 3][d]);
    *(float4*)(cbT + (size_t)d * KCB + c0 + cs) = w;
  }
}

// 128x128 tile bf16 MFMA over K=256, BK=32 double-buffered, 4 blocks/CU.
// RACE FIX vs r9: raw s_barrier -> __syncthreads().  The raw barrier builtin
// has no memory-fence semantics at the LLVM level, so the compiler could hoist
// next-iteration ds_reads above it into the window where other waves' STAGE
// writes (tracked by THEIR vmcnt only) haven't landed.  __syncthreads()
// provides the compiler fence + full drain.
__global__ __launch_bounds__(256) void dist_mfma(
    const unsigned short* __restrict__ A2, const unsigned short* __restrict__ EH,
    const float* __restrict__ e_sq,
    float* __restrict__ p1, int* __restrict__ pi, float* __restrict__ p2) {
  __shared__ __align__(16) unsigned short sZ[2][128 * 32];
  __shared__ __align__(16) unsigned short sE[2][128 * 32];
  __shared__ float se[128];
  __shared__ float sm1[2][128];
  __shared__ int   smi[2][128];
  __shared__ float sm2[2][128];

  int wgid = blockIdx.x;
  int swz = (wgid & 7) * 1024 + (wgid >> 3);   // XCD-contiguous, bijective
  int rowp = swz >> 5, colp = swz & 31;
  int brow = rowp * 128, bcol = colp * 128;
  int tid = threadIdx.x;
  int lane = tid & 63, w = tid >> 6;
  int wr = w >> 1, wc = w & 1;
  int rl = lane & 15, k8 = lane >> 4;

  f32x4 acc[4][4] = {};

  const char* gA = (const char*)A2;
  const char* gB = (const char*)EH;
  int r0 = tid >> 2, s_slot = tid & 3;
  int s_src = s_slot ^ (r0 & 3);   // pre-swizzled global 16B-seg (involution)

#define STAGE(b, ks) do {                                                     \
    _Pragma("unroll")                                                         \
    for (int c = 0; c < 2; ++c) {                                             \
      GLOAD(gA + (size_t)(brow + c * 64 + r0) * 512 + (ks) * 64 + s_src * 16, \
            &sZ[b][c * 2048 + tid * 8]);                                      \
      GLOAD(gB + (size_t)(bcol + c * 64 + r0) * 512 + (ks) * 64 + s_src * 16, \
            &sE[b][c * 2048 + tid * 8]);                                      \
    }                                                                         \
  } while (0)

  if (tid < 128) se[tid] = e_sq[bcol + tid];
  STAGE(0, 0);
  asm volatile("s_waitcnt vmcnt(0)" ::: "memory");
  __syncthreads();

#pragma unroll
  for (int ks = 0; ks < 8; ++ks) {
    int cur = ks & 1;
    if (ks < 7) STAGE(cur ^ 1, ks + 1);
    const unsigned short* za = sZ[cur];
    const unsigned short* ea = sE[cur];
    short8 ef[4], zf[4];
    int sseg = (k8 ^ (rl & 3)) * 8;
#pragma unroll
    for (int mi = 0; mi < 4; ++mi)
      ef[mi] = *(const short8*)&ea[(wr * 64 + mi * 16 + rl) * 32 + sseg];
#pragma unroll
    for (int ni = 0; ni < 4; ++ni)
      zf[ni] = *(const short8*)&za[(wc * 64 + ni * 16 + rl) * 32 + sseg];
#pragma unroll
    for (int mi = 0; mi < 4; ++mi)
#pragma unroll
      for (int ni = 0; ni < 4; ++ni)
        acc[mi][ni] = __builtin_amdgcn_mfma_f32_16x16x32_bf16(
            ef[mi], zf[ni], acc[mi][ni], 0, 0, 0);
    asm volatile("s_waitcnt vmcnt(0)" ::: "memory");
    __syncthreads();
  }
#undef STAGE

  // e_sq for this lane's 16 in-register codes (code = cb0 + mi*16 + j)
  int cb0 = bcol + wr * 64 + k8 * 4;
  float e2l[4][4];
#pragma unroll
  for (int mi = 0; mi < 4; ++mi)
#pragma unroll
    for (int j = 0; j < 4; ++j)
      e2l[mi][j] = se[wr * 64 + mi * 16 + k8 * 4 + j];

  // per z-row (ni, rl): in-lane scan of 16 codes, then 2-stage k8 reduce
#pragma unroll
  for (int ni = 0; ni < 4; ++ni) {
    float m1 = 1e30f, m2 = 1e30f; int i1 = 0;
#pragma unroll
    for (int mi = 0; mi < 4; ++mi) {
#pragma unroll
      for (int j = 0; j < 4; ++j) {
        float q = e2l[mi][j] - 2.0f * acc[mi][ni][j];
        if (q < m1) { m2 = m1; m1 = q; i1 = cb0 + mi * 16 + j; }
        else if (q < m2) m2 = q;
      }
    }
#pragma unroll
    for (int mk = 16; mk <= 32; mk <<= 1) {
      float v1 = __shfl_xor(m1, mk);
      int   vi = __shfl_xor(i1, mk);
      float v2 = __shfl_xor(m2, mk);
      float hi = fmaxf(m1, v1), lo2 = fminf(m2, v2);
      if (v1 < m1) { m1 = v1; i1 = vi; }
      else if (v1 == m1 && vi < i1) i1 = vi;
      m2 = fminf(hi, lo2);
    }
    if (k8 == 0) {
      int rowl = wc * 64 + ni * 16 + rl;
      sm1[wr][rowl] = m1; smi[wr][rowl] = i1; sm2[wr][rowl] = m2;
    }
  }
  __syncthreads();
  if (tid < 128) {
    float a1 = sm1[0][tid]; int ai = smi[0][tid]; float a2 = sm2[0][tid];
    float b1 = sm1[1][tid]; int bi = smi[1][tid]; float b2 = sm2[1][tid];
    float m1, m2; int i1;
    if (b1 < a1) { m1 = b1; i1 = bi; m2 = fminf(a1, b2); }
    else         { m1 = a1; i1 = ai; m2 = fminf(b1, a2); }  // ties keep smaller idx
    size_t o = (size_t)colp * NROWS + (brow + tid);
    p1[o] = m1; pi[o] = i1; p2[o] = m2;
  }
}

// merge 32 panel partials per row; write packed slot for ALL rows
// (flagged rows -> ~0ULL sentinel, resolved by rescore_partial's atomicMin;
// gather unpacks the final index, so no separate rescore_final pass)
__global__ __launch_bounds__(256) void merge_kernel(
    const float* __restrict__ p1, const int* __restrict__ pi,
    const float* __restrict__ p2, int* __restrict__ flist,
    int* __restrict__ flcnt, unsigned long long* __restrict__ slot) {
  int r = blockIdx.x * 256 + threadIdx.x;
  float m1 = 1e30f, m2 = 1e30f; int i1 = 0;
  for (int cb = 0; cb < 32; ++cb) {
    size_t o = (size_t)cb * NROWS + r;
    float v1 = p1[o]; int vi = pi[o]; float v2 = p2[o];
    float hi = fmaxf(m1, v1), lo2 = fminf(m2, v2);
    if (v1 < m1) { m1 = v1; i1 = vi; }
    else if (v1 == m1 && vi < i1) i1 = vi;
    m2 = fminf(hi, lo2);
  }
  if (m2 - m1 < MARGIN) {
    slot[r] = ~0ULL;
    int p = atomicAdd(flcnt, 1);
    flist[p] = r;
  } else {
    slot[r] = ((unsigned long long)__float_as_uint(m1) << 32) | (unsigned)i1;
  }
}

// exact fp32 rescore: item = (16-row batch, 1024-code quarter).
__global__ __launch_bounds__(256) void rescore_partial(
    const float* __restrict__ z, const float* __restrict__ cbT,
    const float* __restrict__ z_sq, const float* __restrict__ e_sq,
    const int* __restrict__ flist, const int* __restrict__ flcnt,
    unsigned long long* __restrict__ slot) {
  __shared__ float zs[16][256];
  __shared__ int   rid[16];
  __shared__ float zq[16];
  __shared__ unsigned long long wred[4][16];
  int t = threadIdx.x;
  int lane = t & 63, w = t >> 6;
  int cnt = *flcnt;
  int nitems = ((cnt + 15) >> 4) << 2;
  for (int it = blockIdx.x; it < nitems; it += gridDim.x) {
    int batch = it >> 2, quarter = it & 3;
    __syncthreads();
    if (t < 16) {
      int fi = batch * 16 + t;
      int rr = flist[fi < cnt ? fi : (cnt - 1)];
      rid[t] = rr; zq[t] = z_sq[rr];
    }
    __syncthreads();
    {
      int r8 = t >> 4, c0 = (t & 15) * 16;
      const float* zp = z + (size_t)rid[r8] * DIM + c0;
#pragma unroll
      for (int i = 0; i < 4; ++i)
        *(float4*)&zs[r8][c0 + i * 4] = *(const float4*)(zp + i * 4);
    }
    __syncthreads();
    int cbase = quarter * 1024 + t * 4;
    float4 es4 = *(const float4*)(e_sq + cbase);
    float a0[16], a1[16], a2[16], a3[16];
#pragma unroll
    for (int r = 0; r < 16; ++r) { a0[r] = 0.f; a1[r] = 0.f; a2[r] = 0.f; a3[r] = 0.f; }
    for (int d = 0; d < DIM; ++d) {
      float4 e = *(const float4*)(cbT + (size_t)d * KCB + cbase);
#pragma unroll
      for (int r = 0; r < 16; ++r) {
        float zv = zs[r][d];
        a0[r] = fmaf(zv, e.x, a0[r]);
        a1[r] = fmaf(zv, e.y, a1[r]);
        a2[r] = fmaf(zv, e.z, a2[r]);
        a3[r] = fmaf(zv, e.w, a3[r]);
      }
    }
#pragma unroll
    for (int r = 0; r < 16; ++r) {
      float d0 = (zq[r] + es4.x) - 2.0f * a0[r];
      float d1 = (zq[r] + es4.y) - 2.0f * a1[r];
      float d2 = (zq[r] + es4.z) - 2.0f * a2[r];
      float d3 = (zq[r] + es4.w) - 2.0f * a3[r];
      float m = d0; int ci = cbase;
      if (d1 < m) { m = d1; ci = cbase + 1; }
      if (d2 < m) { m = d2; ci = cbase + 2; }
      if (d3 < m) { m = d3; ci = cbase + 3; }
      unsigned long long p =
          ((unsigned long long)__float_as_uint(m) << 32) | (unsigned)ci;
#pragma unroll
      for (int mk = 32; mk >= 1; mk >>= 1) {
        unsigned long long q = __shfl_xor(p, mk);
        if (q < p) p = q;
      }
      if (lane == 0) wred[w][r] = p;
    }
    __syncthreads();
    if (t < 16) {
      unsigned long long m = wred[0][t];
      if (wred[1][t] < m) m = wred[1][t];
      if (wred[2][t] < m) m = wred[2][t];
      if (wred[3][t] < m) m = wred[3][t];
      atomicMin(&slot[rid[t]], m);
    }
  }
}

// z_q + straight-through + loss partial + counts; unpacks idx from slot.
__global__ __launch_bounds__(256) void gather_kernel(
    const float* __restrict__ z, const float* __restrict__ cb,
    const unsigned long long* __restrict__ slot, int* __restrict__ idx,
    float* __restrict__ out_idxf, float* __restrict__ out_zq,
    int* __restrict__ counts, float* __restrict__ lossp) {
  __shared__ float ls[4];
  int gw = (blockIdx.x * 256 + threadIdx.x) >> 6;
  int lane = threadIdx.x & 63;
  int w = threadIdx.x >> 6;
  int k = (int)(unsigned)(slot[gw] & 0xFFFFFFFFu);
  float4 zq = *(const float4*)(cb + (size_t)k * DIM + lane * 4);
  float4 zv = *(const float4*)(z + (size_t)gw * DIM + lane * 4);
  float4 o;
  o.x = zv.x + (zq.x - zv.x);
  o.y = zv.y + (zq.y - zv.y);
  o.z = zv.z + (zq.z - zv.z);
  o.w = zv.w + (zq.w - zv.w);
  *(float4*)(out_zq + (size_t)gw * DIM + lane * 4) = o;
  float dx = zv.x - zq.x, dy = zv.y - zq.y, dz = zv.z - zq.z, dw = zv.w - zq.w;
  float s = dx * dx + dy * dy + dz * dz + dw * dw;
#pragma unroll
  for (int off = 32; off > 0; off >>= 1) s += __shfl_down(s, off);
  if (lane == 0) {
    ls[w] = s;
    idx[gw] = k;
    out_idxf[gw] = (float)k;
    atomicAdd(&counts[k], 1);
  }
  __syncthreads();
  if (threadIdx.x == 0)
    lossp[blockIdx.x] = ls[0] + ls[1] + ls[2] + ls[3];
}

__global__ void prefix_kernel(const int* __restrict__ counts,
                              int* __restrict__ base, int* __restrict__ cursor) {
  __shared__ int part[256];
  __shared__ int pre[256];
  int t = threadIdx.x;
  int loc[16]; int s = 0;
#pragma unroll
  for (int i = 0; i < 16; ++i) { loc[i] = counts[t * 16 + i]; s += loc[i]; }
  part[t] = s;
  __syncthreads();
  if (t == 0) { int a = 0; for (int i = 0; i < 256; ++i) { pre[i] = a; a += part[i]; } }
  __syncthreads();
  int a = pre[t];
#pragma unroll
  for (int i = 0; i < 16; ++i) { base[t * 16 + i] = a; cursor[t * 16 + i] = a; a += loc[i]; }
}

__global__ void scatter_kernel(const int* __restrict__ idx,
                               int* __restrict__ cursor, int* __restrict__ list2) {
  int n = blockIdx.x * 256 + threadIdx.x;
  int k = idx[n];
  int p = atomicAdd(&cursor[k], 1);
  list2[p] = n;
}

// per-code: sum assigned z rows (inverted index), EMA update, outputs
__global__ __launch_bounds__(256) void finalize_codes(
    const float* __restrict__ ema_cs, const float* __restrict__ ema_es,
    const int* __restrict__ counts, const int* __restrict__ base,
    const int* __restrict__ list2, const float* __restrict__ z,
    float* __restrict__ out_cb, float* __restrict__ out_cs,
    float* __restrict__ out_es) {
  int gw = (blockIdx.x * 256 + threadIdx.x) >> 6;
  int lane = threadIdx.x & 63;
  int cnt = counts[gw], b0 = base[gw];
  float sx = 0.f, sy = 0.f, sz = 0.f, sw = 0.f;
  for (int i = 0; i < cnt; ++i) {
    int n = list2[b0 + i];
    float4 v = *(const float4*)(z + (size_t)n * DIM + lane * 4);
    sx += v.x; sy += v.y; sz += v.z; sw += v.w;
  }
  const float omd = 1.0f - DECAYF;
  float cntf = (float)cnt;
  float ncs = ema_cs[gw] * DECAYF + omd * cntf;
  float nden = ncs + 0.04096f;
  if (lane == 0) out_cs[gw] = ncs;
  size_t o = (size_t)gw * DIM + lane * 4;
  float4 em = *(const float4*)(ema_es + o);
  float nex = em.x * DECAYF + omd * sx;
  float ney = em.y * DECAYF + omd * sy;
  float nez = em.z * DECAYF + omd * sz;
  float new_ = em.w * DECAYF + omd * sw;
  *(float2*)(out_es + o) = make_float2(nex, ney);
  *(float2*)(out_es + o + 2) = make_float2(nez, new_);
  *(float2*)(out_cb + o) = make_float2(nex / nden, ney / nden);
  *(float2*)(out_cb + o + 2) = make_float2(nez / nden, new_ / nden);
}

// one block: reduce 8192 loss partials + entropy from counts
__global__ __launch_bounds__(256) void finalize_scalars(
    const float* __restrict__ lossp, const int* __restrict__ counts,
    float* __restrict__ out_loss, float* __restrict__ out_ppl) {
  __shared__ float red[256];
  int t = threadIdx.x;
  float s = 0.f;
  for (int i = t; i < 8192; i += 256) s += lossp[i];
  float e = 0.f;
  for (int i = t; i < 4096; i += 256) {
    float p = (float)counts[i] * (1.0f / (float)NROWS);
    e -= p * logf(p + 1e-12f);
  }
  red[t] = s;
  __syncthreads();
  for (int st = 128; st > 0; st >>= 1) {
    if (t < st) red[t] += red[t + st];
    __syncthreads();
  }
  float loss_tot = red[0];
  __syncthreads();
  red[t] = e;
  __syncthreads();
  for (int st = 128; st > 0; st >>= 1) {
    if (t < st) red[t] += red[t + st];
    __syncthreads();
  }
  if (t == 0) {
    out_loss[0] = 0.25f * (loss_tot / 8388608.0f);
    out_ppl[0] = expf(red[0]);
  }
}

extern "C" void kernel_launch(void* const* d_in, const int* in_sizes, int n_in,
                              void* d_out, int out_size, void* d_ws, size_t ws_size,
                              hipStream_t stream) {
  (void)in_sizes; (void)n_in; (void)out_size; (void)ws_size;
  const float* z      = (const float*)d_in[0];
  const float* cb     = (const float*)d_in[1];
  const float* ema_cs = (const float*)d_in[2];
  const float* ema_es = (const float*)d_in[3];
  float* out = (float*)d_out;
  char*  ws  = (char*)d_ws;

  unsigned short* A2 = (unsigned short*)(ws + WS_A2);
  unsigned short* EH = (unsigned short*)(ws + WS_EH);
  float* z_sq  = (float*)(ws + WS_ZSQ);
  float* e_sq  = (float*)(ws + WS_ESQ);
  float* p1    = (float*)(ws + WS_P1);
  int*   pi    = (int*)(ws + WS_PI);
  float* p2    = (float*)(ws + WS_P2);
  float* lossp = (float*)(ws + WS_P2);   // reuse: dead after merge_kernel
  unsigned long long* slot = (unsigned long long*)(ws + WS_SLOT);  // A2 reuse
  float* cbT   = (float*)(ws + WS_CBT);                            // A2 reuse
  int*   idx   = (int*)(ws + WS_IDX);
  int*   flist = (int*)(ws + WS_FLIST);
  int*   list2 = (int*)(ws + WS_LIST2);
  int*   base  = (int*)(ws + WS_BASE);
  int*   counts = (int*)(ws + WS_COUNTS);
  int*   cursor = (int*)(ws + WS_CURSOR);
  int*   flcnt  = (int*)(ws + WS_FLCNT);

  hipMemsetAsync(ws + WS_ZERO, 0, WS_ZEROLEN, stream);

  prep_z<<<NROWS / 4, 256, 0, stream>>>(z, A2, z_sq);
  prep_e<<<KCB / 4, 256, 0, stream>>>(cb, EH, e_sq);
  dist_mfma<<<(NROWS / 128) * (KCB / 128), 256, 0, stream>>>(A2, EH, e_sq,
                                                             p1, pi, p2);
  tp_cb<<<KCB / 32, 256, 0, stream>>>(cb, cbT);            // A2 dead from here
  merge_kernel<<<NROWS / 256, 256, 0, stream>>>(p1, pi, p2, flist, flcnt,
                                                slot);
  rescore_partial<<<2048, 256, 0, stream>>>(z, cbT, z_sq, e_sq, flist, flcnt,
                                            slot);
  gather_kernel<<<NROWS / 4, 256, 0, stream>>>(z, cb, slot, idx,
                                               out + OUT_IDX, out + OUT_ZQ,
                                               counts, lossp);
  prefix_kernel<<<1, 256, 0, stream>>>(counts, base, cursor);
  scatter_kernel<<<NROWS / 256, 256, 0, stream>>>(idx, cursor, list2);
  finalize_codes<<<KCB / 4, 256, 0, stream>>>(ema_cs, ema_es, counts, base,
                                              list2, z, out + OUT_CB,
                                              out + OUT_CS, out + OUT_ES);
  finalize_scalars<<<1, 256, 0, stream>>>(lossp, counts, out + OUT_LOSS,
                                          out + OUT_PPL);
}

// Round 11
// 265.170 us; speedup vs baseline: 13.8084x; 1.0807x over previous
//
#include <hip/hip_runtime.h>
#include <hip/hip_bf16.h>
#include <math.h>

#define DIM    256
#define KCB    4096
#define NROWS  32768
#define DECAYF 0.99f
#define MARGIN 0.024f

// ---- d_out offsets (in floats) ----
#define OUT_ZQ   0
#define OUT_IDX  8388608
#define OUT_LOSS 8421376
#define OUT_PPL  8421377
#define OUT_CB   8421378
#define OUT_CS   9469954
#define OUT_ES   9474050

// ---- d_ws offsets (bytes) ----
#define WS_A2      0u            // [32768][256] bf16 (hi only) 16 MB; dead after
                                 // dist_mfma -> reused: slot[] (+0), cbT (+1MB)
#define WS_EH      33554432u     // [4096][256] bf16            2 MB
#define WS_ZSQ     35651584u     // N f32
#define WS_ESQ     35782656u     // K f32
#define WS_P1      35799040u     // [32][32768] f32 partial min1
#define WS_PI      39993344u     // [32][32768] i32 partial idx1
#define WS_P2      44187648u     // [32][32768] f32 partial min2 (dead after
                                 // merge_kernel -> reused for loss partials)
#define WS_IDX     48381952u     // N i32 final idx
#define WS_FLIST   48513024u     // N i32 flagged rows
#define WS_LIST2   48644096u     // N i32 inverted index
#define WS_BASE    48775168u     // K i32
#define WS_ZERO    48791552u     // zeroed region start
#define WS_COUNTS  48791552u     // K i32
#define WS_CURSOR  48807936u     // K i32
#define WS_FLCNT   48824320u
#define WS_ZEROLEN 32772u

#define WS_SLOT    WS_A2                 // N u64 packed (distbits<<32)|idx
#define WS_CBT     (WS_A2 + 1048576u)    // [256][4096] f32 transposed codebook

typedef __attribute__((ext_vector_type(8))) short short8;
typedef __attribute__((ext_vector_type(4))) float f32x4;

#define GLOAD(g, l) __builtin_amdgcn_global_load_lds( \
    (const __attribute__((address_space(1))) unsigned int*)(g), \
    (__attribute__((address_space(3))) unsigned int*)(l), 16, 0, 0)

__device__ __forceinline__ unsigned short f2bf(float x) {
  __hip_bfloat16 h = __float2bfloat16(x);
  return *reinterpret_cast<unsigned short*>(&h);
}

// z -> A2 = z_hi bf16, plus z_sq.  One wave per row.
__global__ __launch_bounds__(256) void prep_z(
    const float* __restrict__ z, unsigned short* __restrict__ A2,
    float* __restrict__ z_sq) {
  int gw = (blockIdx.x * 256 + threadIdx.x) >> 6;
  int lane = threadIdx.x & 63;
  float4 v = *(const float4*)(z + (size_t)gw * DIM + lane * 4);
  float x[4] = {v.x, v.y, v.z, v.w};
  unsigned short h[4];
  float ss = 0.f;
#pragma unroll
  for (int i = 0; i < 4; ++i) { ss += x[i] * x[i]; h[i] = f2bf(x[i]); }
  *(ushort4*)(A2 + (size_t)gw * 256 + lane * 4) =
      make_ushort4(h[0], h[1], h[2], h[3]);
#pragma unroll
  for (int off = 32; off > 0; off >>= 1) ss += __shfl_down(ss, off);
  if (lane == 0) z_sq[gw] = ss;
}

// codebook -> EH bf16 + e_sq (from fp32).  One wave per code.
__global__ __launch_bounds__(256) void prep_e(
    const float* __restrict__ cb, unsigned short* __restrict__ EH,
    float* __restrict__ e_sq) {
  int gw = (blockIdx.x * 256 + threadIdx.x) >> 6;
  int lane = threadIdx.x & 63;
  float4 v = *(const float4*)(cb + (size_t)gw * DIM + lane * 4);
  float x[4] = {v.x, v.y, v.z, v.w};
  unsigned short h[4];
  float ss = 0.f;
#pragma unroll
  for (int i = 0; i < 4; ++i) { ss += x[i] * x[i]; h[i] = f2bf(x[i]); }
  *(ushort4*)(EH + (size_t)gw * 256 + lane * 4) =
      make_ushort4(h[0], h[1], h[2], h[3]);
#pragma unroll
  for (int off = 32; off > 0; off >>= 1) ss += __shfl_down(ss, off);
  if (lane == 0) e_sq[gw] = ss;
}

// cb[4096][256] -> cbT[256][4096], 32-code LDS tiles (pad 257 kills conflicts)
__global__ __launch_bounds__(256) void tp_cb(
    const float* __restrict__ cb, float* __restrict__ cbT) {
  __shared__ float tile[32][257];
  int c0 = blockIdx.x * 32;
  int t = threadIdx.x;
  int r = t >> 6, c4 = (t & 63) * 4;
#pragma unroll
  for (int i = 0; i < 8; ++i) {
    float4 v = *(const float4*)(cb + (size_t)(c0 + r + i * 4) * DIM + c4);
    tile[r + i * 4][c4 + 0] = v.x;
    tile[r + i * 4][c4 + 1] = v.y;
    tile[r + i * 4][c4 + 2] = v.z;
    tile[r + i * 4][c4 + 3] = v.w;
  }
  __syncthreads();
  int cs = (t & 7) * 4;
#pragma unroll
  for (int j = 0; j < 8; ++j) {
    int d = (t >> 3) + j * 32;
    float4 w = make_float4(tile[cs][d], tile[cs + 1][d],
                           tile[cs + 2][d], tile[cs + 3][d]);
    *(float4*)(cbT + (size_t)d * KCB + c0 + cs) = w;
  }
}

// 128x128 tile bf16 MFMA over K=256, BK=32 double-buffered, 4 blocks/CU.
// Swizzle now includes (r>>2)&3: octet-distinct banks (r10's k8^(rl&3) had
// rl vs rl+4 colliding in the same 8-lane service group -> 8.39e6 conflicts).
__global__ __launch_bounds__(256) void dist_mfma(
    const unsigned short* __restrict__ A2, const unsigned short* __restrict__ EH,
    const float* __restrict__ e_sq,
    float* __restrict__ p1, int* __restrict__ pi, float* __restrict__ p2) {
  __shared__ __align__(16) unsigned short sZ[2][128 * 32];
  __shared__ __align__(16) unsigned short sE[2][128 * 32];
  __shared__ float se[128];
  __shared__ float sm1[2][128];
  __shared__ int   smi[2][128];
  __shared__ float sm2[2][128];

  int wgid = blockIdx.x;
  int swz = (wgid & 7) * 1024 + (wgid >> 3);   // XCD-contiguous, bijective
  int rowp = swz >> 5, colp = swz & 31;
  int brow = rowp * 128, bcol = colp * 128;
  int tid = threadIdx.x;
  int lane = tid & 63, w = tid >> 6;
  int wr = w >> 1, wc = w & 1;
  int rl = lane & 15, k8 = lane >> 4;

  f32x4 acc[4][4] = {};

  const char* gA = (const char*)A2;
  const char* gB = (const char*)EH;
  int r0 = tid >> 2;
  int s_src = (tid & 3) ^ (r0 & 3) ^ ((r0 >> 2) & 3);  // involution w/ read

#define STAGE(b, ks) do {                                                     \
    _Pragma("unroll")                                                         \
    for (int c = 0; c < 2; ++c) {                                             \
      GLOAD(gA + (size_t)(brow + c * 64 + r0) * 512 + (ks) * 64 + s_src * 16, \
            &sZ[b][c * 2048 + tid * 8]);                                      \
      GLOAD(gB + (size_t)(bcol + c * 64 + r0) * 512 + (ks) * 64 + s_src * 16, \
            &sE[b][c * 2048 + tid * 8]);                                      \
    }                                                                         \
  } while (0)

  if (tid < 128) se[tid] = e_sq[bcol + tid];
  STAGE(0, 0);
  asm volatile("s_waitcnt vmcnt(0)" ::: "memory");
  __syncthreads();

#pragma unroll
  for (int ks = 0; ks < 8; ++ks) {
    int cur = ks & 1;
    if (ks < 7) STAGE(cur ^ 1, ks + 1);
    const unsigned short* za = sZ[cur];
    const unsigned short* ea = sE[cur];
    short8 ef[4], zf[4];
    int sseg = (k8 ^ (rl & 3) ^ ((rl >> 2) & 3)) * 8;
#pragma unroll
    for (int mi = 0; mi < 4; ++mi)
      ef[mi] = *(const short8*)&ea[(wr * 64 + mi * 16 + rl) * 32 + sseg];
#pragma unroll
    for (int ni = 0; ni < 4; ++ni)
      zf[ni] = *(const short8*)&za[(wc * 64 + ni * 16 + rl) * 32 + sseg];
#pragma unroll
    for (int mi = 0; mi < 4; ++mi)
#pragma unroll
      for (int ni = 0; ni < 4; ++ni)
        acc[mi][ni] = __builtin_amdgcn_mfma_f32_16x16x32_bf16(
            ef[mi], zf[ni], acc[mi][ni], 0, 0, 0);
    asm volatile("s_waitcnt vmcnt(0)" ::: "memory");
    __syncthreads();
  }
#undef STAGE

  // e_sq for this lane's 16 in-register codes (code = cb0 + mi*16 + j)
  int cb0 = bcol + wr * 64 + k8 * 4;
  float e2l[4][4];
#pragma unroll
  for (int mi = 0; mi < 4; ++mi)
#pragma unroll
    for (int j = 0; j < 4; ++j)
      e2l[mi][j] = se[wr * 64 + mi * 16 + k8 * 4 + j];

  // per z-row (ni, rl): in-lane scan of 16 codes, then 2-stage k8 reduce
#pragma unroll
  for (int ni = 0; ni < 4; ++ni) {
    float m1 = 1e30f, m2 = 1e30f; int i1 = 0;
#pragma unroll
    for (int mi = 0; mi < 4; ++mi) {
#pragma unroll
      for (int j = 0; j < 4; ++j) {
        float q = e2l[mi][j] - 2.0f * acc[mi][ni][j];
        if (q < m1) { m2 = m1; m1 = q; i1 = cb0 + mi * 16 + j; }
        else if (q < m2) m2 = q;
      }
    }
#pragma unroll
    for (int mk = 16; mk <= 32; mk <<= 1) {
      float v1 = __shfl_xor(m1, mk);
      int   vi = __shfl_xor(i1, mk);
      float v2 = __shfl_xor(m2, mk);
      float hi = fmaxf(m1, v1), lo2 = fminf(m2, v2);
      if (v1 < m1) { m1 = v1; i1 = vi; }
      else if (v1 == m1 && vi < i1) i1 = vi;
      m2 = fminf(hi, lo2);
    }
    if (k8 == 0) {
      int rowl = wc * 64 + ni * 16 + rl;
      sm1[wr][rowl] = m1; smi[wr][rowl] = i1; sm2[wr][rowl] = m2;
    }
  }
  __syncthreads();
  if (tid < 128) {
    float a1 = sm1[0][tid]; int ai = smi[0][tid]; float a2 = sm2[0][tid];
    float b1 = sm1[1][tid]; int bi = smi[1][tid]; float b2 = sm2[1][tid];
    float m1, m2; int i1;
    if (b1 < a1) { m1 = b1; i1 = bi; m2 = fminf(a1, b2); }
    else         { m1 = a1; i1 = ai; m2 = fminf(b1, a2); }  // ties keep smaller idx
    size_t o = (size_t)colp * NROWS + (brow + tid);
    p1[o] = m1; pi[o] = i1; p2[o] = m2;
  }
}

// merge 32 panel partials per row; write packed slot for ALL rows
// (flagged rows -> ~0ULL sentinel, resolved by rescore_partial's atomicMin;
// gather unpacks the final index, so no separate rescore_final pass)
__global__ __launch_bounds__(256) void merge_kernel(
    const float* __restrict__ p1, const int* __restrict__ pi,
    const float* __restrict__ p2, int* __restrict__ flist,
    int* __restrict__ flcnt, unsigned long long* __restrict__ slot) {
  int r = blockIdx.x * 256 + threadIdx.x;
  float m1 = 1e30f, m2 = 1e30f; int i1 = 0;
  for (int cb = 0; cb < 32; ++cb) {
    size_t o = (size_t)cb * NROWS + r;
    float v1 = p1[o]; int vi = pi[o]; float v2 = p2[o];
    float hi = fmaxf(m1, v1), lo2 = fminf(m2, v2);
    if (v1 < m1) { m1 = v1; i1 = vi; }
    else if (v1 == m1 && vi < i1) i1 = vi;
    m2 = fminf(hi, lo2);
  }
  if (m2 - m1 < MARGIN) {
    slot[r] = ~0ULL;
    int p = atomicAdd(flcnt, 1);
    flist[p] = r;
  } else {
    slot[r] = ((unsigned long long)__float_as_uint(m1) << 32) | (unsigned)i1;
  }
}

// exact fp32 rescore: item = (8-row batch, 1024-code quarter).
// 4 codes x 8 rows register tile; coalesced cbT loads; packed u64 atomicMin.
__global__ __launch_bounds__(256) void rescore_partial(
    const float* __restrict__ z, const float* __restrict__ cbT,
    const float* __restrict__ z_sq, const float* __restrict__ e_sq,
    const int* __restrict__ flist, const int* __restrict__ flcnt,
    unsigned long long* __restrict__ slot) {
  __shared__ float zs[8][256];
  __shared__ int   rid[8];
  __shared__ float zq[8];
  __shared__ unsigned long long wred[4][8];
  int t = threadIdx.x;
  int lane = t & 63, w = t >> 6;
  int cnt = *flcnt;
  int nitems = ((cnt + 7) >> 3) << 2;
  for (int it = blockIdx.x; it < nitems; it += gridDim.x) {
    int batch = it >> 2, quarter = it & 3;
    __syncthreads();
    if (t < 8) {
      int fi = batch * 8 + t;
      int rr = flist[fi < cnt ? fi : (cnt - 1)];
      rid[t] = rr; zq[t] = z_sq[rr];
    }
    __syncthreads();
    {
      int r8 = t >> 5, d0 = (t & 31) * 8;
      const float* zp = z + (size_t)rid[r8] * DIM + d0;
      *(float4*)&zs[r8][d0] = *(const float4*)(zp);
      *(float4*)&zs[r8][d0 + 4] = *(const float4*)(zp + 4);
    }
    __syncthreads();
    int cbase = quarter * 1024 + t * 4;
    float4 es4 = *(const float4*)(e_sq + cbase);
    float a0[8], a1[8], a2[8], a3[8];
#pragma unroll
    for (int r = 0; r < 8; ++r) { a0[r] = 0.f; a1[r] = 0.f; a2[r] = 0.f; a3[r] = 0.f; }
    for (int d = 0; d < DIM; ++d) {
      float4 e = *(const float4*)(cbT + (size_t)d * KCB + cbase);
#pragma unroll
      for (int r = 0; r < 8; ++r) {
        float zv = zs[r][d];
        a0[r] = fmaf(zv, e.x, a0[r]);
        a1[r] = fmaf(zv, e.y, a1[r]);
        a2[r] = fmaf(zv, e.z, a2[r]);
        a3[r] = fmaf(zv, e.w, a3[r]);
      }
    }
#pragma unroll
    for (int r = 0; r < 8; ++r) {
      float d0 = (zq[r] + es4.x) - 2.0f * a0[r];
      float d1 = (zq[r] + es4.y) - 2.0f * a1[r];
      float d2 = (zq[r] + es4.z) - 2.0f * a2[r];
      float d3 = (zq[r] + es4.w) - 2.0f * a3[r];
      float m = d0; int ci = cbase;
      if (d1 < m) { m = d1; ci = cbase + 1; }
      if (d2 < m) { m = d2; ci = cbase + 2; }
      if (d3 < m) { m = d3; ci = cbase + 3; }
      unsigned long long p =
          ((unsigned long long)__float_as_uint(m) << 32) | (unsigned)ci;
#pragma unroll
      for (int mk = 32; mk >= 1; mk >>= 1) {
        unsigned long long q = __shfl_xor(p, mk);
        if (q < p) p = q;
      }
      if (lane == 0) wred[w][r] = p;
    }
    __syncthreads();
    if (t < 8) {
      unsigned long long m = wred[0][t];
      if (wred[1][t] < m) m = wred[1][t];
      if (wred[2][t] < m) m = wred[2][t];
      if (wred[3][t] < m) m = wred[3][t];
      atomicMin(&slot[rid[t]], m);
    }
  }
}

// z_q + straight-through + loss partial + counts; unpacks idx from slot.
__global__ __launch_bounds__(256) void gather_kernel(
    const float* __restrict__ z, const float* __restrict__ cb,
    const unsigned long long* __restrict__ slot, int* __restrict__ idx,
    float* __restrict__ out_idxf, float* __restrict__ out_zq,
    int* __restrict__ counts, float* __restrict__ lossp) {
  __shared__ float ls[4];
  int gw = (blockIdx.x * 256 + threadIdx.x) >> 6;
  int lane = threadIdx.x & 63;
  int w = threadIdx.x >> 6;
  int k = (int)(unsigned)(slot[gw] & 0xFFFFFFFFu);
  float4 zq = *(const float4*)(cb + (size_t)k * DIM + lane * 4);
  float4 zv = *(const float4*)(z + (size_t)gw * DIM + lane * 4);
  float4 o;
  o.x = zv.x + (zq.x - zv.x);
  o.y = zv.y + (zq.y - zv.y);
  o.z = zv.z + (zq.z - zv.z);
  o.w = zv.w + (zq.w - zv.w);
  *(float4*)(out_zq + (size_t)gw * DIM + lane * 4) = o;
  float dx = zv.x - zq.x, dy = zv.y - zq.y, dz = zv.z - zq.z, dw = zv.w - zq.w;
  float s = dx * dx + dy * dy + dz * dz + dw * dw;
#pragma unroll
  for (int off = 32; off > 0; off >>= 1) s += __shfl_down(s, off);
  if (lane == 0) {
    ls[w] = s;
    idx[gw] = k;
    out_idxf[gw] = (float)k;
    atomicAdd(&counts[k], 1);
  }
  __syncthreads();
  if (threadIdx.x == 0)
    lossp[blockIdx.x] = ls[0] + ls[1] + ls[2] + ls[3];
}

__global__ void prefix_kernel(const int* __restrict__ counts,
                              int* __restrict__ base, int* __restrict__ cursor) {
  __shared__ int part[256];
  __shared__ int pre[256];
  int t = threadIdx.x;
  int loc[16]; int s = 0;
#pragma unroll
  for (int i = 0; i < 16; ++i) { loc[i] = counts[t * 16 + i]; s += loc[i]; }
  part[t] = s;
  __syncthreads();
  if (t == 0) { int a = 0; for (int i = 0; i < 256; ++i) { pre[i] = a; a += part[i]; } }
  __syncthreads();
  int a = pre[t];
#pragma unroll
  for (int i = 0; i < 16; ++i) { base[t * 16 + i] = a; cursor[t * 16 + i] = a; a += loc[i]; }
}

__global__ void scatter_kernel(const int* __restrict__ idx,
                               int* __restrict__ cursor, int* __restrict__ list2) {
  int n = blockIdx.x * 256 + threadIdx.x;
  int k = idx[n];
  int p = atomicAdd(&cursor[k], 1);
  list2[p] = n;
}

// per-code: sum assigned z rows (inverted index), EMA update, outputs
__global__ __launch_bounds__(256) void finalize_codes(
    const float* __restrict__ ema_cs, const float* __restrict__ ema_es,
    const int* __restrict__ counts, const int* __restrict__ base,
    const int* __restrict__ list2, const float* __restrict__ z,
    float* __restrict__ out_cb, float* __restrict__ out_cs,
    float* __restrict__ out_es) {
  int gw = (blockIdx.x * 256 + threadIdx.x) >> 6;
  int lane = threadIdx.x & 63;
  int cnt = counts[gw], b0 = base[gw];
  float sx = 0.f, sy = 0.f, sz = 0.f, sw = 0.f;
  for (int i = 0; i < cnt; ++i) {
    int n = list2[b0 + i];
    float4 v = *(const float4*)(z + (size_t)n * DIM + lane * 4);
    sx += v.x; sy += v.y; sz += v.z; sw += v.w;
  }
  const float omd = 1.0f - DECAYF;
  float cntf = (float)cnt;
  float ncs = ema_cs[gw] * DECAYF + omd * cntf;
  float nden = ncs + 0.04096f;
  if (lane == 0) out_cs[gw] = ncs;
  size_t o = (size_t)gw * DIM + lane * 4;
  float4 em = *(const float4*)(ema_es + o);
  float nex = em.x * DECAYF + omd * sx;
  float ney = em.y * DECAYF + omd * sy;
  float nez = em.z * DECAYF + omd * sz;
  float new_ = em.w * DECAYF + omd * sw;
  *(float2*)(out_es + o) = make_float2(nex, ney);
  *(float2*)(out_es + o + 2) = make_float2(nez, new_);
  *(float2*)(out_cb + o) = make_float2(nex / nden, ney / nden);
  *(float2*)(out_cb + o + 2) = make_float2(nez / nden, new_ / nden);
}

// one block: reduce 8192 loss partials + entropy from counts
__global__ __launch_bounds__(256) void finalize_scalars(
    const float* __restrict__ lossp, const int* __restrict__ counts,
    float* __restrict__ out_loss, float* __restrict__ out_ppl) {
  __shared__ float red[256];
  int t = threadIdx.x;
  float s = 0.f;
  for (int i = t; i < 8192; i += 256) s += lossp[i];
  float e = 0.f;
  for (int i = t; i < 4096; i += 256) {
    float p = (float)counts[i] * (1.0f / (float)NROWS);
    e -= p * logf(p + 1e-12f);
  }
  red[t] = s;
  __syncthreads();
  for (int st = 128; st > 0; st >>= 1) {
    if (t < st) red[t] += red[t + st];
    __syncthreads();
  }
  float loss_tot = red[0];
  __syncthreads();
  red[t] = e;
  __syncthreads();
  for (int st = 128; st > 0; st >>= 1) {
    if (t < st) red[t] += red[t + st];
    __syncthreads();
  }
  if (t == 0) {
    out_loss[0] = 0.25f * (loss_tot / 8388608.0f);
    out_ppl[0] = expf(red[0]);
  }
}

extern "C" void kernel_launch(void* const* d_in, const int* in_sizes, int n_in,
                              void* d_out, int out_size, void* d_ws, size_t ws_size,
                              hipStream_t stream) {
  (void)in_sizes; (void)n_in; (void)out_size; (void)ws_size;
  const float* z      = (const float*)d_in[0];
  const float* cb     = (const float*)d_in[1];
  const float* ema_cs = (const float*)d_in[2];
  const float* ema_es = (const float*)d_in[3];
  float* out = (float*)d_out;
  char*  ws  = (char*)d_ws;

  unsigned short* A2 = (unsigned short*)(ws + WS_A2);
  unsigned short* EH = (unsigned short*)(ws + WS_EH);
  float* z_sq  = (float*)(ws + WS_ZSQ);
  float* e_sq  = (float*)(ws + WS_ESQ);
  float* p1    = (float*)(ws + WS_P1);
  int*   pi    = (int*)(ws + WS_PI);
  float* p2    = (float*)(ws + WS_P2);
  float* lossp = (float*)(ws + WS_P2);   // reuse: dead after merge_kernel
  unsigned long long* slot = (unsigned long long*)(ws + WS_SLOT);  // A2 reuse
  float* cbT   = (float*)(ws + WS_CBT);                            // A2 reuse
  int*   idx   = (int*)(ws + WS_IDX);
  int*   flist = (int*)(ws + WS_FLIST);
  int*   list2 = (int*)(ws + WS_LIST2);
  int*   base  = (int*)(ws + WS_BASE);
  int*   counts = (int*)(ws + WS_COUNTS);
  int*   cursor = (int*)(ws + WS_CURSOR);
  int*   flcnt  = (int*)(ws + WS_FLCNT);

  hipMemsetAsync(ws + WS_ZERO, 0, WS_ZEROLEN, stream);

  prep_z<<<NROWS / 4, 256, 0, stream>>>(z, A2, z_sq);
  prep_e<<<KCB / 4, 256, 0, stream>>>(cb, EH, e_sq);
  dist_mfma<<<(NROWS / 128) * (KCB / 128), 256, 0, stream>>>(A2, EH, e_sq,
                                                             p1, pi, p2);
  tp_cb<<<KCB / 32, 256, 0, stream>>>(cb, cbT);            // A2 dead from here
  merge_kernel<<<NROWS / 256, 256, 0, stream>>>(p1, pi, p2, flist, flcnt,
                                                slot);
  rescore_partial<<<2048, 256, 0, stream>>>(z, cbT, z_sq, e_sq, flist, flcnt,
                                            slot);
  gather_kernel<<<NROWS / 4, 256, 0, stream>>>(z, cb, slot, idx,
                                               out + OUT_IDX, out + OUT_ZQ,
                                               counts, lossp);
  prefix_kernel<<<1, 256, 0, stream>>>(counts, base, cursor);
  scatter_kernel<<<NROWS / 256, 256, 0, stream>>>(idx, cursor, list2);
  finalize_codes<<<KCB / 4, 256, 0, stream>>>(ema_cs, ema_es, counts, base,
                                              list2, z, out + OUT_CB,
                                              out + OUT_CS, out + OUT_ES);
  finalize_scalars<<<1, 256, 0, stream>>>(lossp, counts, out + OUT_LOSS,
                                          out + OUT_PPL);
}

// Round 12
// 258.608 us; speedup vs baseline: 14.1588x; 1.0254x over previous
//
#include <hip/hip_runtime.h>
#include <hip/hip_bf16.h>
#include <math.h>

#define DIM    256
#define KCB    4096
#define NROWS  32768
#define DECAYF 0.99f
#define MARGIN 0.024f

// ---- d_out offsets (in floats) ----
#define OUT_ZQ   0
#define OUT_IDX  8388608
#define OUT_LOSS 8421376
#define OUT_PPL  8421377
#define OUT_CB   8421378
#define OUT_CS   9469954
#define OUT_ES   9474050

// ---- d_ws offsets (bytes) ----
#define WS_A2      0u            // [32768][256] bf16 (hi only) 16 MB; dead after
                                 // dist_mfma -> reused: slot[] (+0), cbT (+1MB)
#define WS_EH      33554432u     // [4096][256] bf16            2 MB
#define WS_ZSQ     35651584u     // N f32
#define WS_ESQ     35782656u     // K f32
#define WS_P1      35799040u     // [32][32768] f32 partial min1
#define WS_PI      39993344u     // [32][32768] i32 partial idx1
#define WS_P2      44187648u     // [32][32768] f32 partial min2 (dead after
                                 // merge_kernel -> reused for loss partials)
#define WS_IDX     48381952u     // N i32 final idx
#define WS_FLIST   48513024u     // N i32 flagged rows
#define WS_LIST2   48644096u     // N i32 inverted index
#define WS_BASE    48775168u     // K i32
#define WS_ZERO    48791552u     // zeroed region start
#define WS_COUNTS  48791552u     // K i32
#define WS_CURSOR  48807936u     // K i32
#define WS_FLCNT   48824320u
#define WS_ZEROLEN 32772u

#define WS_SLOT    WS_A2                 // N u64 packed (distbits<<32)|idx
#define WS_CBT     (WS_A2 + 1048576u)    // [256][4096] f32 transposed codebook

typedef __attribute__((ext_vector_type(8))) short short8;
typedef __attribute__((ext_vector_type(4))) float f32x4;

#define GLOAD(g, l) __builtin_amdgcn_global_load_lds( \
    (const __attribute__((address_space(1))) unsigned int*)(g), \
    (__attribute__((address_space(3))) unsigned int*)(l), 16, 0, 0)

__device__ __forceinline__ unsigned short f2bf(float x) {
  __hip_bfloat16 h = __float2bfloat16(x);
  return *reinterpret_cast<unsigned short*>(&h);
}

// fused: blocks [0, NROWS/4) do z -> A2 + z_sq; rest do cb -> EH + e_sq.
__global__ __launch_bounds__(256) void prep_all(
    const float* __restrict__ z, const float* __restrict__ cb,
    unsigned short* __restrict__ A2, unsigned short* __restrict__ EH,
    float* __restrict__ z_sq, float* __restrict__ e_sq) {
  int b = blockIdx.x;
  int lane = threadIdx.x & 63;
  const float* src;
  unsigned short* dst;
  float* sq;
  int gw;
  if (b < NROWS / 4) {
    gw = (b * 256 + threadIdx.x) >> 6;
    src = z; dst = A2; sq = z_sq;
  } else {
    gw = ((b - NROWS / 4) * 256 + threadIdx.x) >> 6;
    src = cb; dst = EH; sq = e_sq;
  }
  float4 v = *(const float4*)(src + (size_t)gw * DIM + lane * 4);
  float x[4] = {v.x, v.y, v.z, v.w};
  unsigned short h[4];
  float ss = 0.f;
#pragma unroll
  for (int i = 0; i < 4; ++i) { ss += x[i] * x[i]; h[i] = f2bf(x[i]); }
  *(ushort4*)(dst + (size_t)gw * 256 + lane * 4) =
      make_ushort4(h[0], h[1], h[2], h[3]);
#pragma unroll
  for (int off = 32; off > 0; off >>= 1) ss += __shfl_down(ss, off);
  if (lane == 0) sq[gw] = ss;
}

// cb[4096][256] -> cbT[256][4096], 32-code LDS tiles (pad 257 kills conflicts)
__global__ __launch_bounds__(256) void tp_cb(
    const float* __restrict__ cb, float* __restrict__ cbT) {
  __shared__ float tile[32][257];
  int c0 = blockIdx.x * 32;
  int t = threadIdx.x;
  int r = t >> 6, c4 = (t & 63) * 4;
#pragma unroll
  for (int i = 0; i < 8; ++i) {
    float4 v = *(const float4*)(cb + (size_t)(c0 + r + i * 4) * DIM + c4);
    tile[r + i * 4][c4 + 0] = v.x;
    tile[r + i * 4][c4 + 1] = v.y;
    tile[r + i * 4][c4 + 2] = v.z;
    tile[r + i * 4][c4 + 3] = v.w;
  }
  __syncthreads();
  int cs = (t & 7) * 4;
#pragma unroll
  for (int j = 0; j < 8; ++j) {
    int d = (t >> 3) + j * 32;
    float4 w = make_float4(tile[cs][d], tile[cs + 1][d],
                           tile[cs + 2][d], tile[cs + 3][d]);
    *(float4*)(cbT + (size_t)d * KCB + c0 + cs) = w;
  }
}

// 128x128 tile bf16 MFMA over K=256, BK=32, 3-buffer counted-vmcnt pipeline.
// Per iter: vmcnt(4) (next tile's 4 loads stay in flight), raw s_barrier
// flanked by sched_barrier(0) (r9/rule-#18 hoist fence), compute, stage ks+2.
// Buffer safety: STAGE(ks+2) overwrites buf[(ks-1)%3]; all waves passed this
// iter's barrier => finished iter ks-1's ds_reads (retired via lgkmcnt
// before their MFMAs).  Swapped operands: lane holds 16 codes in-register.
__global__ __launch_bounds__(256) void dist_mfma(
    const unsigned short* __restrict__ A2, const unsigned short* __restrict__ EH,
    const float* __restrict__ e_sq,
    float* __restrict__ p1, int* __restrict__ pi, float* __restrict__ p2) {
  __shared__ __align__(16) unsigned short sZ[3][128 * 32];
  __shared__ __align__(16) unsigned short sE[3][128 * 32];
  __shared__ float se[128];
  __shared__ float sm1[2][128];
  __shared__ int   smi[2][128];
  __shared__ float sm2[2][128];

  int wgid = blockIdx.x;
  int swz = (wgid & 7) * 1024 + (wgid >> 3);   // XCD-contiguous, bijective
  int rowp = swz >> 5, colp = swz & 31;
  int brow = rowp * 128, bcol = colp * 128;
  int tid = threadIdx.x;
  int lane = tid & 63, w = tid >> 6;
  int wr = w >> 1, wc = w & 1;
  int rl = lane & 15, k8 = lane >> 4;

  f32x4 acc[4][4] = {};

  int r0 = tid >> 2;
  int s_src = (tid & 3) ^ (r0 & 3) ^ ((r0 >> 2) & 3);  // involution w/ read
  const char* baseA = (const char*)A2 + (size_t)(brow + r0) * 512 + s_src * 16;
  const char* baseB = (const char*)EH + (size_t)(bcol + r0) * 512 + s_src * 16;

#define STAGE(b, ks_) do {                                                    \
    GLOAD(baseA + (ks_) * 64,         &sZ[b][tid * 8]);                       \
    GLOAD(baseA + 32768 + (ks_) * 64, &sZ[b][2048 + tid * 8]);                \
    GLOAD(baseB + (ks_) * 64,         &sE[b][tid * 8]);                       \
    GLOAD(baseB + 32768 + (ks_) * 64, &sE[b][2048 + tid * 8]);                \
  } while (0)

  if (tid < 128) se[tid] = e_sq[bcol + tid];
  STAGE(0, 0);
  STAGE(1, 1);
  __syncthreads();   // full drain: tiles 0,1 resident, se visible

#pragma unroll
  for (int ks = 0; ks < 8; ++ks) {
    if (ks >= 2 && ks < 7) { asm volatile("s_waitcnt vmcnt(4)" ::: "memory"); }
    if (ks == 7)           { asm volatile("s_waitcnt vmcnt(0)" ::: "memory"); }
    if (ks >= 1) {
      __builtin_amdgcn_sched_barrier(0);
      __builtin_amdgcn_s_barrier();
      __builtin_amdgcn_sched_barrier(0);
    }
    const unsigned short* za = sZ[ks % 3];
    const unsigned short* ea = sE[ks % 3];
    short8 ef[4], zf[4];
    int sseg = (k8 ^ (rl & 3) ^ ((rl >> 2) & 3)) * 8;
#pragma unroll
    for (int mi = 0; mi < 4; ++mi)
      ef[mi] = *(const short8*)&ea[(wr * 64 + mi * 16 + rl) * 32 + sseg];
#pragma unroll
    for (int ni = 0; ni < 4; ++ni)
      zf[ni] = *(const short8*)&za[(wc * 64 + ni * 16 + rl) * 32 + sseg];
#pragma unroll
    for (int mi = 0; mi < 4; ++mi)
#pragma unroll
      for (int ni = 0; ni < 4; ++ni)
        acc[mi][ni] = __builtin_amdgcn_mfma_f32_16x16x32_bf16(
            ef[mi], zf[ni], acc[mi][ni], 0, 0, 0);
    if (ks < 6) STAGE((ks + 2) % 3, ks + 2);
  }
#undef STAGE

  // e_sq for this lane's 16 in-register codes (code = cb0 + mi*16 + j)
  int cb0 = bcol + wr * 64 + k8 * 4;
  float e2l[4][4];
#pragma unroll
  for (int mi = 0; mi < 4; ++mi)
#pragma unroll
    for (int j = 0; j < 4; ++j)
      e2l[mi][j] = se[wr * 64 + mi * 16 + k8 * 4 + j];

  // per z-row (ni, rl): in-lane scan of 16 codes, then 2-stage k8 reduce
#pragma unroll
  for (int ni = 0; ni < 4; ++ni) {
    float m1 = 1e30f, m2 = 1e30f; int i1 = 0;
#pragma unroll
    for (int mi = 0; mi < 4; ++mi) {
#pragma unroll
      for (int j = 0; j < 4; ++j) {
        float q = e2l[mi][j] - 2.0f * acc[mi][ni][j];
        if (q < m1) { m2 = m1; m1 = q; i1 = cb0 + mi * 16 + j; }
        else if (q < m2) m2 = q;
      }
    }
#pragma unroll
    for (int mk = 16; mk <= 32; mk <<= 1) {
      float v1 = __shfl_xor(m1, mk);
      int   vi = __shfl_xor(i1, mk);
      float v2 = __shfl_xor(m2, mk);
      float hi = fmaxf(m1, v1), lo2 = fminf(m2, v2);
      if (v1 < m1) { m1 = v1; i1 = vi; }
      else if (v1 == m1 && vi < i1) i1 = vi;
      m2 = fminf(hi, lo2);
    }
    if (k8 == 0) {
      int rowl = wc * 64 + ni * 16 + rl;
      sm1[wr][rowl] = m1; smi[wr][rowl] = i1; sm2[wr][rowl] = m2;
    }
  }
  __syncthreads();
  if (tid < 128) {
    float a1 = sm1[0][tid]; int ai = smi[0][tid]; float a2 = sm2[0][tid];
    float b1 = sm1[1][tid]; int bi = smi[1][tid]; float b2 = sm2[1][tid];
    float m1, m2; int i1;
    if (b1 < a1) { m1 = b1; i1 = bi; m2 = fminf(a1, b2); }
    else         { m1 = a1; i1 = ai; m2 = fminf(b1, a2); }  // ties keep smaller idx
    size_t o = (size_t)colp * NROWS + (brow + tid);
    p1[o] = m1; pi[o] = i1; p2[o] = m2;
  }
}

// merge 32 panel partials per row; write packed slot for ALL rows
__global__ __launch_bounds__(256) void merge_kernel(
    const float* __restrict__ p1, const int* __restrict__ pi,
    const float* __restrict__ p2, int* __restrict__ flist,
    int* __restrict__ flcnt, unsigned long long* __restrict__ slot) {
  int r = blockIdx.x * 256 + threadIdx.x;
  float m1 = 1e30f, m2 = 1e30f; int i1 = 0;
  for (int cb = 0; cb < 32; ++cb) {
    size_t o = (size_t)cb * NROWS + r;
    float v1 = p1[o]; int vi = pi[o]; float v2 = p2[o];
    float hi = fmaxf(m1, v1), lo2 = fminf(m2, v2);
    if (v1 < m1) { m1 = v1; i1 = vi; }
    else if (v1 == m1 && vi < i1) i1 = vi;
    m2 = fminf(hi, lo2);
  }
  if (m2 - m1 < MARGIN) {
    slot[r] = ~0ULL;
    int p = atomicAdd(flcnt, 1);
    flist[p] = r;
  } else {
    slot[r] = ((unsigned long long)__float_as_uint(m1) << 32) | (unsigned)i1;
  }
}

// exact fp32 rescore: item = (8-row batch, 1024-code quarter).
__global__ __launch_bounds__(256) void rescore_partial(
    const float* __restrict__ z, const float* __restrict__ cbT,
    const float* __restrict__ z_sq, const float* __restrict__ e_sq,
    const int* __restrict__ flist, const int* __restrict__ flcnt,
    unsigned long long* __restrict__ slot) {
  __shared__ float zs[8][256];
  __shared__ int   rid[8];
  __shared__ float zq[8];
  __shared__ unsigned long long wred[4][8];
  int t = threadIdx.x;
  int lane = t & 63, w = t >> 6;
  int cnt = *flcnt;
  int nitems = ((cnt + 7) >> 3) << 2;
  for (int it = blockIdx.x; it < nitems; it += gridDim.x) {
    int batch = it >> 2, quarter = it & 3;
    __syncthreads();
    if (t < 8) {
      int fi = batch * 8 + t;
      int rr = flist[fi < cnt ? fi : (cnt - 1)];
      rid[t] = rr; zq[t] = z_sq[rr];
    }
    __syncthreads();
    {
      int r8 = t >> 5, d0 = (t & 31) * 8;
      const float* zp = z + (size_t)rid[r8] * DIM + d0;
      *(float4*)&zs[r8][d0] = *(const float4*)(zp);
      *(float4*)&zs[r8][d0 + 4] = *(const float4*)(zp + 4);
    }
    __syncthreads();
    int cbase = quarter * 1024 + t * 4;
    float4 es4 = *(const float4*)(e_sq + cbase);
    float a0[8], a1[8], a2[8], a3[8];
#pragma unroll
    for (int r = 0; r < 8; ++r) { a0[r] = 0.f; a1[r] = 0.f; a2[r] = 0.f; a3[r] = 0.f; }
    for (int d = 0; d < DIM; ++d) {
      float4 e = *(const float4*)(cbT + (size_t)d * KCB + cbase);
#pragma unroll
      for (int r = 0; r < 8; ++r) {
        float zv = zs[r][d];
        a0[r] = fmaf(zv, e.x, a0[r]);
        a1[r] = fmaf(zv, e.y, a1[r]);
        a2[r] = fmaf(zv, e.z, a2[r]);
        a3[r] = fmaf(zv, e.w, a3[r]);
      }
    }
#pragma unroll
    for (int r = 0; r < 8; ++r) {
      float d0 = (zq[r] + es4.x) - 2.0f * a0[r];
      float d1 = (zq[r] + es4.y) - 2.0f * a1[r];
      float d2 = (zq[r] + es4.z) - 2.0f * a2[r];
      float d3 = (zq[r] + es4.w) - 2.0f * a3[r];
      float m = d0; int ci = cbase;
      if (d1 < m) { m = d1; ci = cbase + 1; }
      if (d2 < m) { m = d2; ci = cbase + 2; }
      if (d3 < m) { m = d3; ci = cbase + 3; }
      unsigned long long p =
          ((unsigned long long)__float_as_uint(m) << 32) | (unsigned)ci;
#pragma unroll
      for (int mk = 32; mk >= 1; mk >>= 1) {
        unsigned long long q = __shfl_xor(p, mk);
        if (q < p) p = q;
      }
      if (lane == 0) wred[w][r] = p;
    }
    __syncthreads();
    if (t < 8) {
      unsigned long long m = wred[0][t];
      if (wred[1][t] < m) m = wred[1][t];
      if (wred[2][t] < m) m = wred[2][t];
      if (wred[3][t] < m) m = wred[3][t];
      atomicMin(&slot[rid[t]], m);
    }
  }
}

// z_q + straight-through + loss partial + counts; unpacks idx from slot.
__global__ __launch_bounds__(256) void gather_kernel(
    const float* __restrict__ z, const float* __restrict__ cb,
    const unsigned long long* __restrict__ slot, int* __restrict__ idx,
    float* __restrict__ out_idxf, float* __restrict__ out_zq,
    int* __restrict__ counts, float* __restrict__ lossp) {
  __shared__ float ls[4];
  int gw = (blockIdx.x * 256 + threadIdx.x) >> 6;
  int lane = threadIdx.x & 63;
  int w = threadIdx.x >> 6;
  int k = (int)(unsigned)(slot[gw] & 0xFFFFFFFFu);
  float4 zq = *(const float4*)(cb + (size_t)k * DIM + lane * 4);
  float4 zv = *(const float4*)(z + (size_t)gw * DIM + lane * 4);
  float4 o;
  o.x = zv.x + (zq.x - zv.x);
  o.y = zv.y + (zq.y - zv.y);
  o.z = zv.z + (zq.z - zv.z);
  o.w = zv.w + (zq.w - zv.w);
  *(float4*)(out_zq + (size_t)gw * DIM + lane * 4) = o;
  float dx = zv.x - zq.x, dy = zv.y - zq.y, dz = zv.z - zq.z, dw = zv.w - zq.w;
  float s = dx * dx + dy * dy + dz * dz + dw * dw;
#pragma unroll
  for (int off = 32; off > 0; off >>= 1) s += __shfl_down(s, off);
  if (lane == 0) {
    ls[w] = s;
    idx[gw] = k;
    out_idxf[gw] = (float)k;
    atomicAdd(&counts[k], 1);
  }
  __syncthreads();
  if (threadIdx.x == 0)
    lossp[blockIdx.x] = ls[0] + ls[1] + ls[2] + ls[3];
}

__global__ void prefix_kernel(const int* __restrict__ counts,
                              int* __restrict__ base, int* __restrict__ cursor) {
  __shared__ int part[256];
  __shared__ int pre[256];
  int t = threadIdx.x;
  int loc[16]; int s = 0;
#pragma unroll
  for (int i = 0; i < 16; ++i) { loc[i] = counts[t * 16 + i]; s += loc[i]; }
  part[t] = s;
  __syncthreads();
  if (t == 0) { int a = 0; for (int i = 0; i < 256; ++i) { pre[i] = a; a += part[i]; } }
  __syncthreads();
  int a = pre[t];
#pragma unroll
  for (int i = 0; i < 16; ++i) { base[t * 16 + i] = a; cursor[t * 16 + i] = a; a += loc[i]; }
}

__global__ void scatter_kernel(const int* __restrict__ idx,
                               int* __restrict__ cursor, int* __restrict__ list2) {
  int n = blockIdx.x * 256 + threadIdx.x;
  int k = idx[n];
  int p = atomicAdd(&cursor[k], 1);
  list2[p] = n;
}

// per-code: sum assigned z rows (inverted index), EMA update, outputs.
// Block 0 additionally reduces loss partials + entropy (inputs ready since
// gather) -- replaces the standalone finalize_scalars launch.
__global__ __launch_bounds__(256) void finalize_codes(
    const float* __restrict__ ema_cs, const float* __restrict__ ema_es,
    const int* __restrict__ counts, const int* __restrict__ base,
    const int* __restrict__ list2, const float* __restrict__ z,
    float* __restrict__ out_cb, float* __restrict__ out_cs,
    float* __restrict__ out_es, const float* __restrict__ lossp,
    float* __restrict__ out_loss, float* __restrict__ out_ppl) {
  __shared__ float red[256];
  int gw = (blockIdx.x * 256 + threadIdx.x) >> 6;
  int lane = threadIdx.x & 63;
  int cnt = counts[gw], b0 = base[gw];
  float sx = 0.f, sy = 0.f, sz = 0.f, sw = 0.f;
  for (int i = 0; i < cnt; ++i) {
    int n = list2[b0 + i];
    float4 v = *(const float4*)(z + (size_t)n * DIM + lane * 4);
    sx += v.x; sy += v.y; sz += v.z; sw += v.w;
  }
  const float omd = 1.0f - DECAYF;
  float cntf = (float)cnt;
  float ncs = ema_cs[gw] * DECAYF + omd * cntf;
  float nden = ncs + 0.04096f;
  if (lane == 0) out_cs[gw] = ncs;
  size_t o = (size_t)gw * DIM + lane * 4;
  float4 em = *(const float4*)(ema_es + o);
  float nex = em.x * DECAYF + omd * sx;
  float ney = em.y * DECAYF + omd * sy;
  float nez = em.z * DECAYF + omd * sz;
  float new_ = em.w * DECAYF + omd * sw;
  *(float2*)(out_es + o) = make_float2(nex, ney);
  *(float2*)(out_es + o + 2) = make_float2(nez, new_);
  *(float2*)(out_cb + o) = make_float2(nex / nden, ney / nden);
  *(float2*)(out_cb + o + 2) = make_float2(nez / nden, new_ / nden);

  if (blockIdx.x == 0) {
    int t = threadIdx.x;
    float s = 0.f;
    for (int i = t; i < 8192; i += 256) s += lossp[i];
    float e = 0.f;
    for (int i = t; i < 4096; i += 256) {
      float p = (float)counts[i] * (1.0f / (float)NROWS);
      e -= p * logf(p + 1e-12f);
    }
    red[t] = s;
    __syncthreads();
    for (int st = 128; st > 0; st >>= 1) {
      if (t < st) red[t] += red[t + st];
      __syncthreads();
    }
    float loss_tot = red[0];
    __syncthreads();
    red[t] = e;
    __syncthreads();
    for (int st = 128; st > 0; st >>= 1) {
      if (t < st) red[t] += red[t + st];
      __syncthreads();
    }
    if (t == 0) {
      out_loss[0] = 0.25f * (loss_tot / 8388608.0f);
      out_ppl[0] = expf(red[0]);
    }
  }
}

extern "C" void kernel_launch(void* const* d_in, const int* in_sizes, int n_in,
                              void* d_out, int out_size, void* d_ws, size_t ws_size,
                              hipStream_t stream) {
  (void)in_sizes; (void)n_in; (void)out_size; (void)ws_size;
  const float* z      = (const float*)d_in[0];
  const float* cb     = (const float*)d_in[1];
  const float* ema_cs = (const float*)d_in[2];
  const float* ema_es = (const float*)d_in[3];
  float* out = (float*)d_out;
  char*  ws  = (char*)d_ws;

  unsigned short* A2 = (unsigned short*)(ws + WS_A2);
  unsigned short* EH = (unsigned short*)(ws + WS_EH);
  float* z_sq  = (float*)(ws + WS_ZSQ);
  float* e_sq  = (float*)(ws + WS_ESQ);
  float* p1    = (float*)(ws + WS_P1);
  int*   pi    = (int*)(ws + WS_PI);
  float* p2    = (float*)(ws + WS_P2);
  float* lossp = (float*)(ws + WS_P2);   // reuse: dead after merge_kernel
  unsigned long long* slot = (unsigned long long*)(ws + WS_SLOT);  // A2 reuse
  float* cbT   = (float*)(ws + WS_CBT);                            // A2 reuse
  int*   idx   = (int*)(ws + WS_IDX);
  int*   flist = (int*)(ws + WS_FLIST);
  int*   list2 = (int*)(ws + WS_LIST2);
  int*   base  = (int*)(ws + WS_BASE);
  int*   counts = (int*)(ws + WS_COUNTS);
  int*   cursor = (int*)(ws + WS_CURSOR);
  int*   flcnt  = (int*)(ws + WS_FLCNT);

  hipMemsetAsync(ws + WS_ZERO, 0, WS_ZEROLEN, stream);

  prep_all<<<NROWS / 4 + KCB / 4, 256, 0, stream>>>(z, cb, A2, EH, z_sq, e_sq);
  dist_mfma<<<(NROWS / 128) * (KCB / 128), 256, 0, stream>>>(A2, EH, e_sq,
                                                             p1, pi, p2);
  tp_cb<<<KCB / 32, 256, 0, stream>>>(cb, cbT);            // A2 dead from here
  merge_kernel<<<NROWS / 256, 256, 0, stream>>>(p1, pi, p2, flist, flcnt,
                                                slot);
  rescore_partial<<<2048, 256, 0, stream>>>(z, cbT, z_sq, e_sq, flist, flcnt,
                                            slot);
  gather_kernel<<<NROWS / 4, 256, 0, stream>>>(z, cb, slot, idx,
                                               out + OUT_IDX, out + OUT_ZQ,
                                               counts, lossp);
  prefix_kernel<<<1, 256, 0, stream>>>(counts, base, cursor);
  scatter_kernel<<<NROWS / 256, 256, 0, stream>>>(idx, cursor, list2);
  finalize_codes<<<KCB / 4, 256, 0, stream>>>(ema_cs, ema_es, counts, base,
                                              list2, z, out + OUT_CB,
                                              out + OUT_CS, out + OUT_ES,
                                              lossp, out + OUT_LOSS,
                                              out + OUT_PPL);
}